// Round 10
// baseline (268.495 us; speedup 1.0000x reference)
//
#include <hip/hip_runtime.h>
#include <cstdint>

#define T_LEN 1024
#define NBIG  6400     // padded N for fused projection GEMM (6160 real cols, 50 x 128 tiles)
#define SCALE_Q 0.08838834764831843f   // DK^-0.5
#define NBT 8          // timesteps per convnorm block

typedef __bf16 bf16;
typedef __bf16 bf16x8 __attribute__((ext_vector_type(8)));
typedef float  f32x4  __attribute__((ext_vector_type(4)));

__device__ __forceinline__ unsigned short f2bf(float f) {
  unsigned int u = __builtin_bit_cast(unsigned int, f);
  u += 0x7FFFu + ((u >> 16) & 1u);          // RNE
  return (unsigned short)(u >> 16);
}
__device__ __forceinline__ float bf2f(unsigned short u) {
  return __builtin_bit_cast(float, (unsigned int)u << 16);
}
__device__ __forceinline__ float silu_f(float x) { return x / (1.f + __expf(-x)); }

#define GLDS(src, dst) \
  __builtin_amdgcn_global_load_lds( \
      (__attribute__((address_space(1))) void*)(void*)(src), \
      (__attribute__((address_space(3))) void*)(void*)(dst), 16, 0, 0)

// ---------------- fp32 -> bf16 conversion (4 elems/thread) ----------------
__global__ __launch_bounds__(256) void cvt_bf16(const float* __restrict__ in,
                                                unsigned short* __restrict__ out, int n4) {
  int idx = blockIdx.x * 256 + threadIdx.x;
  if (idx >= n4) return;
  float4 f = ((const float4*)in)[idx];
  ushort4 o = { f2bf(f.x), f2bf(f.y), f2bf(f.z), f2bf(f.w) };
  ((ushort4*)out)[idx] = o;
}

// ------------- build concatenated weight matrix W[NBIG][2048] bf16 -------------
__global__ __launch_bounds__(256) void build_w(
    const float* __restrict__ qw, const float* __restrict__ kw,
    const float* __restrict__ vw, const float* __restrict__ gw,
    const float* __restrict__ aw, const float* __restrict__ bw,
    unsigned short* __restrict__ W) {
  int idx = blockIdx.x * 256 + threadIdx.x;   // quad id, exact grid
  int r = idx >> 9;                           // row (2048/4 = 512 quads per row)
  int c = (idx & 511) << 2;
  const float* src;
  if      (r < 1024) src = qw + (size_t)r * 2048;
  else if (r < 2048) src = kw + (size_t)(r - 1024) * 2048;
  else if (r < 4096) src = vw + (size_t)(r - 2048) * 2048;
  else if (r < 6144) src = gw + (size_t)(r - 4096) * 2048;
  else if (r < 6152) src = aw + (size_t)(r - 6144) * 2048;
  else if (r < 6160) src = bw + (size_t)(r - 6152) * 2048;
  else               src = nullptr;
  ushort4 o;
  if (src) {
    float4 f = *(const float4*)(src + c);
    o = { f2bf(f.x), f2bf(f.y), f2bf(f.z), f2bf(f.w) };
  } else {
    o = { 0, 0, 0, 0 };
  }
  *(ushort4*)(W + (size_t)r * 2048 + c) = o;
}

// ============ pipelined NT GEMM: BM=128 x BN tile, BK=32, ring-3 LDS, counted vmcnt ============
// C[M][N] = A[M][K] * B[N][K]^T, bf16 in. T threads = T/64 waves (2 x WN), wave tile 64x64.
// R6-proven schedule: per K-step { STAGE(kt+2); setprio(1); 16 MFMA; setprio(0);
// lgkmcnt(0); vmcnt(LOADS); s_barrier; ds_read next frags }. vmcnt never drains to 0.
// WAR: stage slot (kt+2)%3 == (kt-1)%3, whose reads completed before the previous barrier.
// LDS swizzle (0-conflict, R4-verified): logical k-slot s of row r at phys s ^ ((r>>1)&3).
// Requires M = 2048 (16 M-tiles) for the XCD-chunked block map.
template <int BN, int WN, int T, bool BF16OUT>
__global__ __launch_bounds__(T, 4) void gemm_pipe(
    const bf16* __restrict__ A, const bf16* __restrict__ Bm,
    void* __restrict__ Cv, int N, int K) {
  constexpr int AI = (128 * 32) / (T * 8);   // A glds insts/thread per K-tile
  constexpr int BI = (BN * 32) / (T * 8);    // B glds insts/thread per K-tile
  constexpr int LOADS = AI + BI;
  __shared__ bf16 LA[3][128 * 32];
  __shared__ bf16 LB[3][BN * 32];
  const int tid = threadIdx.x;
  const int lane = tid & 63;
  const int wid = tid >> 6;
  const int wm = wid / WN, wn = wid % WN;
  // XCD-chunked bijective block map: xcd owns m-rows {xcd, xcd+8} x all n-tiles
  const int bid = blockIdx.x;
  const int xcd = bid & 7, jj = bid >> 3;
  const long brow = (long)(xcd + 8 * (jj & 1)) * 128;
  const long bcol = (long)(jj >> 1) * BN;

  f32x4 acc[4][4];
#pragma unroll
  for (int m = 0; m < 4; ++m)
#pragma unroll
    for (int n = 0; n < 4; ++n)
#pragma unroll
      for (int r = 0; r < 4; ++r) acc[m][n][r] = 0.f;

  // staging map: flat slot = e*T + tid -> (row = flat>>2, pslot = flat&3);
  // global source col = (pslot ^ ((row>>1)&3)) * 8  (inverse swizzle, linear LDS dest)
  const bf16* AgS[AI];
  const bf16* BgS[BI];
  int adst[AI], bdst[BI];
#pragma unroll
  for (int e = 0; e < AI; ++e) {
    const int flat = e * T + tid;
    const int row = flat >> 2;
    const int sl = (flat & 3) ^ ((row >> 1) & 3);
    AgS[e] = A + (brow + row) * (long)K + sl * 8;
    adst[e] = flat * 8;
  }
#pragma unroll
  for (int e = 0; e < BI; ++e) {
    const int flat = e * T + tid;
    const int row = flat >> 2;
    const int sl = (flat & 3) ^ ((row >> 1) & 3);
    BgS[e] = Bm + (bcol + row) * (long)K + sl * 8;
    bdst[e] = flat * 8;
  }

#define STAGE(kt, sb)                                              \
  {                                                                \
    const long ko = (long)(kt) * 32;                               \
    _Pragma("unroll")                                              \
    for (int e = 0; e < AI; ++e) GLDS(AgS[e] + ko, &LA[sb][0] + adst[e]); \
    _Pragma("unroll")                                              \
    for (int e = 0; e < BI; ++e) GLDS(BgS[e] + ko, &LB[sb][0] + bdst[e]); \
  }
#define WAIT_VM()                                                  \
  if constexpr (LOADS == 3) asm volatile("s_waitcnt vmcnt(3)" ::: "memory"); \
  else                      asm volatile("s_waitcnt vmcnt(4)" ::: "memory");

  // read offsets (halfwords): row*32 + (ks ^ ((r16>>1)&3))*8
  const int r16 = lane & 15;
  const int ks = lane >> 4;
  const int pso = (ks ^ ((r16 >> 1) & 3)) * 8;
  int rdA[4], rdB[4];
#pragma unroll
  for (int i = 0; i < 4; ++i) rdA[i] = (wm * 64 + i * 16 + r16) * 32 + pso;
#pragma unroll
  for (int j = 0; j < 4; ++j) rdB[j] = (wn * 64 + j * 16 + r16) * 32 + pso;

  const int nkt = K >> 5;
  STAGE(0, 0);
  STAGE(1, 1);
  WAIT_VM();                         // buf0 landed (stage(1) may stay in flight)
  __builtin_amdgcn_s_barrier();

  bf16x8 af[4], bfr[4];
#pragma unroll
  for (int i = 0; i < 4; ++i) af[i] = *(const bf16x8*)(&LA[0][0] + rdA[i]);
#pragma unroll
  for (int j = 0; j < 4; ++j) bfr[j] = *(const bf16x8*)(&LB[0][0] + rdB[j]);

  for (int kt = 0; kt < nkt; ++kt) {
    const int kts = (kt + 2 < nkt) ? kt + 2 : nkt - 1;  // clamp src, keep count uniform
    const int sb = (kt + 2) % 3;                        // == (kt-1)%3: read-complete slot
    const int nb = (kt + 1) % 3;

    STAGE(kts, sb);
    __builtin_amdgcn_s_setprio(1);
#pragma unroll
    for (int i = 0; i < 4; ++i)
#pragma unroll
      for (int j = 0; j < 4; ++j)
        acc[i][j] = __builtin_amdgcn_mfma_f32_16x16x32_bf16(af[i], bfr[j], acc[i][j], 0, 0, 0);
    __builtin_amdgcn_s_setprio(0);

    asm volatile("s_waitcnt lgkmcnt(0)" ::: "memory");
    WAIT_VM();                       // kt+1 landed; kt+2 stays in flight
    __builtin_amdgcn_s_barrier();
#pragma unroll
    for (int i = 0; i < 4; ++i) af[i] = *(const bf16x8*)(&LA[nb][0] + rdA[i]);
#pragma unroll
    for (int j = 0; j < 4; ++j) bfr[j] = *(const bf16x8*)(&LB[nb][0] + rdB[j]);
  }
#undef STAGE
#undef WAIT_VM

  // epilogue: C/D layout col=lane&15, row=(lane>>4)*4+r
  const long row0 = brow + wm * 64 + ((lane >> 4) * 4);
  const long col0 = bcol + wn * 64 + (lane & 15);
#pragma unroll
  for (int m = 0; m < 4; ++m)
#pragma unroll
    for (int n = 0; n < 4; ++n)
#pragma unroll
      for (int r = 0; r < 4; ++r) {
        if constexpr (BF16OUT)
          ((unsigned short*)Cv)[(row0 + m * 16 + r) * (long)N + col0 + n * 16] = f2bf(acc[m][n][r]);
        else
          ((float*)Cv)[(row0 + m * 16 + r) * (long)N + col0 + n * 16] = acc[m][n][r];
      }
}

// ------------- conv(K=4)+SiLU+l2norm for q,k (bf16 out); conv+SiLU for v; scalars -------------
// Fat-block: 256 blocks x NBT=8 timesteps; weights hoisted to registers, 11-row window.
__global__ __launch_bounds__(256) void convnorm(
    const unsigned short* __restrict__ Y,
    const float* __restrict__ qcw, const float* __restrict__ kcw, const float* __restrict__ vcw,
    const float* __restrict__ A_log, const float* __restrict__ dt_bias,
    unsigned short* __restrict__ qb, unsigned short* __restrict__ kb,
    float* __restrict__ vb, float2* __restrict__ scb) {
  const int bt0 = blockIdx.x * NBT;
  const bool head = (bt0 & (T_LEN - 1)) == 0;   // first chunk of a sequence
  const int tid = threadIdx.x;

  // ---- q: channels 4*tid..+3 ----
  {
    const int c = tid * 4;
    float4 w[4];
#pragma unroll
    for (int e = 0; e < 4; ++e) w[e] = ((const float4*)qcw)[c + e];
    float rows[NBT + 3][4];
#pragma unroll
    for (int r = 0; r < NBT + 3; ++r) {
      if (head && r < 3) {
        rows[r][0] = rows[r][1] = rows[r][2] = rows[r][3] = 0.f;
      } else {
        const ushort4 x = *(const ushort4*)(Y + (size_t)(bt0 - 3 + r) * NBIG + c);
        rows[r][0] = bf2f(x.x); rows[r][1] = bf2f(x.y);
        rows[r][2] = bf2f(x.z); rows[r][3] = bf2f(x.w);
      }
    }
#pragma unroll
    for (int i = 0; i < NBT; ++i) {
      float acc[4], ss = 0.f;
#pragma unroll
      for (int e = 0; e < 4; ++e) {
        float a = w[e].x * rows[i][e];
        a = fmaf(w[e].y, rows[i + 1][e], a);
        a = fmaf(w[e].z, rows[i + 2][e], a);
        a = fmaf(w[e].w, rows[i + 3][e], a);
        a = silu_f(a);
        acc[e] = a;
        ss += a * a;
      }
#pragma unroll
      for (int m = 16; m >= 1; m >>= 1) ss += __shfl_xor(ss, m);
      const float rn = rsqrtf(ss + 1e-6f) * SCALE_Q;
      ushort4 o = {f2bf(acc[0] * rn), f2bf(acc[1] * rn), f2bf(acc[2] * rn), f2bf(acc[3] * rn)};
      *(ushort4*)(qb + (size_t)(bt0 + i) * 1024 + c) = o;
    }
  }
  // ---- k ----
  {
    const int c = tid * 4;
    float4 w[4];
#pragma unroll
    for (int e = 0; e < 4; ++e) w[e] = ((const float4*)kcw)[c + e];
    float rows[NBT + 3][4];
#pragma unroll
    for (int r = 0; r < NBT + 3; ++r) {
      if (head && r < 3) {
        rows[r][0] = rows[r][1] = rows[r][2] = rows[r][3] = 0.f;
      } else {
        const ushort4 x = *(const ushort4*)(Y + (size_t)(bt0 - 3 + r) * NBIG + 1024 + c);
        rows[r][0] = bf2f(x.x); rows[r][1] = bf2f(x.y);
        rows[r][2] = bf2f(x.z); rows[r][3] = bf2f(x.w);
      }
    }
#pragma unroll
    for (int i = 0; i < NBT; ++i) {
      float acc[4], ss = 0.f;
#pragma unroll
      for (int e = 0; e < 4; ++e) {
        float a = w[e].x * rows[i][e];
        a = fmaf(w[e].y, rows[i + 1][e], a);
        a = fmaf(w[e].z, rows[i + 2][e], a);
        a = fmaf(w[e].w, rows[i + 3][e], a);
        a = silu_f(a);
        acc[e] = a;
        ss += a * a;
      }
#pragma unroll
      for (int m = 16; m >= 1; m >>= 1) ss += __shfl_xor(ss, m);
      const float rn = rsqrtf(ss + 1e-6f);
      ushort4 o = {f2bf(acc[0] * rn), f2bf(acc[1] * rn), f2bf(acc[2] * rn), f2bf(acc[3] * rn)};
      *(ushort4*)(kb + (size_t)(bt0 + i) * 1024 + c) = o;
    }
  }
  // ---- v: two 4-channel halves (channels 8*tid..+7), fp32 out ----
#pragma unroll
  for (int half = 0; half < 2; ++half) {
    const int c2 = tid * 8 + half * 4;
    float4 w[4];
#pragma unroll
    for (int e = 0; e < 4; ++e) w[e] = ((const float4*)vcw)[c2 + e];
    float rows[NBT + 3][4];
#pragma unroll
    for (int r = 0; r < NBT + 3; ++r) {
      if (head && r < 3) {
        rows[r][0] = rows[r][1] = rows[r][2] = rows[r][3] = 0.f;
      } else {
        const ushort4 x = *(const ushort4*)(Y + (size_t)(bt0 - 3 + r) * NBIG + 2048 + c2);
        rows[r][0] = bf2f(x.x); rows[r][1] = bf2f(x.y);
        rows[r][2] = bf2f(x.z); rows[r][3] = bf2f(x.w);
      }
    }
#pragma unroll
    for (int i = 0; i < NBT; ++i) {
      float4 o;
      float a0 = w[0].x * rows[i][0];
      a0 = fmaf(w[0].y, rows[i + 1][0], a0); a0 = fmaf(w[0].z, rows[i + 2][0], a0);
      a0 = fmaf(w[0].w, rows[i + 3][0], a0); o.x = silu_f(a0);
      float a1 = w[1].x * rows[i][1];
      a1 = fmaf(w[1].y, rows[i + 1][1], a1); a1 = fmaf(w[1].z, rows[i + 2][1], a1);
      a1 = fmaf(w[1].w, rows[i + 3][1], a1); o.y = silu_f(a1);
      float a2 = w[2].x * rows[i][2];
      a2 = fmaf(w[2].y, rows[i + 1][2], a2); a2 = fmaf(w[2].z, rows[i + 2][2], a2);
      a2 = fmaf(w[2].w, rows[i + 3][2], a2); o.z = silu_f(a2);
      float a3 = w[3].x * rows[i][3];
      a3 = fmaf(w[3].y, rows[i + 1][3], a3); a3 = fmaf(w[3].z, rows[i + 2][3], a3);
      a3 = fmaf(w[3].w, rows[i + 3][3], a3); o.w = silu_f(a3);
      *(float4*)(vb + (size_t)(bt0 + i) * 2048 + c2) = o;
    }
  }
  // ---- per-step scalars: {g (log decay), beta} ----
  if (tid < 8) {
    const int hh = tid;
    const float Al = A_log[hh], db = dt_bias[hh];
#pragma unroll
    for (int i = 0; i < NBT; ++i) {
      const unsigned short* Yb = Y + (size_t)(bt0 + i) * NBIG;
      float a = bf2f(Yb[6144 + hh]) + db;
      float sp = (a > 20.f) ? a : log1pf(expf(a));
      float g = -expf(Al) * sp;
      float bp = bf2f(Yb[6152 + hh]);
      float be = 1.f / (1.f + expf(-bp));
      float2 o; o.x = g; o.y = be;
      scb[(size_t)(bt0 + i) * 8 + hh] = o;
    }
  }
}

// ---------------- small NT GEMM on LDS operands: OUT[i][j] = sum_k A[i][k]*B[j][k] ----------------
// A: [M][K] bf16 LDS, B: [N][K] bf16 LDS. NW waves. Output fp32 LDS (ld=N) or bf16 global (ldg).
template <int M, int N, int K, bool TOGLOB, int NW>
__device__ __forceinline__ void mm_nt_lds(const unsigned short* A, const unsigned short* B,
                                          float* outF, unsigned short* outG, int ldg, int tid) {
  constexpr int NT16 = N / 16;
  constexpr int PW = (M / 16) * NT16 / NW;
  const int w = tid >> 6, l = tid & 63;
  const int row = l & 15, ko = (l >> 4) * 8;
  f32x4 acc[PW];
#pragma unroll
  for (int i = 0; i < PW; ++i)
#pragma unroll
    for (int r = 0; r < 4; ++r) acc[i][r] = 0.f;
#pragma unroll
  for (int i = 0; i < PW; ++i) {
    const int ti = w + NW * i;
    const int rt = ti / NT16, ct = ti % NT16;
#pragma unroll
    for (int kk = 0; kk < K / 32; ++kk) {
      bf16x8 af = *(const bf16x8*)(A + (rt * 16 + row) * K + kk * 32 + ko);
      bf16x8 bf = *(const bf16x8*)(B + (ct * 16 + row) * K + kk * 32 + ko);
      acc[i] = __builtin_amdgcn_mfma_f32_16x16x32_bf16(af, bf, acc[i], 0, 0, 0);
    }
  }
#pragma unroll
  for (int i = 0; i < PW; ++i) {
    const int ti = w + NW * i;
    const int rt = ti / NT16, ct = ti % NT16;
    const int r0 = rt * 16 + (l >> 4) * 4;
    const int col = ct * 16 + (l & 15);
#pragma unroll
    for (int r = 0; r < 4; ++r) {
      if constexpr (TOGLOB) outG[(size_t)(r0 + r) * ldg + col] = f2bf(acc[i][r]);
      else                  outF[(r0 + r) * N + col] = acc[i][r];
    }
  }
}

// 64x64 NT MFMA accumulate (8 waves, 2 tiles/wave), epilogue left to caller
template <int K>
__device__ __forceinline__ void mm64_acc(const unsigned short* A, const unsigned short* B,
                                         f32x4 acc[2], int w, int row, int ko) {
#pragma unroll
  for (int i = 0; i < 2; ++i) {
    const int ti = w + 8 * i;
    const int rt = ti >> 2, ct = ti & 3;
#pragma unroll
    for (int kk = 0; kk < K / 32; ++kk) {
      bf16x8 af = *(const bf16x8*)(A + (rt * 16 + row) * K + kk * 32 + ko);
      bf16x8 bf = *(const bf16x8*)(B + (ct * 16 + row) * K + kk * 32 + ko);
      acc[i] = __builtin_amdgcn_mfma_f32_16x16x32_bf16(af, bf, acc[i], 0, 0, 0);
    }
  }
}

// ---------------- phase 1: per-chunk UT transform (chunk C=64), 512 threads ----------------
// per chunk-head ch = bh*16 + p: outputs W, Ub, Att, Qg, KgT, dec.
// Phase-fused: M/X0 built in A_raw epilogue; Newton = 2 phases/iter (transposed-write
// epilogue + ping-ponged X buffers, eliminating transpose passes); Att mask fused into
// QK^T epilogue. ~20 phases vs 35.
__global__ __launch_bounds__(512, 1) void chunk_prep(
    const unsigned short* __restrict__ qb, const unsigned short* __restrict__ kb,
    const float* __restrict__ vb, const float2* __restrict__ scb,
    unsigned short* __restrict__ Wg, unsigned short* __restrict__ Ubg,
    unsigned short* __restrict__ Attg, unsigned short* __restrict__ Qgg,
    unsigned short* __restrict__ KgTg, float* __restrict__ decg) {
  __shared__ unsigned short Kb_s[64 * 128];
  __shared__ unsigned short Qb_s[64 * 128];     // later reused as KbgT [128][64]
  __shared__ unsigned short VbT_s[256 * 64];    // beta*V transposed
  __shared__ unsigned short Mb_s[4096];         // I + A (bf16)
  __shared__ unsigned short Xrow_s[2][4096];    // X row-major bf16 (ping-pong)
  __shared__ unsigned short Xt_s[2][4096];      // X^T bf16 (ping-pong)
  __shared__ unsigned short Yt_s[4096];         // (M X)^T bf16
  __shared__ float F1_s[4096];                  // X fp32
  __shared__ float carr_s[64];
  __shared__ float beta_s[64];

  const int tid = threadIdx.x;
  const int w = tid >> 6, l = tid & 63;
  const int row16 = l & 15, ko = (l >> 4) * 8;
  const int ch = blockIdx.x;
  const int bh = ch >> 4, p = ch & 15;
  const int b = bh >> 3, h = bh & 7;
  const size_t tbase = (size_t)b * T_LEN + p * 64;

  // 1. per-step scalars + cumulative log-decay (inclusive scan over 64 lanes of wave 0)
  if (tid < 64) {
    float2 gb = scb[(tbase + tid) * 8 + h];
    float c = gb.x;
#pragma unroll
    for (int d = 1; d < 64; d <<= 1) {
      float y = __shfl_up(c, d);
      if (tid >= d) c += y;
    }
    carr_s[tid] = c;
    beta_s[tid] = gb.y;
    if (tid == 63) decg[ch] = __expf(c);
  }
  // 2. stage K, Q chunks (bf16) via global_load_lds
#pragma unroll
  for (int i = 0; i < 2; ++i) {
    const int f = i * 512 + tid;
    const int t = f >> 4, c8 = f & 15;
    GLDS(kb + (tbase + t) * 1024 + h * 128 + c8 * 8, (char*)Kb_s + f * 16);
    GLDS(qb + (tbase + t) * 1024 + h * 128 + c8 * 8, (char*)Qb_s + f * 16);
  }
  __syncthreads();   // staging drained; carr/beta visible
  // 3. VbT[v][t] = bf16(beta_t * v[t][v])  (read later by Ub mm; no barrier needed here)
#pragma unroll
  for (int i = 0; i < 8; ++i) {
    const int m = i * 512 + tid;
    const int t = m >> 6, c4 = (m & 63) * 4;
    float4 v = *(const float4*)(vb + (tbase + t) * 2048 + h * 256 + c4);
    const float bt = beta_s[t];
    VbT_s[(c4 + 0) * 64 + t] = f2bf(bt * v.x);
    VbT_s[(c4 + 1) * 64 + t] = f2bf(bt * v.y);
    VbT_s[(c4 + 2) * 64 + t] = f2bf(bt * v.z);
    VbT_s[(c4 + 3) * 64 + t] = f2bf(bt * v.w);
  }
  // 4+5 fused: A_raw = K K^T; epilogue builds M = I+A, X0 = I-A (F1, Xrow0, Xt0)
  {
    f32x4 acc[2];
#pragma unroll
    for (int i = 0; i < 2; ++i)
#pragma unroll
      for (int r = 0; r < 4; ++r) acc[i][r] = 0.f;
    mm64_acc<128>(Kb_s, Kb_s, acc, w, row16, ko);
#pragma unroll
    for (int i = 0; i < 2; ++i) {
      const int ti = w + 8 * i;
      const int rt = ti >> 2, ct = ti & 3;
      const int r0 = rt * 16 + (l >> 4) * 4;
      const int col = ct * 16 + (l & 15);
#pragma unroll
      for (int r = 0; r < 4; ++r) {
        const int t = r0 + r, j = col;
        const float av = (j < t) ? beta_s[t] * __expf(carr_s[t] - carr_s[j]) * acc[i][r] : 0.f;
        const float dg = (t == j) ? 1.f : 0.f;
        Mb_s[t * 64 + j] = f2bf(dg + av);
        const float x0 = dg - av;
        F1_s[t * 64 + j] = x0;
        const unsigned short xb = f2bf(x0);
        Xrow_s[0][t * 64 + j] = xb;
        Xt_s[0][j * 64 + t] = xb;
      }
    }
  }
  __syncthreads();
  // 6. Newton x5: X <- X(2I - M X), 2 phases/iter, ping-pong X (exact: A nilpotent)
  int cur = 0;
  for (int it = 0; it < 5; ++it) {
    {  // Yt = (M X)^T  (transposed-write epilogue)
      f32x4 acc[2];
#pragma unroll
      for (int i = 0; i < 2; ++i)
#pragma unroll
        for (int r = 0; r < 4; ++r) acc[i][r] = 0.f;
      mm64_acc<64>(Mb_s, Xt_s[cur], acc, w, row16, ko);
#pragma unroll
      for (int i = 0; i < 2; ++i) {
        const int ti = w + 8 * i;
        const int rt = ti >> 2, ct = ti & 3;
        const int r0 = rt * 16 + (l >> 4) * 4;
        const int col = ct * 16 + (l & 15);
#pragma unroll
        for (int r = 0; r < 4; ++r)
          Yt_s[col * 64 + (r0 + r)] = f2bf(acc[i][r]);
      }
    }
    __syncthreads();
    {  // P = X Y ; X' = 2*F1 - P  -> buffers cur^1 (no read/write overlap)
      f32x4 acc[2];
#pragma unroll
      for (int i = 0; i < 2; ++i)
#pragma unroll
        for (int r = 0; r < 4; ++r) acc[i][r] = 0.f;
      mm64_acc<64>(Xrow_s[cur], Yt_s, acc, w, row16, ko);
#pragma unroll
      for (int i = 0; i < 2; ++i) {
        const int ti = w + 8 * i;
        const int rt = ti >> 2, ct = ti & 3;
        const int r0 = rt * 16 + (l >> 4) * 4;
        const int col = ct * 16 + (l & 15);
#pragma unroll
        for (int r = 0; r < 4; ++r) {
          const int idx = (r0 + r) * 64 + col;
          const float xn = 2.f * F1_s[idx] - acc[i][r];
          F1_s[idx] = xn;
          const unsigned short xb = f2bf(xn);
          Xrow_s[cur ^ 1][idx] = xb;
          Xt_s[cur ^ 1][col * 64 + (r0 + r)] = xb;
        }
      }
    }
    cur ^= 1;
    __syncthreads();
  }
  const unsigned short* Xfin = Xrow_s[cur];
  const float ctot = carr_s[63];
  // 7+8 fused: Att = mask(exp) o (Q K^T) -> global directly
  {
    f32x4 acc[2];
#pragma unroll
    for (int i = 0; i < 2; ++i)
#pragma unroll
      for (int r = 0; r < 4; ++r) acc[i][r] = 0.f;
    mm64_acc<128>(Qb_s, Kb_s, acc, w, row16, ko);
#pragma unroll
    for (int i = 0; i < 2; ++i) {
      const int ti = w + 8 * i;
      const int rt = ti >> 2, ct = ti & 3;
      const int r0 = rt * 16 + (l >> 4) * 4;
      const int col = ct * 16 + (l & 15);
#pragma unroll
      for (int r = 0; r < 4; ++r) {
        const int t = r0 + r, j = col;
        const float av = (j <= t) ? __expf(carr_s[t] - carr_s[j]) * acc[i][r] : 0.f;
        Attg[(size_t)ch * 4096 + t * 64 + j] = f2bf(av);
      }
    }
  }
  // Qg, KgT -> global (elementwise from Qb/Kb)
#pragma unroll
  for (int i = 0; i < 16; ++i) {
    const int idx = i * 512 + tid;
    const int t = idx >> 7;
    Qgg[(size_t)ch * 8192 + idx] = f2bf(__expf(carr_s[t]) * bf2f(Qb_s[idx]));
  }
#pragma unroll
  for (int i = 0; i < 16; ++i) {
    const int idx = i * 512 + tid;
    const int d = idx >> 6, t = idx & 63;
    KgTg[(size_t)ch * 8192 + idx] = f2bf(__expf(ctot - carr_s[t]) * bf2f(Kb_s[t * 128 + d]));
  }
  __syncthreads();   // Qb reads done before reuse
  // 9. KbgT[d][t] = bf16(beta_t exp(c_t) k[t][d])  (into Qb space)
  unsigned short* KbgT = Qb_s;
#pragma unroll
  for (int i = 0; i < 16; ++i) {
    const int idx = i * 512 + tid;
    const int d = idx >> 6, t = idx & 63;
    KbgT[idx] = f2bf(beta_s[t] * __expf(carr_s[t]) * bf2f(Kb_s[t * 128 + d]));
  }
  __syncthreads();
  // 10. W = T (betaG.K)  [64x128];  Ub = T (betaV)  [64x256]  -> global bf16
  mm_nt_lds<64, 128, 64, true, 8>(Xfin, KbgT, nullptr, Wg + (size_t)ch * 8192, 128, tid);
  mm_nt_lds<64, 256, 64, true, 8>(Xfin, VbT_s, nullptr, Ubg + (size_t)ch * 16384, 256, tid);
}

// ---------------- phase 2: serial chunk recurrence (MFMA), 16 bh x 8 v-blocks, 512 thr ----------------
// stage buffer (ushort offsets): W@0(8192) Att@8192(4096) Qg@12288(8192) KgT@20480(8192) Ub@28672(2048)
__device__ __forceinline__ void p2_stage(
    const unsigned short* Wg, const unsigned short* Attg, const unsigned short* Qgg,
    const unsigned short* KgTg, const unsigned short* Ubg,
    int ch, int vb, unsigned short* buf, int tid) {
#pragma unroll
  for (int i = 0; i < 2; ++i) {
    const int f = i * 512 + tid;
    GLDS(Wg + (size_t)ch * 8192 + f * 8, (char*)buf + f * 16);
  }
  {
    const int f = tid;
    GLDS(Attg + (size_t)ch * 4096 + f * 8, (char*)(buf + 8192) + f * 16);
  }
#pragma unroll
  for (int i = 0; i < 2; ++i) {
    const int f = i * 512 + tid;
    GLDS(Qgg + (size_t)ch * 8192 + f * 8, (char*)(buf + 12288) + f * 16);
  }
#pragma unroll
  for (int i = 0; i < 2; ++i) {
    const int f = i * 512 + tid;
    GLDS(KgTg + (size_t)ch * 8192 + f * 8, (char*)(buf + 20480) + f * 16);
  }
  if (tid < 256) {
    const int f = tid;
    const int t = f >> 2, c8 = f & 3;
    GLDS(Ubg + (size_t)ch * 16384 + t * 256 + vb * 32 + c8 * 8, (char*)(buf + 28672) + f * 16);
  }
}

__global__ __launch_bounds__(512, 1) void scan_chunks(
    const unsigned short* __restrict__ Wg, const unsigned short* __restrict__ Ubg,
    const unsigned short* __restrict__ Attg, const unsigned short* __restrict__ Qgg,
    const unsigned short* __restrict__ KgTg, const float* __restrict__ decg,
    float* __restrict__ osc) {
  __shared__ float StT_s[32 * 128];            // S^T fp32 [vcol][d]
  __shared__ unsigned short StTb_s[32 * 128];  // S^T bf16
  __shared__ unsigned short uT_s[32 * 64];     // u^T bf16 [vcol][t]
  __shared__ unsigned short stage_s[2][30720];

  const int tid = threadIdx.x;
  const int w = tid >> 6, l = tid & 63;
  const int row = l & 15, ko = (l >> 4) * 8;
  const int blk = blockIdx.x;                  // vb*16 + bh  (same-bh blocks share an XCD)
  const int vb = blk >> 4, bh = blk & 15;
  const int b = bh >> 3, h = bh & 7;

  for (int i = tid; i < 4096; i += 512) { StT_s[i] = 0.f; StTb_s[i] = 0; }
  p2_stage(Wg, Attg, Qgg, KgTg, Ubg, bh * 16, vb, stage_s[0], tid);

  for (int p = 0; p < 16; ++p) {
    unsigned short* bufc = stage_s[p & 1];
    const unsigned short* Wl   = bufc;
    const unsigned short* Attl = bufc + 8192;
    const unsigned short* Qgl  = bufc + 12288;
    const unsigned short* KgTl = bufc + 20480;
    const unsigned short* Ubl  = bufc + 28672;
    __syncthreads();   // staged buf + previous S writes visible (vmcnt drained)

    // ---- u = Ub - W S : acc [64x32], 8 tiles, 1/wave ----
    f32x4 uacc;
#pragma unroll
    for (int r = 0; r < 4; ++r) uacc[r] = 0.f;
    const int rt = w >> 1, ct = w & 1;
#pragma unroll
    for (int kk = 0; kk < 4; ++kk) {
      bf16x8 af = *(const bf16x8*)(Wl + (rt * 16 + row) * 128 + kk * 32 + ko);
      bf16x8 bf = *(const bf16x8*)(StTb_s + (ct * 16 + row) * 128 + kk * 32 + ko);
      uacc = __builtin_amdgcn_mfma_f32_16x16x32_bf16(af, bf, uacc, 0, 0, 0);
    }
    {
      const int r0 = rt * 16 + (l >> 4) * 4;
      const int col = ct * 16 + (l & 15);
#pragma unroll
      for (int r = 0; r < 4; ++r) {
        const int t = r0 + r;
        const float ubv = bf2f(Ubl[t * 32 + col]);
        uT_s[col * 64 + t] = f2bf(ubv - uacc[r]);
      }
    }
    __syncthreads();   // uT ready
    if (p < 15)
      p2_stage(Wg, Attg, Qgg, KgTg, Ubg, bh * 16 + p + 1, vb, stage_s[(p + 1) & 1], tid);

    // ---- O = Qg S + Att u : acc [64x32], 1 tile/wave ----
    f32x4 oacc;
#pragma unroll
    for (int r = 0; r < 4; ++r) oacc[r] = 0.f;
#pragma unroll
    for (int kk = 0; kk < 4; ++kk) {
      bf16x8 af = *(const bf16x8*)(Qgl + (rt * 16 + row) * 128 + kk * 32 + ko);
      bf16x8 bf = *(const bf16x8*)(StTb_s + (ct * 16 + row) * 128 + kk * 32 + ko);
      oacc = __builtin_amdgcn_mfma_f32_16x16x32_bf16(af, bf, oacc, 0, 0, 0);
    }
#pragma unroll
    for (int kk = 0; kk < 2; ++kk) {
      bf16x8 af = *(const bf16x8*)(Attl + (rt * 16 + row) * 64 + kk * 32 + ko);
      bf16x8 bf = *(const bf16x8*)(uT_s + (ct * 16 + row) * 64 + kk * 32 + ko);
      oacc = __builtin_amdgcn_mfma_f32_16x16x32_bf16(af, bf, oacc, 0, 0, 0);
    }
    // ---- Snew^T = dec*S^T + (u^T)(KgT^T) : acc [32x128], 16 tiles, 2/wave ----
    f32x4 sacc[2];
#pragma unroll
    for (int i = 0; i < 2; ++i)
#pragma unroll
      for (int r = 0; r < 4; ++r) sacc[i][r] = 0.f;
#pragma unroll
    for (int i = 0; i < 2; ++i) {
      const int ti = w + 8 * i;
      const int srt = ti >> 3, sct = ti & 7;
#pragma unroll
      for (int kk = 0; kk < 2; ++kk) {
        bf16x8 af = *(const bf16x8*)(uT_s + (srt * 16 + row) * 64 + kk * 32 + ko);
        bf16x8 bf = *(const bf16x8*)(KgTl + (sct * 16 + row) * 64 + kk * 32 + ko);
        sacc[i] = __builtin_amdgcn_mfma_f32_16x16x32_bf16(af, bf, sacc[i], 0, 0, 0);
      }
    }
    const float dec = decg[bh * 16 + p];
    __syncthreads();   // all reads of StT/StTb done before overwrite

    // epilogues
    {
      const int r0 = rt * 16 + (l >> 4) * 4;
      const int col = ct * 16 + (l & 15);
#pragma unroll
      for (int r = 0; r < 4; ++r) {
        const size_t trow = (size_t)b * T_LEN + p * 64 + r0 + r;
        osc[(trow * 8 + h) * 256 + vb * 32 + col] = oacc[r];
      }
    }
#pragma unroll
    for (int i = 0; i < 2; ++i) {
      const int ti = w + 8 * i;
      const int srt = ti >> 3, sct = ti & 7;
      const int r0 = srt * 16 + (l >> 4) * 4;
      const int cold = sct * 16 + (l & 15);
#pragma unroll
      for (int r = 0; r < 4; ++r) {
        const int idx = (r0 + r) * 128 + cold;
        const float sn = fmaf(dec, StT_s[idx], sacc[i][r]);
        StT_s[idx] = sn;
        StTb_s[idx] = f2bf(sn);
      }
    }
  }
}

// ---------------- gated RMSNorm + silu(gate) -> bf16 ----------------
__global__ __launch_bounds__(256) void rmsgate(
    const float* __restrict__ ob, const unsigned short* __restrict__ Y,
    const float* __restrict__ onw, unsigned short* __restrict__ Obf) {
  const int bt = blockIdx.x;
  const int tid = threadIdx.x;
  const int c = tid * 8;                // head = c/256 = tid/32
  const float* orow = ob + (size_t)bt * 2048 + c;
  const unsigned short* grow = Y + (size_t)bt * NBIG + 4096 + c;
  const float4 o0 = *(const float4*)orow, o1 = *(const float4*)(orow + 4);
  const ushort4 g0 = *(const ushort4*)grow, g1 = *(const ushort4*)(grow + 4);
  const float ov[8] = {o0.x, o0.y, o0.z, o0.w, o1.x, o1.y, o1.z, o1.w};
  const float gv[8] = {bf2f(g0.x), bf2f(g0.y), bf2f(g0.z), bf2f(g0.w),
                       bf2f(g1.x), bf2f(g1.y), bf2f(g1.z), bf2f(g1.w)};
  float ss = 0.f;
#pragma unroll
  for (int e = 0; e < 8; ++e) ss += ov[e] * ov[e];
#pragma unroll
  for (int m = 16; m >= 1; m >>= 1) ss += __shfl_xor(ss, m);
  const float rn = rsqrtf(ss * (1.f / 256.f) + 1e-5f);
  const int dv = c & 255;
  unsigned short rr[8];
#pragma unroll
  for (int e = 0; e < 8; ++e) {
    const float val = ov[e] * rn * onw[dv + e] * silu_f(gv[e]);
    rr[e] = f2bf(val);
  }
  ushort4 r0 = {rr[0], rr[1], rr[2], rr[3]};
  ushort4 r1 = {rr[4], rr[5], rr[6], rr[7]};
  *(ushort4*)(Obf + (size_t)bt * 2048 + c) = r0;
  *(ushort4*)(Obf + (size_t)bt * 2048 + c + 4) = r1;
}

extern "C" void kernel_launch(void* const* d_in, const int* in_sizes, int n_in,
                              void* d_out, int out_size, void* d_ws, size_t ws_size,
                              hipStream_t stream) {
  (void)in_sizes; (void)n_in; (void)out_size; (void)ws_size;
  const float* h    = (const float*)d_in[0];
  const float* qw   = (const float*)d_in[1];
  const float* kw   = (const float*)d_in[2];
  const float* vw   = (const float*)d_in[3];
  const float* aw   = (const float*)d_in[4];
  const float* bw   = (const float*)d_in[5];
  const float* gw   = (const float*)d_in[6];
  const float* ow   = (const float*)d_in[7];
  const float* qcw  = (const float*)d_in[8];
  const float* kcw  = (const float*)d_in[9];
  const float* vcw  = (const float*)d_in[10];
  const float* Alog = (const float*)d_in[11];
  const float* dtb  = (const float*)d_in[12];
  const float* onw  = (const float*)d_in[13];

  char* ws = (char*)d_ws;
  size_t off = 0;
  auto alloc = [&](size_t bytes) {
    char* p = ws + off;
    off = (off + bytes + 255) & ~(size_t)255;
    return p;
  };
  unsigned short* qb   = (unsigned short*)alloc(2048ull * 1024 * 2);
  unsigned short* kb   = (unsigned short*)alloc(2048ull * 1024 * 2);
  float* vb            = (float*)alloc(2048ull * 2048 * 4);
  float2* scb          = (float2*)alloc(2048ull * 8 * 8);
  unsigned short* hbf  = (unsigned short*)alloc(2048ull * 2048 * 2);
  unsigned short* Wb   = (unsigned short*)alloc((size_t)NBIG * 2048 * 2);
  unsigned short* owb  = (unsigned short*)alloc(2048ull * 2048 * 2);
  unsigned short* Ybf  = (unsigned short*)alloc(2048ull * NBIG * 2);
  float* osc           = (float*)alloc(2048ull * 2048 * 4);
  unsigned short* Obf  = (unsigned short*)alloc(2048ull * 2048 * 2);
  unsigned short* Wg   = (unsigned short*)alloc(256ull * 8192 * 2);
  unsigned short* Ubg  = (unsigned short*)alloc(256ull * 16384 * 2);
  unsigned short* Attg = (unsigned short*)alloc(256ull * 4096 * 2);
  unsigned short* Qgg  = (unsigned short*)alloc(256ull * 8192 * 2);
  unsigned short* KgTg = (unsigned short*)alloc(256ull * 8192 * 2);
  float* decg          = (float*)alloc(256ull * 4);

  cvt_bf16<<<4096, 256, 0, stream>>>(h, hbf, 1048576);
  build_w<<<12800, 256, 0, stream>>>(qw, kw, vw, gw, aw, bw, Wb);
  cvt_bf16<<<4096, 256, 0, stream>>>(ow, owb, 1048576);
  // GEMM1: 16 x 50 tiles of 128x128 -> 800 blocks, 3 blocks/CU (balanced)
  gemm_pipe<128, 2, 256, true><<<800, 256, 0, stream>>>(
      (const bf16*)hbf, (const bf16*)Wb, Ybf, NBIG, 2048);
  convnorm<<<256, 256, 0, stream>>>(Ybf, qcw, kcw, vcw, Alog, dtb, qb, kb, vb, scb);
  chunk_prep<<<256, 512, 0, stream>>>(qb, kb, vb, scb, Wg, Ubg, Attg, Qgg, KgTg, decg);
  scan_chunks<<<128, 512, 0, stream>>>(Wg, Ubg, Attg, Qgg, KgTg, decg, osc);
  rmsgate<<<2048, 256, 0, stream>>>(osc, Ybf, onw, Obf);
  // GEMM2: 16 x 16 tiles of 128x128 -> 256 blocks
  gemm_pipe<128, 2, 256, false><<<256, 256, 0, stream>>>(
      (const bf16*)Obf, (const bf16*)owb, d_out, 2048, 2048);
}

// Round 12
// 225.527 us; speedup vs baseline: 1.1905x; 1.1905x over previous
//
#include <hip/hip_runtime.h>
#include <cstdint>

#define T_LEN 1024
#define NBIG  6400     // padded N for fused projection GEMM (6160 real cols, 25 x 256 tiles)
#define SCALE_Q 0.08838834764831843f   // DK^-0.5

typedef __bf16 bf16;
typedef __bf16 bf16x8 __attribute__((ext_vector_type(8)));
typedef float  f32x4  __attribute__((ext_vector_type(4)));

__device__ __forceinline__ unsigned short f2bf(float f) {
  unsigned int u = __builtin_bit_cast(unsigned int, f);
  u += 0x7FFFu + ((u >> 16) & 1u);          // RNE
  return (unsigned short)(u >> 16);
}
__device__ __forceinline__ float bf2f(unsigned short u) {
  return __builtin_bit_cast(float, (unsigned int)u << 16);
}
__device__ __forceinline__ float silu_f(float x) { return x / (1.f + __expf(-x)); }

#define GLDS(src, dst) \
  __builtin_amdgcn_global_load_lds( \
      (__attribute__((address_space(1))) void*)(void*)(src), \
      (__attribute__((address_space(3))) void*)(void*)(dst), 16, 0, 0)

// ---------------- fp32 -> bf16 conversion (4 elems/thread) ----------------
__global__ __launch_bounds__(256) void cvt_bf16(const float* __restrict__ in,
                                                unsigned short* __restrict__ out, int n4) {
  int idx = blockIdx.x * 256 + threadIdx.x;
  if (idx >= n4) return;
  float4 f = ((const float4*)in)[idx];
  ushort4 o = { f2bf(f.x), f2bf(f.y), f2bf(f.z), f2bf(f.w) };
  ((ushort4*)out)[idx] = o;
}

// ------------- build concatenated weight matrix W[NBIG][2048] bf16 -------------
__global__ __launch_bounds__(256) void build_w(
    const float* __restrict__ qw, const float* __restrict__ kw,
    const float* __restrict__ vw, const float* __restrict__ gw,
    const float* __restrict__ aw, const float* __restrict__ bw,
    unsigned short* __restrict__ W) {
  int idx = blockIdx.x * 256 + threadIdx.x;   // quad id, exact grid
  int r = idx >> 9;                           // row (2048/4 = 512 quads per row)
  int c = (idx & 511) << 2;
  const float* src;
  if      (r < 1024) src = qw + (size_t)r * 2048;
  else if (r < 2048) src = kw + (size_t)(r - 1024) * 2048;
  else if (r < 4096) src = vw + (size_t)(r - 2048) * 2048;
  else if (r < 6144) src = gw + (size_t)(r - 4096) * 2048;
  else if (r < 6152) src = aw + (size_t)(r - 6144) * 2048;
  else if (r < 6160) src = bw + (size_t)(r - 6152) * 2048;
  else               src = nullptr;
  ushort4 o;
  if (src) {
    float4 f = *(const float4*)(src + c);
    o = { f2bf(f.x), f2bf(f.y), f2bf(f.z), f2bf(f.w) };
  } else {
    o = { 0, 0, 0, 0 };
  }
  *(ushort4*)(W + (size_t)r * 2048 + c) = o;
}

// ============ pipelined NT GEMM: BM=128 x BN tile, BK=32, ring-3 LDS, counted vmcnt ============
// C[M][N] = A[M][K] * B[N][K]^T, bf16 in. T threads = T/64 waves (2 x WN), wave tile 64x64.
// R6-proven schedule: per K-step { STAGE(kt+2); setprio(1); 16 MFMA; setprio(0);
// lgkmcnt(0); vmcnt(LOADS); s_barrier; ds_read next frags }. vmcnt never drains to 0.
// WAR: stage slot (kt+2)%3 == (kt-1)%3, whose reads completed before the previous barrier.
// LDS swizzle (0-conflict, R4-verified): logical k-slot s of row r at phys s ^ ((r>>1)&3).
// Requires M = 2048 (16 M-tiles) for the XCD-chunked block map.
template <int BN, int WN, int T, bool BF16OUT>
__global__ __launch_bounds__(T, 4) void gemm_pipe(
    const bf16* __restrict__ A, const bf16* __restrict__ Bm,
    void* __restrict__ Cv, int N, int K) {
  constexpr int AI = (128 * 32) / (T * 8);   // A glds insts/thread per K-tile
  constexpr int BI = (BN * 32) / (T * 8);    // B glds insts/thread per K-tile
  constexpr int LOADS = AI + BI;
  __shared__ bf16 LA[3][128 * 32];
  __shared__ bf16 LB[3][BN * 32];
  const int tid = threadIdx.x;
  const int lane = tid & 63;
  const int wid = tid >> 6;
  const int wm = wid / WN, wn = wid % WN;
  // XCD-chunked bijective block map: xcd owns m-rows {xcd, xcd+8} x all n-tiles
  const int bid = blockIdx.x;
  const int xcd = bid & 7, jj = bid >> 3;
  const long brow = (long)(xcd + 8 * (jj & 1)) * 128;
  const long bcol = (long)(jj >> 1) * BN;

  f32x4 acc[4][4];
#pragma unroll
  for (int m = 0; m < 4; ++m)
#pragma unroll
    for (int n = 0; n < 4; ++n)
#pragma unroll
      for (int r = 0; r < 4; ++r) acc[m][n][r] = 0.f;

  // staging map: flat slot = e*T + tid -> (row = flat>>2, pslot = flat&3);
  // global source col = (pslot ^ ((row>>1)&3)) * 8  (inverse swizzle, linear LDS dest)
  const bf16* AgS[AI];
  const bf16* BgS[BI];
  int adst[AI], bdst[BI];
#pragma unroll
  for (int e = 0; e < AI; ++e) {
    const int flat = e * T + tid;
    const int row = flat >> 2;
    const int sl = (flat & 3) ^ ((row >> 1) & 3);
    AgS[e] = A + (brow + row) * (long)K + sl * 8;
    adst[e] = flat * 8;
  }
#pragma unroll
  for (int e = 0; e < BI; ++e) {
    const int flat = e * T + tid;
    const int row = flat >> 2;
    const int sl = (flat & 3) ^ ((row >> 1) & 3);
    BgS[e] = Bm + (bcol + row) * (long)K + sl * 8;
    bdst[e] = flat * 8;
  }

#define STAGE(kt, sb)                                              \
  {                                                                \
    const long ko = (long)(kt) * 32;                               \
    _Pragma("unroll")                                              \
    for (int e = 0; e < AI; ++e) GLDS(AgS[e] + ko, &LA[sb][0] + adst[e]); \
    _Pragma("unroll")                                              \
    for (int e = 0; e < BI; ++e) GLDS(BgS[e] + ko, &LB[sb][0] + bdst[e]); \
  }
#define WAIT_VM()                                                  \
  if constexpr (LOADS == 3) asm volatile("s_waitcnt vmcnt(3)" ::: "memory"); \
  else                      asm volatile("s_waitcnt vmcnt(4)" ::: "memory");

  // read offsets (halfwords): row*32 + (ks ^ ((r16>>1)&3))*8
  const int r16 = lane & 15;
  const int ks = lane >> 4;
  const int pso = (ks ^ ((r16 >> 1) & 3)) * 8;
  int rdA[4], rdB[4];
#pragma unroll
  for (int i = 0; i < 4; ++i) rdA[i] = (wm * 64 + i * 16 + r16) * 32 + pso;
#pragma unroll
  for (int j = 0; j < 4; ++j) rdB[j] = (wn * 64 + j * 16 + r16) * 32 + pso;

  const int nkt = K >> 5;
  STAGE(0, 0);
  STAGE(1, 1);
  WAIT_VM();                         // buf0 landed (stage(1) may stay in flight)
  __builtin_amdgcn_s_barrier();

  bf16x8 af[4], bfr[4];
#pragma unroll
  for (int i = 0; i < 4; ++i) af[i] = *(const bf16x8*)(&LA[0][0] + rdA[i]);
#pragma unroll
  for (int j = 0; j < 4; ++j) bfr[j] = *(const bf16x8*)(&LB[0][0] + rdB[j]);

  for (int kt = 0; kt < nkt; ++kt) {
    const int kts = (kt + 2 < nkt) ? kt + 2 : nkt - 1;  // clamp src, keep count uniform
    const int sb = (kt + 2) % 3;                        // == (kt-1)%3: read-complete slot
    const int nb = (kt + 1) % 3;

    STAGE(kts, sb);
    __builtin_amdgcn_s_setprio(1);
#pragma unroll
    for (int i = 0; i < 4; ++i)
#pragma unroll
      for (int j = 0; j < 4; ++j)
        acc[i][j] = __builtin_amdgcn_mfma_f32_16x16x32_bf16(af[i], bfr[j], acc[i][j], 0, 0, 0);
    __builtin_amdgcn_s_setprio(0);

    asm volatile("s_waitcnt lgkmcnt(0)" ::: "memory");
    WAIT_VM();                       // kt+1 landed; kt+2 stays in flight
    __builtin_amdgcn_s_barrier();
#pragma unroll
    for (int i = 0; i < 4; ++i) af[i] = *(const bf16x8*)(&LA[nb][0] + rdA[i]);
#pragma unroll
    for (int j = 0; j < 4; ++j) bfr[j] = *(const bf16x8*)(&LB[nb][0] + rdB[j]);
  }
#undef STAGE
#undef WAIT_VM

  // epilogue: C/D layout col=lane&15, row=(lane>>4)*4+r
  const long row0 = brow + wm * 64 + ((lane >> 4) * 4);
  const long col0 = bcol + wn * 64 + (lane & 15);
#pragma unroll
  for (int m = 0; m < 4; ++m)
#pragma unroll
    for (int n = 0; n < 4; ++n)
#pragma unroll
      for (int r = 0; r < 4; ++r) {
        if constexpr (BF16OUT)
          ((unsigned short*)Cv)[(row0 + m * 16 + r) * (long)N + col0 + n * 16] = f2bf(acc[m][n][r]);
        else
          ((float*)Cv)[(row0 + m * 16 + r) * (long)N + col0 + n * 16] = acc[m][n][r];
      }
}

// ---------------- small NT GEMM on LDS operands: OUT[i][j] = sum_k A[i][k]*B[j][k] ----------------
// A: [M][K] bf16 LDS, B: [N][K] bf16 LDS. NW waves. Output fp32 LDS (ld=N) or bf16 global (ldg).
template <int M, int N, int K, bool TOGLOB, int NW>
__device__ __forceinline__ void mm_nt_lds(const unsigned short* A, const unsigned short* B,
                                          float* outF, unsigned short* outG, int ldg, int tid) {
  constexpr int NT16 = N / 16;
  constexpr int PW = (M / 16) * NT16 / NW;
  const int w = tid >> 6, l = tid & 63;
  const int row = l & 15, ko = (l >> 4) * 8;
  f32x4 acc[PW];
#pragma unroll
  for (int i = 0; i < PW; ++i)
#pragma unroll
    for (int r = 0; r < 4; ++r) acc[i][r] = 0.f;
#pragma unroll
  for (int i = 0; i < PW; ++i) {
    const int ti = w + NW * i;
    const int rt = ti / NT16, ct = ti % NT16;
#pragma unroll
    for (int kk = 0; kk < K / 32; ++kk) {
      bf16x8 af = *(const bf16x8*)(A + (rt * 16 + row) * K + kk * 32 + ko);
      bf16x8 bf = *(const bf16x8*)(B + (ct * 16 + row) * K + kk * 32 + ko);
      acc[i] = __builtin_amdgcn_mfma_f32_16x16x32_bf16(af, bf, acc[i], 0, 0, 0);
    }
  }
#pragma unroll
  for (int i = 0; i < PW; ++i) {
    const int ti = w + NW * i;
    const int rt = ti / NT16, ct = ti % NT16;
    const int r0 = rt * 16 + (l >> 4) * 4;
    const int col = ct * 16 + (l & 15);
#pragma unroll
    for (int r = 0; r < 4; ++r) {
      if constexpr (TOGLOB) outG[(size_t)(r0 + r) * ldg + col] = f2bf(acc[i][r]);
      else                  outF[(r0 + r) * N + col] = acc[i][r];
    }
  }
}

// 64x64 NT MFMA accumulate (8 waves, 2 tiles/wave), epilogue left to caller
template <int K>
__device__ __forceinline__ void mm64_acc(const unsigned short* A, const unsigned short* B,
                                         f32x4 acc[2], int w, int row, int ko) {
#pragma unroll
  for (int i = 0; i < 2; ++i) {
    const int ti = w + 8 * i;
    const int rt = ti >> 2, ct = ti & 3;
#pragma unroll
    for (int kk = 0; kk < K / 32; ++kk) {
      bf16x8 af = *(const bf16x8*)(A + (rt * 16 + row) * K + kk * 32 + ko);
      bf16x8 bf = *(const bf16x8*)(B + (ct * 16 + row) * K + kk * 32 + ko);
      acc[i] = __builtin_amdgcn_mfma_f32_16x16x32_bf16(af, bf, acc[i], 0, 0, 0);
    }
  }
}

// ---------------- phase 1: conv+norm fused + per-chunk UT transform (C=64), 512 threads ----------------
// Each block owns (bh, p): computes conv(K=4)+SiLU(+l2norm) for q,k,v of its head-slice
// directly from Y (convnorm kernel eliminated), then the UT transform.
// Outputs per chunk-head ch = bh*16 + p: W, Ub, Att, Qg, KgT, dec.
__global__ __launch_bounds__(512, 1) void chunk_prep(
    const unsigned short* __restrict__ Y,
    const float* __restrict__ qcw, const float* __restrict__ kcw, const float* __restrict__ vcw,
    const float* __restrict__ A_log, const float* __restrict__ dt_bias,
    unsigned short* __restrict__ Wg, unsigned short* __restrict__ Ubg,
    unsigned short* __restrict__ Attg, unsigned short* __restrict__ Qgg,
    unsigned short* __restrict__ KgTg, float* __restrict__ decg) {
  __shared__ unsigned short Kb_s[64 * 128];
  __shared__ unsigned short Qb_s[64 * 128];     // later reused as KbgT [128][64]
  __shared__ unsigned short VbT_s[256 * 64];    // beta*V transposed
  __shared__ unsigned short Mb_s[4096];         // I + A (bf16)
  __shared__ unsigned short Xrow_s[2][4096];    // X row-major bf16 (ping-pong)
  __shared__ unsigned short Xt_s[2][4096];      // X^T bf16 (ping-pong)
  __shared__ unsigned short Yt_s[4096];         // (M X)^T bf16
  __shared__ float F1_s[4096];                  // X fp32
  __shared__ float carr_s[64];
  __shared__ float beta_s[64];

  const int tid = threadIdx.x;
  const int w = tid >> 6, l = tid & 63;
  const int row16 = l & 15, ko = (l >> 4) * 8;
  const int ch = blockIdx.x;
  const int bh = ch >> 4, p = ch & 15;
  const int b = bh >> 3, h = bh & 7;
  const size_t tbase = (size_t)b * T_LEN + p * 64;
  const bool head = (p == 0);

  // 1. per-step scalars + cumulative log-decay (wave 0, from Y directly)
  if (tid < 64) {
    const unsigned short* Yr = Y + (tbase + tid) * NBIG;
    float a = bf2f(Yr[6144 + h]) + dt_bias[h];
    float sp = (a > 20.f) ? a : log1pf(expf(a));
    float g = -expf(A_log[h]) * sp;
    float bp = bf2f(Yr[6152 + h]);
    beta_s[tid] = 1.f / (1.f + expf(-bp));
    float c = g;
#pragma unroll
    for (int d = 1; d < 64; d <<= 1) {
      float y = __shfl_up(c, d);
      if (tid >= d) c += y;
    }
    carr_s[tid] = c;
    if (tid == 63) decg[ch] = __expf(c);
  }
  __syncthreads();   // beta/carr ready for conv-v and epilogues

  // 2. conv+SiLU+l2norm for q (waves 0-3) and k (waves 4-7) -> Qb_s/Kb_s [64][128]
  //    Head-slice offsets: q chans h*128+c, k chans 1024+h*128+c  (R11 bug: these were missing)
  {
    const bool isQ = (tid < 256);
    const int wk = tid & 255;
    const int quad = wk & 31, tg = wk >> 5;     // 32 quads x 8 t-groups (8 t each)
    const int c = quad * 4;
    const float* cw = isQ ? qcw : kcw;
    const int cb = (isQ ? 0 : 1024) + h * 128 + c;
    float4 wv[4];
#pragma unroll
    for (int e = 0; e < 4; ++e) wv[e] = ((const float4*)cw)[h * 128 + c + e];
    float rows[11][4];
#pragma unroll
    for (int r = 0; r < 11; ++r) {
      if (head && tg == 0 && r < 3) {
        rows[r][0] = rows[r][1] = rows[r][2] = rows[r][3] = 0.f;
      } else {
        const ushort4 x = *(const ushort4*)(Y + (tbase + tg * 8 - 3 + r) * NBIG + cb);
        rows[r][0] = bf2f(x.x); rows[r][1] = bf2f(x.y);
        rows[r][2] = bf2f(x.z); rows[r][3] = bf2f(x.w);
      }
    }
    unsigned short* dst = isQ ? Qb_s : Kb_s;
    const float sc = isQ ? SCALE_Q : 1.f;
#pragma unroll
    for (int i = 0; i < 8; ++i) {
      float acc[4], ss = 0.f;
#pragma unroll
      for (int e = 0; e < 4; ++e) {
        float a = wv[e].x * rows[i][e];
        a = fmaf(wv[e].y, rows[i + 1][e], a);
        a = fmaf(wv[e].z, rows[i + 2][e], a);
        a = fmaf(wv[e].w, rows[i + 3][e], a);
        a = silu_f(a);
        acc[e] = a;
        ss += a * a;
      }
      // reduce over the 32 quads sharing this t (half-wave; masks <32 stay inside)
#pragma unroll
      for (int m = 16; m >= 1; m >>= 1) ss += __shfl_xor(ss, m);
      const float rn = rsqrtf(ss + 1e-6f) * sc;
      ushort4 o = {f2bf(acc[0] * rn), f2bf(acc[1] * rn), f2bf(acc[2] * rn), f2bf(acc[3] * rn)};
      *(ushort4*)(dst + (tg * 8 + i) * 128 + c) = o;
    }
  }
  // 3. conv+SiLU for v, *beta, transposed -> VbT_s [256][64]
  //    Head-slice offsets: v chans 2048 + h*256 + c, weights vcw[h*256 + c]
  {
    const int quad = tid & 63, tg = tid >> 6;   // 64 quads x 8 t-groups
    const int c = quad * 4;
    float4 wv[4];
#pragma unroll
    for (int e = 0; e < 4; ++e) wv[e] = ((const float4*)vcw)[h * 256 + c + e];
    float rows[11][4];
#pragma unroll
    for (int r = 0; r < 11; ++r) {
      if (head && tg == 0 && r < 3) {
        rows[r][0] = rows[r][1] = rows[r][2] = rows[r][3] = 0.f;
      } else {
        const ushort4 x = *(const ushort4*)(Y + (tbase + tg * 8 - 3 + r) * NBIG + 2048 + h * 256 + c);
        rows[r][0] = bf2f(x.x); rows[r][1] = bf2f(x.y);
        rows[r][2] = bf2f(x.z); rows[r][3] = bf2f(x.w);
      }
    }
#pragma unroll
    for (int i = 0; i < 8; ++i) {
      const int t = tg * 8 + i;
      const float bt = beta_s[t];
#pragma unroll
      for (int e = 0; e < 4; ++e) {
        float a = wv[e].x * rows[i][e];
        a = fmaf(wv[e].y, rows[i + 1][e], a);
        a = fmaf(wv[e].z, rows[i + 2][e], a);
        a = fmaf(wv[e].w, rows[i + 3][e], a);
        VbT_s[(c + e) * 64 + t] = f2bf(bt * silu_f(a));
      }
    }
  }
  __syncthreads();   // Kb/Qb/VbT ready

  // 4+5 fused: A_raw = K K^T; epilogue builds M = I+A, X0 = I-A (F1, Xrow0, Xt0)
  {
    f32x4 acc[2];
#pragma unroll
    for (int i = 0; i < 2; ++i)
#pragma unroll
      for (int r = 0; r < 4; ++r) acc[i][r] = 0.f;
    mm64_acc<128>(Kb_s, Kb_s, acc, w, row16, ko);
#pragma unroll
    for (int i = 0; i < 2; ++i) {
      const int ti = w + 8 * i;
      const int rt = ti >> 2, ct = ti & 3;
      const int r0 = rt * 16 + (l >> 4) * 4;
      const int col = ct * 16 + (l & 15);
#pragma unroll
      for (int r = 0; r < 4; ++r) {
        const int t = r0 + r, j = col;
        const float av = (j < t) ? beta_s[t] * __expf(carr_s[t] - carr_s[j]) * acc[i][r] : 0.f;
        const float dg = (t == j) ? 1.f : 0.f;
        Mb_s[t * 64 + j] = f2bf(dg + av);
        const float x0 = dg - av;
        F1_s[t * 64 + j] = x0;
        const unsigned short xb = f2bf(x0);
        Xrow_s[0][t * 64 + j] = xb;
        Xt_s[0][j * 64 + t] = xb;
      }
    }
  }
  __syncthreads();
  // 6. Newton x5: X <- X(2I - M X), 2 phases/iter, ping-pong X (exact: A nilpotent)
  int cur = 0;
  for (int it = 0; it < 5; ++it) {
    {  // Yt = (M X)^T  (transposed-write epilogue)
      f32x4 acc[2];
#pragma unroll
      for (int i = 0; i < 2; ++i)
#pragma unroll
        for (int r = 0; r < 4; ++r) acc[i][r] = 0.f;
      mm64_acc<64>(Mb_s, Xt_s[cur], acc, w, row16, ko);
#pragma unroll
      for (int i = 0; i < 2; ++i) {
        const int ti = w + 8 * i;
        const int rt = ti >> 2, ct = ti & 3;
        const int r0 = rt * 16 + (l >> 4) * 4;
        const int col = ct * 16 + (l & 15);
#pragma unroll
        for (int r = 0; r < 4; ++r)
          Yt_s[col * 64 + (r0 + r)] = f2bf(acc[i][r]);
      }
    }
    __syncthreads();
    {  // P = X Y ; X' = 2*F1 - P  -> buffers cur^1 (no read/write overlap)
      f32x4 acc[2];
#pragma unroll
      for (int i = 0; i < 2; ++i)
#pragma unroll
        for (int r = 0; r < 4; ++r) acc[i][r] = 0.f;
      mm64_acc<64>(Xrow_s[cur], Yt_s, acc, w, row16, ko);
#pragma unroll
      for (int i = 0; i < 2; ++i) {
        const int ti = w + 8 * i;
        const int rt = ti >> 2, ct = ti & 3;
        const int r0 = rt * 16 + (l >> 4) * 4;
        const int col = ct * 16 + (l & 15);
#pragma unroll
        for (int r = 0; r < 4; ++r) {
          const int idx = (r0 + r) * 64 + col;
          const float xn = 2.f * F1_s[idx] - acc[i][r];
          F1_s[idx] = xn;
          const unsigned short xb = f2bf(xn);
          Xrow_s[cur ^ 1][idx] = xb;
          Xt_s[cur ^ 1][col * 64 + (r0 + r)] = xb;
        }
      }
    }
    cur ^= 1;
    __syncthreads();
  }
  const unsigned short* Xfin = Xrow_s[cur];
  const float ctot = carr_s[63];
  // 7+8 fused: Att = mask(exp) o (Q K^T) -> global directly
  {
    f32x4 acc[2];
#pragma unroll
    for (int i = 0; i < 2; ++i)
#pragma unroll
      for (int r = 0; r < 4; ++r) acc[i][r] = 0.f;
    mm64_acc<128>(Qb_s, Kb_s, acc, w, row16, ko);
#pragma unroll
    for (int i = 0; i < 2; ++i) {
      const int ti = w + 8 * i;
      const int rt = ti >> 2, ct = ti & 3;
      const int r0 = rt * 16 + (l >> 4) * 4;
      const int col = ct * 16 + (l & 15);
#pragma unroll
      for (int r = 0; r < 4; ++r) {
        const int t = r0 + r, j = col;
        const float av = (j <= t) ? __expf(carr_s[t] - carr_s[j]) * acc[i][r] : 0.f;
        Attg[(size_t)ch * 4096 + t * 64 + j] = f2bf(av);
      }
    }
  }
  // Qg, KgT -> global (elementwise from Qb/Kb)
#pragma unroll
  for (int i = 0; i < 16; ++i) {
    const int idx = i * 512 + tid;
    const int t = idx >> 7;
    Qgg[(size_t)ch * 8192 + idx] = f2bf(__expf(carr_s[t]) * bf2f(Qb_s[idx]));
  }
#pragma unroll
  for (int i = 0; i < 16; ++i) {
    const int idx = i * 512 + tid;
    const int d = idx >> 6, t = idx & 63;
    KgTg[(size_t)ch * 8192 + idx] = f2bf(__expf(ctot - carr_s[t]) * bf2f(Kb_s[t * 128 + d]));
  }
  __syncthreads();   // Qb reads done before reuse
  // 9. KbgT[d][t] = bf16(beta_t exp(c_t) k[t][d])  (into Qb space)
  unsigned short* KbgT = Qb_s;
#pragma unroll
  for (int i = 0; i < 16; ++i) {
    const int idx = i * 512 + tid;
    const int d = idx >> 6, t = idx & 63;
    KbgT[idx] = f2bf(beta_s[t] * __expf(carr_s[t]) * bf2f(Kb_s[t * 128 + d]));
  }
  __syncthreads();
  // 10. W = T (betaG.K)  [64x128];  Ub = T (betaV)  [64x256]  -> global bf16
  mm_nt_lds<64, 128, 64, true, 8>(Xfin, KbgT, nullptr, Wg + (size_t)ch * 8192, 128, tid);
  mm_nt_lds<64, 256, 64, true, 8>(Xfin, VbT_s, nullptr, Ubg + (size_t)ch * 16384, 256, tid);
}

// ---------------- phase 2: serial chunk recurrence (MFMA), 16 bh x 8 v-blocks, 512 thr ----------------
// stage buffer (ushort offsets): W@0(8192) Att@8192(4096) Qg@12288(8192) KgT@20480(8192) Ub@28672(2048)
__device__ __forceinline__ void p2_stage(
    const unsigned short* Wg, const unsigned short* Attg, const unsigned short* Qgg,
    const unsigned short* KgTg, const unsigned short* Ubg,
    int ch, int vb, unsigned short* buf, int tid) {
#pragma unroll
  for (int i = 0; i < 2; ++i) {
    const int f = i * 512 + tid;
    GLDS(Wg + (size_t)ch * 8192 + f * 8, (char*)buf + f * 16);
  }
  {
    const int f = tid;
    GLDS(Attg + (size_t)ch * 4096 + f * 8, (char*)(buf + 8192) + f * 16);
  }
#pragma unroll
  for (int i = 0; i < 2; ++i) {
    const int f = i * 512 + tid;
    GLDS(Qgg + (size_t)ch * 8192 + f * 8, (char*)(buf + 12288) + f * 16);
  }
#pragma unroll
  for (int i = 0; i < 2; ++i) {
    const int f = i * 512 + tid;
    GLDS(KgTg + (size_t)ch * 8192 + f * 8, (char*)(buf + 20480) + f * 16);
  }
  if (tid < 256) {
    const int f = tid;
    const int t = f >> 2, c8 = f & 3;
    GLDS(Ubg + (size_t)ch * 16384 + t * 256 + vb * 32 + c8 * 8, (char*)(buf + 28672) + f * 16);
  }
}

__global__ __launch_bounds__(512, 1) void scan_chunks(
    const unsigned short* __restrict__ Wg, const unsigned short* __restrict__ Ubg,
    const unsigned short* __restrict__ Attg, const unsigned short* __restrict__ Qgg,
    const unsigned short* __restrict__ KgTg, const float* __restrict__ decg,
    float* __restrict__ osc) {
  __shared__ float StT_s[32 * 128];            // S^T fp32 [vcol][d]
  __shared__ unsigned short StTb_s[32 * 128];  // S^T bf16
  __shared__ unsigned short uT_s[32 * 64];     // u^T bf16 [vcol][t]
  __shared__ unsigned short stage_s[2][30720];

  const int tid = threadIdx.x;
  const int w = tid >> 6, l = tid & 63;
  const int row = l & 15, ko = (l >> 4) * 8;
  const int blk = blockIdx.x;                  // vb*16 + bh  (same-bh blocks share an XCD)
  const int vb = blk >> 4, bh = blk & 15;
  const int b = bh >> 3, h = bh & 7;

  for (int i = tid; i < 4096; i += 512) { StT_s[i] = 0.f; StTb_s[i] = 0; }
  p2_stage(Wg, Attg, Qgg, KgTg, Ubg, bh * 16, vb, stage_s[0], tid);

  for (int p = 0; p < 16; ++p) {
    unsigned short* bufc = stage_s[p & 1];
    const unsigned short* Wl   = bufc;
    const unsigned short* Attl = bufc + 8192;
    const unsigned short* Qgl  = bufc + 12288;
    const unsigned short* KgTl = bufc + 20480;
    const unsigned short* Ubl  = bufc + 28672;
    __syncthreads();   // staged buf + previous S writes visible (vmcnt drained)

    // ---- u = Ub - W S : acc [64x32], 8 tiles, 1/wave ----
    f32x4 uacc;
#pragma unroll
    for (int r = 0; r < 4; ++r) uacc[r] = 0.f;
    const int rt = w >> 1, ct = w & 1;
#pragma unroll
    for (int kk = 0; kk < 4; ++kk) {
      bf16x8 af = *(const bf16x8*)(Wl + (rt * 16 + row) * 128 + kk * 32 + ko);
      bf16x8 bf = *(const bf16x8*)(StTb_s + (ct * 16 + row) * 128 + kk * 32 + ko);
      uacc = __builtin_amdgcn_mfma_f32_16x16x32_bf16(af, bf, uacc, 0, 0, 0);
    }
    {
      const int r0 = rt * 16 + (l >> 4) * 4;
      const int col = ct * 16 + (l & 15);
#pragma unroll
      for (int r = 0; r < 4; ++r) {
        const int t = r0 + r;
        const float ubv = bf2f(Ubl[t * 32 + col]);
        uT_s[col * 64 + t] = f2bf(ubv - uacc[r]);
      }
    }
    __syncthreads();   // uT ready
    if (p < 15)
      p2_stage(Wg, Attg, Qgg, KgTg, Ubg, bh * 16 + p + 1, vb, stage_s[(p + 1) & 1], tid);

    // ---- O = Qg S + Att u : acc [64x32], 1 tile/wave ----
    f32x4 oacc;
#pragma unroll
    for (int r = 0; r < 4; ++r) oacc[r] = 0.f;
#pragma unroll
    for (int kk = 0; kk < 4; ++kk) {
      bf16x8 af = *(const bf16x8*)(Qgl + (rt * 16 + row) * 128 + kk * 32 + ko);
      bf16x8 bf = *(const bf16x8*)(StTb_s + (ct * 16 + row) * 128 + kk * 32 + ko);
      oacc = __builtin_amdgcn_mfma_f32_16x16x32_bf16(af, bf, oacc, 0, 0, 0);
    }
#pragma unroll
    for (int kk = 0; kk < 2; ++kk) {
      bf16x8 af = *(const bf16x8*)(Attl + (rt * 16 + row) * 64 + kk * 32 + ko);
      bf16x8 bf = *(const bf16x8*)(uT_s + (ct * 16 + row) * 64 + kk * 32 + ko);
      oacc = __builtin_amdgcn_mfma_f32_16x16x32_bf16(af, bf, oacc, 0, 0, 0);
    }
    // ---- Snew^T = dec*S^T + (u^T)(KgT^T) : acc [32x128], 16 tiles, 2/wave ----
    f32x4 sacc[2];
#pragma unroll
    for (int i = 0; i < 2; ++i)
#pragma unroll
      for (int r = 0; r < 4; ++r) sacc[i][r] = 0.f;
#pragma unroll
    for (int i = 0; i < 2; ++i) {
      const int ti = w + 8 * i;
      const int srt = ti >> 3, sct = ti & 7;
#pragma unroll
      for (int kk = 0; kk < 2; ++kk) {
        bf16x8 af = *(const bf16x8*)(uT_s + (srt * 16 + row) * 64 + kk * 32 + ko);
        bf16x8 bf = *(const bf16x8*)(KgTl + (sct * 16 + row) * 64 + kk * 32 + ko);
        sacc[i] = __builtin_amdgcn_mfma_f32_16x16x32_bf16(af, bf, sacc[i], 0, 0, 0);
      }
    }
    const float dec = decg[bh * 16 + p];
    __syncthreads();   // all reads of StT/StTb done before overwrite

    // epilogues
    {
      const int r0 = rt * 16 + (l >> 4) * 4;
      const int col = ct * 16 + (l & 15);
#pragma unroll
      for (int r = 0; r < 4; ++r) {
        const size_t trow = (size_t)b * T_LEN + p * 64 + r0 + r;
        osc[(trow * 8 + h) * 256 + vb * 32 + col] = oacc[r];
      }
    }
#pragma unroll
    for (int i = 0; i < 2; ++i) {
      const int ti = w + 8 * i;
      const int srt = ti >> 3, sct = ti & 7;
      const int r0 = srt * 16 + (l >> 4) * 4;
      const int cold = sct * 16 + (l & 15);
#pragma unroll
      for (int r = 0; r < 4; ++r) {
        const int idx = (r0 + r) * 128 + cold;
        const float sn = fmaf(dec, StT_s[idx], sacc[i][r]);
        StT_s[idx] = sn;
        StTb_s[idx] = f2bf(sn);
      }
    }
  }
}

// ---------------- gated RMSNorm + silu(gate) -> bf16 ----------------
__global__ __launch_bounds__(256) void rmsgate(
    const float* __restrict__ ob, const unsigned short* __restrict__ Y,
    const float* __restrict__ onw, unsigned short* __restrict__ Obf) {
  const int bt = blockIdx.x;
  const int tid = threadIdx.x;
  const int c = tid * 8;                // head = c/256 = tid/32
  const float* orow = ob + (size_t)bt * 2048 + c;
  const unsigned short* grow = Y + (size_t)bt * NBIG + 4096 + c;
  const float4 o0 = *(const float4*)orow, o1 = *(const float4*)(orow + 4);
  const ushort4 g0 = *(const ushort4*)grow, g1 = *(const ushort4*)(grow + 4);
  const float ov[8] = {o0.x, o0.y, o0.z, o0.w, o1.x, o1.y, o1.z, o1.w};
  const float gv[8] = {bf2f(g0.x), bf2f(g0.y), bf2f(g0.z), bf2f(g0.w),
                       bf2f(g1.x), bf2f(g1.y), bf2f(g1.z), bf2f(g1.w)};
  float ss = 0.f;
#pragma unroll
  for (int e = 0; e < 8; ++e) ss += ov[e] * ov[e];
#pragma unroll
  for (int m = 16; m >= 1; m >>= 1) ss += __shfl_xor(ss, m);
  const float rn = rsqrtf(ss * (1.f / 256.f) + 1e-5f);
  const int dv = c & 255;
  unsigned short rr[8];
#pragma unroll
  for (int e = 0; e < 8; ++e) {
    const float val = ov[e] * rn * onw[dv + e] * silu_f(gv[e]);
    rr[e] = f2bf(val);
  }
  ushort4 r0 = {rr[0], rr[1], rr[2], rr[3]};
  ushort4 r1 = {rr[4], rr[5], rr[6], rr[7]};
  *(ushort4*)(Obf + (size_t)bt * 2048 + c) = r0;
  *(ushort4*)(Obf + (size_t)bt * 2048 + c + 4) = r1;
}

extern "C" void kernel_launch(void* const* d_in, const int* in_sizes, int n_in,
                              void* d_out, int out_size, void* d_ws, size_t ws_size,
                              hipStream_t stream) {
  (void)in_sizes; (void)n_in; (void)out_size; (void)ws_size;
  const float* h    = (const float*)d_in[0];
  const float* qw   = (const float*)d_in[1];
  const float* kw   = (const float*)d_in[2];
  const float* vw   = (const float*)d_in[3];
  const float* aw   = (const float*)d_in[4];
  const float* bw   = (const float*)d_in[5];
  const float* gw   = (const float*)d_in[6];
  const float* ow   = (const float*)d_in[7];
  const float* qcw  = (const float*)d_in[8];
  const float* kcw  = (const float*)d_in[9];
  const float* vcw  = (const float*)d_in[10];
  const float* Alog = (const float*)d_in[11];
  const float* dtb  = (const float*)d_in[12];
  const float* onw  = (const float*)d_in[13];

  char* ws = (char*)d_ws;
  size_t off = 0;
  auto alloc = [&](size_t bytes) {
    char* p = ws + off;
    off = (off + bytes + 255) & ~(size_t)255;
    return p;
  };
  unsigned short* hbf  = (unsigned short*)alloc(2048ull * 2048 * 2);
  unsigned short* Wb   = (unsigned short*)alloc((size_t)NBIG * 2048 * 2);
  unsigned short* owb  = (unsigned short*)alloc(2048ull * 2048 * 2);
  unsigned short* Ybf  = (unsigned short*)alloc(2048ull * NBIG * 2);
  float* osc           = (float*)alloc(2048ull * 2048 * 4);
  unsigned short* Obf  = (unsigned short*)alloc(2048ull * 2048 * 2);
  unsigned short* Wg   = (unsigned short*)alloc(256ull * 8192 * 2);
  unsigned short* Ubg  = (unsigned short*)alloc(256ull * 16384 * 2);
  unsigned short* Attg = (unsigned short*)alloc(256ull * 4096 * 2);
  unsigned short* Qgg  = (unsigned short*)alloc(256ull * 8192 * 2);
  unsigned short* KgTg = (unsigned short*)alloc(256ull * 8192 * 2);
  float* decg          = (float*)alloc(256ull * 4);

  cvt_bf16<<<4096, 256, 0, stream>>>(h, hbf, 1048576);
  build_w<<<12800, 256, 0, stream>>>(qw, kw, vw, gw, aw, bw, Wb);
  cvt_bf16<<<4096, 256, 0, stream>>>(ow, owb, 1048576);
  // GEMM1: 16 x 25 tiles of 128x256 -> 400 blocks (R9-measured best config)
  gemm_pipe<256, 4, 512, true><<<400, 512, 0, stream>>>(
      (const bf16*)hbf, (const bf16*)Wb, Ybf, NBIG, 2048);
  chunk_prep<<<256, 512, 0, stream>>>(Ybf, qcw, kcw, vcw, Alog, dtb,
                                      Wg, Ubg, Attg, Qgg, KgTg, decg);
  scan_chunks<<<128, 512, 0, stream>>>(Wg, Ubg, Attg, Qgg, KgTg, decg, osc);
  rmsgate<<<2048, 256, 0, stream>>>(osc, Ybf, onw, Obf);
  // GEMM2: 16 x 16 tiles of 128x128 -> 256 blocks
  gemm_pipe<128, 2, 256, false><<<256, 256, 0, stream>>>(
      (const bf16*)Obf, (const bf16*)owb, d_out, 2048, 2048);
}

// Round 13
// 220.883 us; speedup vs baseline: 1.2156x; 1.0210x over previous
//
#include <hip/hip_runtime.h>
#include <cstdint>

#define T_LEN 1024
#define NBIG  6400     // padded N for fused projection GEMM (6160 real cols, 25 x 256 tiles)
#define SCALE_Q 0.08838834764831843f   // DK^-0.5

typedef __bf16 bf16;
typedef __bf16 bf16x8 __attribute__((ext_vector_type(8)));
typedef float  f32x4  __attribute__((ext_vector_type(4)));

__device__ __forceinline__ unsigned short f2bf(float f) {
  unsigned int u = __builtin_bit_cast(unsigned int, f);
  u += 0x7FFFu + ((u >> 16) & 1u);          // RNE
  return (unsigned short)(u >> 16);
}
__device__ __forceinline__ float bf2f(unsigned short u) {
  return __builtin_bit_cast(float, (unsigned int)u << 16);
}
__device__ __forceinline__ float silu_f(float x) { return x / (1.f + __expf(-x)); }

#define GLDS(src, dst) \
  __builtin_amdgcn_global_load_lds( \
      (__attribute__((address_space(1))) void*)(void*)(src), \
      (__attribute__((address_space(3))) void*)(void*)(dst), 16, 0, 0)

// ---------------- fp32 -> bf16 conversion (4 elems/thread) ----------------
__global__ __launch_bounds__(256) void cvt_bf16(const float* __restrict__ in,
                                                unsigned short* __restrict__ out, int n4) {
  int idx = blockIdx.x * 256 + threadIdx.x;
  if (idx >= n4) return;
  float4 f = ((const float4*)in)[idx];
  ushort4 o = { f2bf(f.x), f2bf(f.y), f2bf(f.z), f2bf(f.w) };
  ((ushort4*)out)[idx] = o;
}

// ---------------- zero fp32 buffer (float4/thread) ----------------
__global__ __launch_bounds__(256) void zero_f32(float* __restrict__ p, int n4) {
  int idx = blockIdx.x * 256 + threadIdx.x;
  if (idx >= n4) return;
  float4 z = {0.f, 0.f, 0.f, 0.f};
  ((float4*)p)[idx] = z;
}

// ------------- build concatenated weight matrix W[NBIG][2048] bf16 -------------
__global__ __launch_bounds__(256) void build_w(
    const float* __restrict__ qw, const float* __restrict__ kw,
    const float* __restrict__ vw, const float* __restrict__ gw,
    const float* __restrict__ aw, const float* __restrict__ bw,
    unsigned short* __restrict__ W) {
  int idx = blockIdx.x * 256 + threadIdx.x;   // quad id, exact grid
  int r = idx >> 9;                           // row (2048/4 = 512 quads per row)
  int c = (idx & 511) << 2;
  const float* src;
  if      (r < 1024) src = qw + (size_t)r * 2048;
  else if (r < 2048) src = kw + (size_t)(r - 1024) * 2048;
  else if (r < 4096) src = vw + (size_t)(r - 2048) * 2048;
  else if (r < 6144) src = gw + (size_t)(r - 4096) * 2048;
  else if (r < 6152) src = aw + (size_t)(r - 6144) * 2048;
  else if (r < 6160) src = bw + (size_t)(r - 6152) * 2048;
  else               src = nullptr;
  ushort4 o;
  if (src) {
    float4 f = *(const float4*)(src + c);
    o = { f2bf(f.x), f2bf(f.y), f2bf(f.z), f2bf(f.w) };
  } else {
    o = { 0, 0, 0, 0 };
  }
  *(ushort4*)(W + (size_t)r * 2048 + c) = o;
}

// ============ pipelined NT GEMM: BM=128 x BN tile, BK=32, ring-3 LDS, counted vmcnt ============
// C[M][N] = A[M][K_total] * B[N][K_total]^T over a K-slice. bf16 in. T threads = T/64 waves.
// If ATOMIC: grid = 2*nInner, block bid>>8 handles K-half (K elems starting at (bid>>8)*K),
// epilogue atomicAdd fp32 (exactly 2 contributions/addr -> deterministic).
// R6-proven schedule: per K-step { STAGE(kt+2); setprio(1); 16 MFMA; setprio(0);
// lgkmcnt(0); vmcnt(LOADS); s_barrier; ds_read next frags }. vmcnt never drains to 0.
// LDS swizzle (0-conflict, R4-verified): logical k-slot s of row r at phys s ^ ((r>>1)&3).
template <int BN, int WN, int T, bool BF16OUT, bool ATOMIC>
__global__ __launch_bounds__(T, 4) void gemm_pipe(
    const bf16* __restrict__ A, const bf16* __restrict__ Bm,
    void* __restrict__ Cv, int N, int K, int ldk) {
  constexpr int AI = (128 * 32) / (T * 8);   // A glds insts/thread per K-tile
  constexpr int BI = (BN * 32) / (T * 8);    // B glds insts/thread per K-tile
  constexpr int LOADS = AI + BI;
  __shared__ bf16 LA[3][128 * 32];
  __shared__ bf16 LB[3][BN * 32];
  const int tid = threadIdx.x;
  const int lane = tid & 63;
  const int wid = tid >> 6;
  const int wm = wid / WN, wn = wid % WN;
  // XCD-chunked bijective block map: xcd owns m-rows {xcd, xcd+8} x all n-tiles
  const int bidAll = blockIdx.x;
  const int bid = ATOMIC ? (bidAll & 255) : bidAll;
  const long kofs = ATOMIC ? (long)(bidAll >> 8) * K : 0;
  const int xcd = bid & 7, jj = bid >> 3;
  const long brow = (long)(xcd + 8 * (jj & 1)) * 128;
  const long bcol = (long)(jj >> 1) * BN;

  f32x4 acc[4][4];
#pragma unroll
  for (int m = 0; m < 4; ++m)
#pragma unroll
    for (int n = 0; n < 4; ++n)
#pragma unroll
      for (int r = 0; r < 4; ++r) acc[m][n][r] = 0.f;

  // staging map: flat slot = e*T + tid -> (row = flat>>2, pslot = flat&3);
  // global source col = (pslot ^ ((row>>1)&3)) * 8  (inverse swizzle, linear LDS dest)
  const bf16* AgS[AI];
  const bf16* BgS[BI];
  int adst[AI], bdst[BI];
#pragma unroll
  for (int e = 0; e < AI; ++e) {
    const int flat = e * T + tid;
    const int row = flat >> 2;
    const int sl = (flat & 3) ^ ((row >> 1) & 3);
    AgS[e] = A + (brow + row) * (long)ldk + kofs + sl * 8;
    adst[e] = flat * 8;
  }
#pragma unroll
  for (int e = 0; e < BI; ++e) {
    const int flat = e * T + tid;
    const int row = flat >> 2;
    const int sl = (flat & 3) ^ ((row >> 1) & 3);
    BgS[e] = Bm + (bcol + row) * (long)ldk + kofs + sl * 8;
    bdst[e] = flat * 8;
  }

#define STAGE(kt, sb)                                              \
  {                                                                \
    const long ko = (long)(kt) * 32;                               \
    _Pragma("unroll")                                              \
    for (int e = 0; e < AI; ++e) GLDS(AgS[e] + ko, &LA[sb][0] + adst[e]); \
    _Pragma("unroll")                                              \
    for (int e = 0; e < BI; ++e) GLDS(BgS[e] + ko, &LB[sb][0] + bdst[e]); \
  }
#define WAIT_VM()                                                  \
  if constexpr (LOADS == 3) asm volatile("s_waitcnt vmcnt(3)" ::: "memory"); \
  else                      asm volatile("s_waitcnt vmcnt(4)" ::: "memory");

  // read offsets (halfwords): row*32 + (ks ^ ((r16>>1)&3))*8
  const int r16 = lane & 15;
  const int ks = lane >> 4;
  const int pso = (ks ^ ((r16 >> 1) & 3)) * 8;
  int rdA[4], rdB[4];
#pragma unroll
  for (int i = 0; i < 4; ++i) rdA[i] = (wm * 64 + i * 16 + r16) * 32 + pso;
#pragma unroll
  for (int j = 0; j < 4; ++j) rdB[j] = (wn * 64 + j * 16 + r16) * 32 + pso;

  const int nkt = K >> 5;
  STAGE(0, 0);
  STAGE(1, 1);
  WAIT_VM();                         // buf0 landed (stage(1) may stay in flight)
  __builtin_amdgcn_s_barrier();

  bf16x8 af[4], bfr[4];
#pragma unroll
  for (int i = 0; i < 4; ++i) af[i] = *(const bf16x8*)(&LA[0][0] + rdA[i]);
#pragma unroll
  for (int j = 0; j < 4; ++j) bfr[j] = *(const bf16x8*)(&LB[0][0] + rdB[j]);

  for (int kt = 0; kt < nkt; ++kt) {
    const int kts = (kt + 2 < nkt) ? kt + 2 : nkt - 1;  // clamp src, keep count uniform
    const int sb = (kt + 2) % 3;                        // == (kt-1)%3: read-complete slot
    const int nb = (kt + 1) % 3;

    STAGE(kts, sb);
    __builtin_amdgcn_s_setprio(1);
#pragma unroll
    for (int i = 0; i < 4; ++i)
#pragma unroll
      for (int j = 0; j < 4; ++j)
        acc[i][j] = __builtin_amdgcn_mfma_f32_16x16x32_bf16(af[i], bfr[j], acc[i][j], 0, 0, 0);
    __builtin_amdgcn_s_setprio(0);

    asm volatile("s_waitcnt lgkmcnt(0)" ::: "memory");
    WAIT_VM();                       // kt+1 landed; kt+2 stays in flight
    __builtin_amdgcn_s_barrier();
#pragma unroll
    for (int i = 0; i < 4; ++i) af[i] = *(const bf16x8*)(&LA[nb][0] + rdA[i]);
#pragma unroll
    for (int j = 0; j < 4; ++j) bfr[j] = *(const bf16x8*)(&LB[nb][0] + rdB[j]);
  }
#undef STAGE
#undef WAIT_VM

  // epilogue: C/D layout col=lane&15, row=(lane>>4)*4+r
  const long row0 = brow + wm * 64 + ((lane >> 4) * 4);
  const long col0 = bcol + wn * 64 + (lane & 15);
#pragma unroll
  for (int m = 0; m < 4; ++m)
#pragma unroll
    for (int n = 0; n < 4; ++n)
#pragma unroll
      for (int r = 0; r < 4; ++r) {
        const long idx = (row0 + m * 16 + r) * (long)N + col0 + n * 16;
        if constexpr (ATOMIC)
          atomicAdd((float*)Cv + idx, acc[m][n][r]);
        else if constexpr (BF16OUT)
          ((unsigned short*)Cv)[idx] = f2bf(acc[m][n][r]);
        else
          ((float*)Cv)[idx] = acc[m][n][r];
      }
}

// ---------------- small NT GEMM on LDS operands: OUT[i][j] = sum_k A[i][k]*B[j][k] ----------------
// A: [M][K] bf16 LDS, B: [N][K] bf16 LDS. NW waves. Output bf16 global (ldg).
template <int M, int N, int K, int NW>
__device__ __forceinline__ void mm_nt_lds(const unsigned short* A, const unsigned short* B,
                                          unsigned short* outG, int ldg, int tid) {
  constexpr int NT16 = N / 16;
  constexpr int PW = (M / 16) * NT16 / NW;
  const int w = tid >> 6, l = tid & 63;
  const int row = l & 15, ko = (l >> 4) * 8;
  f32x4 acc[PW];
#pragma unroll
  for (int i = 0; i < PW; ++i)
#pragma unroll
    for (int r = 0; r < 4; ++r) acc[i][r] = 0.f;
#pragma unroll
  for (int i = 0; i < PW; ++i) {
    const int ti = w + NW * i;
    const int rt = ti / NT16, ct = ti % NT16;
#pragma unroll
    for (int kk = 0; kk < K / 32; ++kk) {
      bf16x8 af = *(const bf16x8*)(A + (rt * 16 + row) * K + kk * 32 + ko);
      bf16x8 bf = *(const bf16x8*)(B + (ct * 16 + row) * K + kk * 32 + ko);
      acc[i] = __builtin_amdgcn_mfma_f32_16x16x32_bf16(af, bf, acc[i], 0, 0, 0);
    }
  }
#pragma unroll
  for (int i = 0; i < PW; ++i) {
    const int ti = w + NW * i;
    const int rt = ti / NT16, ct = ti % NT16;
    const int r0 = rt * 16 + (l >> 4) * 4;
    const int col = ct * 16 + (l & 15);
#pragma unroll
    for (int r = 0; r < 4; ++r)
      outG[(size_t)(r0 + r) * ldg + col] = f2bf(acc[i][r]);
  }
}

// 64x64 NT MFMA accumulate (8 waves, 2 tiles/wave), epilogue left to caller
template <int K>
__device__ __forceinline__ void mm64_acc(const unsigned short* A, const unsigned short* B,
                                         f32x4 acc[2], int w, int row, int ko) {
#pragma unroll
  for (int i = 0; i < 2; ++i) {
    const int ti = w + 8 * i;
    const int rt = ti >> 2, ct = ti & 3;
#pragma unroll
    for (int kk = 0; kk < K / 32; ++kk) {
      bf16x8 af = *(const bf16x8*)(A + (rt * 16 + row) * K + kk * 32 + ko);
      bf16x8 bf = *(const bf16x8*)(B + (ct * 16 + row) * K + kk * 32 + ko);
      acc[i] = __builtin_amdgcn_mfma_f32_16x16x32_bf16(af, bf, acc[i], 0, 0, 0);
    }
  }
}

// ---------------- phase 1: conv+norm fused + per-chunk UT transform (C=64), 512 threads ----------------
// Each block owns (bh, p): conv(K=4)+SiLU(+l2norm) for its head-slice directly from Y,
// then the UT transform. X fp32 master kept in REGISTERS (thread re-reads what it wrote).
__global__ __launch_bounds__(512, 1) void chunk_prep(
    const unsigned short* __restrict__ Y,
    const float* __restrict__ qcw, const float* __restrict__ kcw, const float* __restrict__ vcw,
    const float* __restrict__ A_log, const float* __restrict__ dt_bias,
    unsigned short* __restrict__ Wg, unsigned short* __restrict__ Ubg,
    unsigned short* __restrict__ Attg, unsigned short* __restrict__ Qgg,
    unsigned short* __restrict__ KgTg, float* __restrict__ decg) {
  __shared__ unsigned short Kb_s[64 * 128];
  __shared__ unsigned short Qb_s[64 * 128];     // later reused as KbgT [128][64]
  __shared__ unsigned short VbT_s[256 * 64];    // beta*V transposed
  __shared__ unsigned short Mb_s[4096];         // I + A (bf16)
  __shared__ unsigned short Xrow_s[2][4096];    // X row-major bf16 (ping-pong)
  __shared__ unsigned short Xt_s[2][4096];      // X^T bf16 (ping-pong)
  __shared__ unsigned short Yt_s[4096];         // (M X)^T bf16
  __shared__ float carr_s[64];
  __shared__ float beta_s[64];

  const int tid = threadIdx.x;
  const int w = tid >> 6, l = tid & 63;
  const int row16 = l & 15, ko = (l >> 4) * 8;
  const int ch = blockIdx.x;
  const int bh = ch >> 4, p = ch & 15;
  const int b = bh >> 3, h = bh & 7;
  const size_t tbase = (size_t)b * T_LEN + p * 64;
  const bool head = (p == 0);

  // 1. per-step scalars + cumulative log-decay (wave 0, from Y directly)
  if (tid < 64) {
    const unsigned short* Yr = Y + (tbase + tid) * NBIG;
    float a = bf2f(Yr[6144 + h]) + dt_bias[h];
    float sp = (a > 20.f) ? a : log1pf(expf(a));
    float g = -expf(A_log[h]) * sp;
    float bp = bf2f(Yr[6152 + h]);
    beta_s[tid] = 1.f / (1.f + expf(-bp));
    float c = g;
#pragma unroll
    for (int d = 1; d < 64; d <<= 1) {
      float y = __shfl_up(c, d);
      if (tid >= d) c += y;
    }
    carr_s[tid] = c;
    if (tid == 63) decg[ch] = __expf(c);
  }
  __syncthreads();   // beta/carr ready for conv-v and epilogues

  // 2. conv+SiLU+l2norm for q (waves 0-3) and k (waves 4-7) -> Qb_s/Kb_s [64][128]
  {
    const bool isQ = (tid < 256);
    const int wk = tid & 255;
    const int quad = wk & 31, tg = wk >> 5;     // 32 quads x 8 t-groups (8 t each)
    const int c = quad * 4;
    const float* cw = isQ ? qcw : kcw;
    const int cb = (isQ ? 0 : 1024) + h * 128 + c;
    float4 wv[4];
#pragma unroll
    for (int e = 0; e < 4; ++e) wv[e] = ((const float4*)cw)[h * 128 + c + e];
    float rows[11][4];
#pragma unroll
    for (int r = 0; r < 11; ++r) {
      if (head && tg == 0 && r < 3) {
        rows[r][0] = rows[r][1] = rows[r][2] = rows[r][3] = 0.f;
      } else {
        const ushort4 x = *(const ushort4*)(Y + (tbase + tg * 8 - 3 + r) * NBIG + cb);
        rows[r][0] = bf2f(x.x); rows[r][1] = bf2f(x.y);
        rows[r][2] = bf2f(x.z); rows[r][3] = bf2f(x.w);
      }
    }
    unsigned short* dst = isQ ? Qb_s : Kb_s;
    const float sc = isQ ? SCALE_Q : 1.f;
#pragma unroll
    for (int i = 0; i < 8; ++i) {
      float acc[4], ss = 0.f;
#pragma unroll
      for (int e = 0; e < 4; ++e) {
        float a = wv[e].x * rows[i][e];
        a = fmaf(wv[e].y, rows[i + 1][e], a);
        a = fmaf(wv[e].z, rows[i + 2][e], a);
        a = fmaf(wv[e].w, rows[i + 3][e], a);
        a = silu_f(a);
        acc[e] = a;
        ss += a * a;
      }
#pragma unroll
      for (int m = 16; m >= 1; m >>= 1) ss += __shfl_xor(ss, m);
      const float rn = rsqrtf(ss + 1e-6f) * sc;
      ushort4 o = {f2bf(acc[0] * rn), f2bf(acc[1] * rn), f2bf(acc[2] * rn), f2bf(acc[3] * rn)};
      *(ushort4*)(dst + (tg * 8 + i) * 128 + c) = o;
    }
  }
  // 3. conv+SiLU for v, *beta, transposed -> VbT_s [256][64]
  {
    const int quad = tid & 63, tg = tid >> 6;   // 64 quads x 8 t-groups
    const int c = quad * 4;
    float4 wv[4];
#pragma unroll
    for (int e = 0; e < 4; ++e) wv[e] = ((const float4*)vcw)[h * 256 + c + e];
    float rows[11][4];
#pragma unroll
    for (int r = 0; r < 11; ++r) {
      if (head && tg == 0 && r < 3) {
        rows[r][0] = rows[r][1] = rows[r][2] = rows[r][3] = 0.f;
      } else {
        const ushort4 x = *(const ushort4*)(Y + (tbase + tg * 8 - 3 + r) * NBIG + 2048 + h * 256 + c);
        rows[r][0] = bf2f(x.x); rows[r][1] = bf2f(x.y);
        rows[r][2] = bf2f(x.z); rows[r][3] = bf2f(x.w);
      }
    }
#pragma unroll
    for (int i = 0; i < 8; ++i) {
      const int t = tg * 8 + i;
      const float bt = beta_s[t];
#pragma unroll
      for (int e = 0; e < 4; ++e) {
        float a = wv[e].x * rows[i][e];
        a = fmaf(wv[e].y, rows[i + 1][e], a);
        a = fmaf(wv[e].z, rows[i + 2][e], a);
        a = fmaf(wv[e].w, rows[i + 3][e], a);
        VbT_s[(c + e) * 64 + t] = f2bf(bt * silu_f(a));
      }
    }
  }
  __syncthreads();   // Kb/Qb/VbT ready

  float xf[2][4];    // X fp32 master, per-thread (same tile indices in 4+5 and Newton B)
  // 4+5 fused: A_raw = K K^T; epilogue builds M = I+A, X0 = I-A (xf, Xrow0, Xt0)
  {
    f32x4 acc[2];
#pragma unroll
    for (int i = 0; i < 2; ++i)
#pragma unroll
      for (int r = 0; r < 4; ++r) acc[i][r] = 0.f;
    mm64_acc<128>(Kb_s, Kb_s, acc, w, row16, ko);
#pragma unroll
    for (int i = 0; i < 2; ++i) {
      const int ti = w + 8 * i;
      const int rt = ti >> 2, ct = ti & 3;
      const int r0 = rt * 16 + (l >> 4) * 4;
      const int col = ct * 16 + (l & 15);
#pragma unroll
      for (int r = 0; r < 4; ++r) {
        const int t = r0 + r, j = col;
        const float av = (j < t) ? beta_s[t] * __expf(carr_s[t] - carr_s[j]) * acc[i][r] : 0.f;
        const float dg = (t == j) ? 1.f : 0.f;
        Mb_s[t * 64 + j] = f2bf(dg + av);
        const float x0 = dg - av;
        xf[i][r] = x0;
        const unsigned short xb = f2bf(x0);
        Xrow_s[0][t * 64 + j] = xb;
        Xt_s[0][j * 64 + t] = xb;
      }
    }
  }
  __syncthreads();
  // 6. Newton x5: X <- X(2I - M X), 2 phases/iter, ping-pong X (exact: A nilpotent)
  int cur = 0;
  for (int it = 0; it < 5; ++it) {
    {  // Yt = (M X)^T  (transposed-write epilogue)
      f32x4 acc[2];
#pragma unroll
      for (int i = 0; i < 2; ++i)
#pragma unroll
        for (int r = 0; r < 4; ++r) acc[i][r] = 0.f;
      mm64_acc<64>(Mb_s, Xt_s[cur], acc, w, row16, ko);
#pragma unroll
      for (int i = 0; i < 2; ++i) {
        const int ti = w + 8 * i;
        const int rt = ti >> 2, ct = ti & 3;
        const int r0 = rt * 16 + (l >> 4) * 4;
        const int col = ct * 16 + (l & 15);
#pragma unroll
        for (int r = 0; r < 4; ++r)
          Yt_s[col * 64 + (r0 + r)] = f2bf(acc[i][r]);
      }
    }
    __syncthreads();
    {  // P = X Y ; X' = 2*xf - P  -> buffers cur^1 (no read/write overlap)
      f32x4 acc[2];
#pragma unroll
      for (int i = 0; i < 2; ++i)
#pragma unroll
        for (int r = 0; r < 4; ++r) acc[i][r] = 0.f;
      mm64_acc<64>(Xrow_s[cur], Yt_s, acc, w, row16, ko);
#pragma unroll
      for (int i = 0; i < 2; ++i) {
        const int ti = w + 8 * i;
        const int rt = ti >> 2, ct = ti & 3;
        const int r0 = rt * 16 + (l >> 4) * 4;
        const int col = ct * 16 + (l & 15);
#pragma unroll
        for (int r = 0; r < 4; ++r) {
          const float xn = 2.f * xf[i][r] - acc[i][r];
          xf[i][r] = xn;
          const unsigned short xb = f2bf(xn);
          Xrow_s[cur ^ 1][(r0 + r) * 64 + col] = xb;
          Xt_s[cur ^ 1][col * 64 + (r0 + r)] = xb;
        }
      }
    }
    cur ^= 1;
    __syncthreads();
  }
  const unsigned short* Xfin = Xrow_s[cur];
  const float ctot = carr_s[63];
  // 7+8 fused: Att = mask(exp) o (Q K^T) -> global directly
  {
    f32x4 acc[2];
#pragma unroll
    for (int i = 0; i < 2; ++i)
#pragma unroll
      for (int r = 0; r < 4; ++r) acc[i][r] = 0.f;
    mm64_acc<128>(Qb_s, Kb_s, acc, w, row16, ko);
#pragma unroll
    for (int i = 0; i < 2; ++i) {
      const int ti = w + 8 * i;
      const int rt = ti >> 2, ct = ti & 3;
      const int r0 = rt * 16 + (l >> 4) * 4;
      const int col = ct * 16 + (l & 15);
#pragma unroll
      for (int r = 0; r < 4; ++r) {
        const int t = r0 + r, j = col;
        const float av = (j <= t) ? __expf(carr_s[t] - carr_s[j]) * acc[i][r] : 0.f;
        Attg[(size_t)ch * 4096 + t * 64 + j] = f2bf(av);
      }
    }
  }
  // Qg, KgT -> global (elementwise from Qb/Kb)
#pragma unroll
  for (int i = 0; i < 16; ++i) {
    const int idx = i * 512 + tid;
    const int t = idx >> 7;
    Qgg[(size_t)ch * 8192 + idx] = f2bf(__expf(carr_s[t]) * bf2f(Qb_s[idx]));
  }
#pragma unroll
  for (int i = 0; i < 16; ++i) {
    const int idx = i * 512 + tid;
    const int d = idx >> 6, t = idx & 63;
    KgTg[(size_t)ch * 8192 + idx] = f2bf(__expf(ctot - carr_s[t]) * bf2f(Kb_s[t * 128 + d]));
  }
  __syncthreads();   // Qb reads done before reuse
  // 9. KbgT[d][t] = bf16(beta_t exp(c_t) k[t][d])  (into Qb space)
  unsigned short* KbgT = Qb_s;
#pragma unroll
  for (int i = 0; i < 16; ++i) {
    const int idx = i * 512 + tid;
    const int d = idx >> 6, t = idx & 63;
    KbgT[idx] = f2bf(beta_s[t] * __expf(carr_s[t]) * bf2f(Kb_s[t * 128 + d]));
  }
  __syncthreads();
  // 10. W = T (betaG.K)  [64x128];  Ub = T (betaV)  [64x256]  -> global bf16
  mm_nt_lds<64, 128, 64, 8>(Xfin, KbgT, Wg + (size_t)ch * 8192, 128, tid);
  mm_nt_lds<64, 256, 64, 8>(Xfin, VbT_s, Ubg + (size_t)ch * 16384, 256, tid);
}

// ---------------- phase 2: serial chunk recurrence (MFMA), 16 bh x 16 v-blocks, 512 thr ----------------
// 256 blocks (1/CU). Same-bh blocks land on one XCD (blk%8 = bh%8) -> staged data L2-shared.
// stage buffer (ushort offsets): W@0(8192) Att@8192(4096) Qg@12288(8192) KgT@20480(8192) Ub@28672(1024)
__device__ __forceinline__ void p2_stage(
    const unsigned short* Wg, const unsigned short* Attg, const unsigned short* Qgg,
    const unsigned short* KgTg, const unsigned short* Ubg,
    int ch, int vb, unsigned short* buf, int tid) {
#pragma unroll
  for (int i = 0; i < 2; ++i) {
    const int f = i * 512 + tid;
    GLDS(Wg + (size_t)ch * 8192 + f * 8, (char*)buf + f * 16);
  }
  {
    const int f = tid;
    GLDS(Attg + (size_t)ch * 4096 + f * 8, (char*)(buf + 8192) + f * 16);
  }
#pragma unroll
  for (int i = 0; i < 2; ++i) {
    const int f = i * 512 + tid;
    GLDS(Qgg + (size_t)ch * 8192 + f * 8, (char*)(buf + 12288) + f * 16);
  }
#pragma unroll
  for (int i = 0; i < 2; ++i) {
    const int f = i * 512 + tid;
    GLDS(KgTg + (size_t)ch * 8192 + f * 8, (char*)(buf + 20480) + f * 16);
  }
  if (tid < 128) {                   // Ub slice: 64 t x 16 cols
    const int f = tid;
    const int t = f >> 1, c8 = f & 1;
    GLDS(Ubg + (size_t)ch * 16384 + t * 256 + vb * 16 + c8 * 8, (char*)(buf + 28672) + f * 16);
  }
}

__global__ __launch_bounds__(512, 1) void scan_chunks(
    const unsigned short* __restrict__ Wg, const unsigned short* __restrict__ Ubg,
    const unsigned short* __restrict__ Attg, const unsigned short* __restrict__ Qgg,
    const unsigned short* __restrict__ KgTg, const float* __restrict__ decg,
    float* __restrict__ osc) {
  __shared__ float StT_s[16 * 128];            // S^T fp32 [vcol][d]
  __shared__ unsigned short StTb_s[16 * 128];  // S^T bf16
  __shared__ unsigned short uT_s[16 * 64];     // u^T bf16 [vcol][t]
  __shared__ unsigned short stage_s[2][29696];

  const int tid = threadIdx.x;
  const int w = tid >> 6, l = tid & 63;
  const int row = l & 15, ko = (l >> 4) * 8;
  const int blk = blockIdx.x;                  // vb*16 + bh  (same-bh blocks share an XCD)
  const int vb = blk >> 4, bh = blk & 15;
  const int b = bh >> 3, h = bh & 7;
  const bool uw = (w < 4);                     // u/O phases use 4 waves (4 tiles of 64x16)

  for (int i = tid; i < 2048; i += 512) { StT_s[i] = 0.f; StTb_s[i] = 0; }
  p2_stage(Wg, Attg, Qgg, KgTg, Ubg, bh * 16, vb, stage_s[0], tid);

  for (int p = 0; p < 16; ++p) {
    unsigned short* bufc = stage_s[p & 1];
    const unsigned short* Wl   = bufc;
    const unsigned short* Attl = bufc + 8192;
    const unsigned short* Qgl  = bufc + 12288;
    const unsigned short* KgTl = bufc + 20480;
    const unsigned short* Ubl  = bufc + 28672;
    __syncthreads();   // staged buf + previous S writes visible (vmcnt drained)

    // ---- u = Ub - W S : acc [64x16], 4 tiles, waves 0-3 ----
    f32x4 uacc;
#pragma unroll
    for (int r = 0; r < 4; ++r) uacc[r] = 0.f;
    if (uw) {
#pragma unroll
      for (int kk = 0; kk < 4; ++kk) {
        bf16x8 af = *(const bf16x8*)(Wl + (w * 16 + row) * 128 + kk * 32 + ko);
        bf16x8 bf = *(const bf16x8*)(StTb_s + row * 128 + kk * 32 + ko);
        uacc = __builtin_amdgcn_mfma_f32_16x16x32_bf16(af, bf, uacc, 0, 0, 0);
      }
      const int r0 = w * 16 + (l >> 4) * 4;
      const int col = l & 15;
#pragma unroll
      for (int r = 0; r < 4; ++r) {
        const int t = r0 + r;
        const float ubv = bf2f(Ubl[t * 16 + col]);
        uT_s[col * 64 + t] = f2bf(ubv - uacc[r]);
      }
    }
    __syncthreads();   // uT ready
    if (p < 15)
      p2_stage(Wg, Attg, Qgg, KgTg, Ubg, bh * 16 + p + 1, vb, stage_s[(p + 1) & 1], tid);

    // ---- O = Qg S + Att u : acc [64x16], waves 0-3 ----
    f32x4 oacc;
#pragma unroll
    for (int r = 0; r < 4; ++r) oacc[r] = 0.f;
    if (uw) {
#pragma unroll
      for (int kk = 0; kk < 4; ++kk) {
        bf16x8 af = *(const bf16x8*)(Qgl + (w * 16 + row) * 128 + kk * 32 + ko);
        bf16x8 bf = *(const bf16x8*)(StTb_s + row * 128 + kk * 32 + ko);
        oacc = __builtin_amdgcn_mfma_f32_16x16x32_bf16(af, bf, oacc, 0, 0, 0);
      }
#pragma unroll
      for (int kk = 0; kk < 2; ++kk) {
        bf16x8 af = *(const bf16x8*)(Attl + (w * 16 + row) * 64 + kk * 32 + ko);
        bf16x8 bf = *(const bf16x8*)(uT_s + row * 64 + kk * 32 + ko);
        oacc = __builtin_amdgcn_mfma_f32_16x16x32_bf16(af, bf, oacc, 0, 0, 0);
      }
    }
    // ---- Snew^T = dec*S^T + (u^T)(KgT^T) : acc [16x128], 8 tiles, 1/wave ----
    f32x4 sacc;
#pragma unroll
    for (int r = 0; r < 4; ++r) sacc[r] = 0.f;
#pragma unroll
    for (int kk = 0; kk < 2; ++kk) {
      bf16x8 af = *(const bf16x8*)(uT_s + row * 64 + kk * 32 + ko);
      bf16x8 bf = *(const bf16x8*)(KgTl + (w * 16 + row) * 64 + kk * 32 + ko);
      sacc = __builtin_amdgcn_mfma_f32_16x16x32_bf16(af, bf, sacc, 0, 0, 0);
    }
    const float dec = decg[bh * 16 + p];
    __syncthreads();   // all reads of StT/StTb/uT done before overwrite

    // epilogues
    if (uw) {
      const int r0 = w * 16 + (l >> 4) * 4;
      const int col = l & 15;
#pragma unroll
      for (int r = 0; r < 4; ++r) {
        const size_t trow = (size_t)b * T_LEN + p * 64 + r0 + r;
        osc[(trow * 8 + h) * 256 + vb * 16 + col] = oacc[r];
      }
    }
    {
      const int cold = w * 16 + (l & 15);
#pragma unroll
      for (int r = 0; r < 4; ++r) {
        const int idx = ((l >> 4) * 4 + r) * 128 + cold;
        const float sn = fmaf(dec, StT_s[idx], sacc[r]);
        StT_s[idx] = sn;
        StTb_s[idx] = f2bf(sn);
      }
    }
  }
}

// ---------------- gated RMSNorm + silu(gate) -> bf16 ----------------
__global__ __launch_bounds__(256) void rmsgate(
    const float* __restrict__ ob, const unsigned short* __restrict__ Y,
    const float* __restrict__ onw, unsigned short* __restrict__ Obf) {
  const int bt = blockIdx.x;
  const int tid = threadIdx.x;
  const int c = tid * 8;                // head = c/256 = tid/32
  const float* orow = ob + (size_t)bt * 2048 + c;
  const unsigned short* grow = Y + (size_t)bt * NBIG + 4096 + c;
  const float4 o0 = *(const float4*)orow, o1 = *(const float4*)(orow + 4);
  const ushort4 g0 = *(const ushort4*)grow, g1 = *(const ushort4*)(grow + 4);
  const float ov[8] = {o0.x, o0.y, o0.z, o0.w, o1.x, o1.y, o1.z, o1.w};
  const float gv[8] = {bf2f(g0.x), bf2f(g0.y), bf2f(g0.z), bf2f(g0.w),
                       bf2f(g1.x), bf2f(g1.y), bf2f(g1.z), bf2f(g1.w)};
  float ss = 0.f;
#pragma unroll
  for (int e = 0; e < 8; ++e) ss += ov[e] * ov[e];
#pragma unroll
  for (int m = 16; m >= 1; m >>= 1) ss += __shfl_xor(ss, m);
  const float rn = rsqrtf(ss * (1.f / 256.f) + 1e-5f);
  const int dv = c & 255;
  unsigned short rr[8];
#pragma unroll
  for (int e = 0; e < 8; ++e) {
    const float val = ov[e] * rn * onw[dv + e] * silu_f(gv[e]);
    rr[e] = f2bf(val);
  }
  ushort4 r0 = {rr[0], rr[1], rr[2], rr[3]};
  ushort4 r1 = {rr[4], rr[5], rr[6], rr[7]};
  *(ushort4*)(Obf + (size_t)bt * 2048 + c) = r0;
  *(ushort4*)(Obf + (size_t)bt * 2048 + c + 4) = r1;
}

extern "C" void kernel_launch(void* const* d_in, const int* in_sizes, int n_in,
                              void* d_out, int out_size, void* d_ws, size_t ws_size,
                              hipStream_t stream) {
  (void)in_sizes; (void)n_in; (void)out_size; (void)ws_size;
  const float* h    = (const float*)d_in[0];
  const float* qw   = (const float*)d_in[1];
  const float* kw   = (const float*)d_in[2];
  const float* vw   = (const float*)d_in[3];
  const float* aw   = (const float*)d_in[4];
  const float* bw   = (const float*)d_in[5];
  const float* gw   = (const float*)d_in[6];
  const float* ow   = (const float*)d_in[7];
  const float* qcw  = (const float*)d_in[8];
  const float* kcw  = (const float*)d_in[9];
  const float* vcw  = (const float*)d_in[10];
  const float* Alog = (const float*)d_in[11];
  const float* dtb  = (const float*)d_in[12];
  const float* onw  = (const float*)d_in[13];

  char* ws = (char*)d_ws;
  size_t off = 0;
  auto alloc = [&](size_t bytes) {
    char* p = ws + off;
    off = (off + bytes + 255) & ~(size_t)255;
    return p;
  };
  unsigned short* hbf  = (unsigned short*)alloc(2048ull * 2048 * 2);
  unsigned short* Wb   = (unsigned short*)alloc((size_t)NBIG * 2048 * 2);
  unsigned short* owb  = (unsigned short*)alloc(2048ull * 2048 * 2);
  unsigned short* Ybf  = (unsigned short*)alloc(2048ull * NBIG * 2);
  float* osc           = (float*)alloc(2048ull * 2048 * 4);
  unsigned short* Obf  = (unsigned short*)alloc(2048ull * 2048 * 2);
  unsigned short* Wg   = (unsigned short*)alloc(256ull * 8192 * 2);
  unsigned short* Ubg  = (unsigned short*)alloc(256ull * 16384 * 2);
  unsigned short* Attg = (unsigned short*)alloc(256ull * 4096 * 2);
  unsigned short* Qgg  = (unsigned short*)alloc(256ull * 8192 * 2);
  unsigned short* KgTg = (unsigned short*)alloc(256ull * 8192 * 2);
  float* decg          = (float*)alloc(256ull * 4);

  cvt_bf16<<<4096, 256, 0, stream>>>(h, hbf, 1048576);
  build_w<<<12800, 256, 0, stream>>>(qw, kw, vw, gw, aw, bw, Wb);
  cvt_bf16<<<4096, 256, 0, stream>>>(ow, owb, 1048576);
  zero_f32<<<4096, 256, 0, stream>>>((float*)d_out, 1048576);
  // GEMM1: 16 x 25 tiles of 128x256 -> 400 blocks (R9-measured best config)
  gemm_pipe<256, 4, 512, true, false><<<400, 512, 0, stream>>>(
      (const bf16*)hbf, (const bf16*)Wb, Ybf, NBIG, 2048, 2048);
  chunk_prep<<<256, 512, 0, stream>>>(Ybf, qcw, kcw, vcw, Alog, dtb,
                                      Wg, Ubg, Attg, Qgg, KgTg, decg);
  scan_chunks<<<256, 512, 0, stream>>>(Wg, Ubg, Attg, Qgg, KgTg, decg, osc);
  rmsgate<<<2048, 256, 0, stream>>>(osc, Ybf, onw, Obf);
  // GEMM2: K-split x2 -> 512 blocks (2/CU), fp32 atomicAdd epilogue (2 contribs/addr)
  gemm_pipe<128, 2, 256, false, true><<<512, 256, 0, stream>>>(
      (const bf16*)Obf, (const bf16*)owb, d_out, 2048, 1024, 2048);
}

// Round 14
// 215.137 us; speedup vs baseline: 1.2480x; 1.0267x over previous
//
#include <hip/hip_runtime.h>
#include <cstdint>

#define T_LEN 1024
#define NBIG  6400     // padded N for fused projection GEMM (6160 real cols, 25 x 256 tiles)
#define SCALE_Q 0.08838834764831843f   // DK^-0.5

typedef __bf16 bf16;
typedef __bf16 bf16x8 __attribute__((ext_vector_type(8)));
typedef float  f32x4  __attribute__((ext_vector_type(4)));

__device__ __forceinline__ unsigned short f2bf(float f) {
  unsigned int u = __builtin_bit_cast(unsigned int, f);
  u += 0x7FFFu + ((u >> 16) & 1u);          // RNE
  return (unsigned short)(u >> 16);
}
__device__ __forceinline__ float bf2f(unsigned short u) {
  return __builtin_bit_cast(float, (unsigned int)u << 16);
}
__device__ __forceinline__ float silu_f(float x) { return x / (1.f + __expf(-x)); }

#define GLDS(src, dst) \
  __builtin_amdgcn_global_load_lds( \
      (__attribute__((address_space(1))) void*)(void*)(src), \
      (__attribute__((address_space(3))) void*)(void*)(dst), 16, 0, 0)

// ---------------- fused prologue: cvt(h), build_w, cvt(ow), zero(d_out) ----------------
// one dispatch, 25088 blocks of 256: [0,4096) h->hbf, [4096,16896) W concat,
// [16896,20992) ow->owb, [20992,25088) zero d_out.
__global__ __launch_bounds__(256) void prep_all(
    const float* __restrict__ h, const float* __restrict__ ow,
    const float* __restrict__ qw, const float* __restrict__ kw,
    const float* __restrict__ vw, const float* __restrict__ gw,
    const float* __restrict__ aw, const float* __restrict__ bw,
    unsigned short* __restrict__ hbf, unsigned short* __restrict__ owb,
    unsigned short* __restrict__ Wb, float* __restrict__ zout) {
  const int blk = blockIdx.x;
  const int tid = threadIdx.x;
  if (blk < 4096) {
    const int idx = blk * 256 + tid;
    float4 f = ((const float4*)h)[idx];
    ushort4 o = { f2bf(f.x), f2bf(f.y), f2bf(f.z), f2bf(f.w) };
    ((ushort4*)hbf)[idx] = o;
  } else if (blk < 16896) {
    const int idx = (blk - 4096) * 256 + tid;
    const int r = idx >> 9;
    const int c = (idx & 511) << 2;
    const float* src;
    if      (r < 1024) src = qw + (size_t)r * 2048;
    else if (r < 2048) src = kw + (size_t)(r - 1024) * 2048;
    else if (r < 4096) src = vw + (size_t)(r - 2048) * 2048;
    else if (r < 6144) src = gw + (size_t)(r - 4096) * 2048;
    else if (r < 6152) src = aw + (size_t)(r - 6144) * 2048;
    else if (r < 6160) src = bw + (size_t)(r - 6152) * 2048;
    else               src = nullptr;
    ushort4 o;
    if (src) {
      float4 f = *(const float4*)(src + c);
      o = { f2bf(f.x), f2bf(f.y), f2bf(f.z), f2bf(f.w) };
    } else {
      o = { 0, 0, 0, 0 };
    }
    *(ushort4*)(Wb + (size_t)r * 2048 + c) = o;
  } else if (blk < 20992) {
    const int idx = (blk - 16896) * 256 + tid;
    float4 f = ((const float4*)ow)[idx];
    ushort4 o = { f2bf(f.x), f2bf(f.y), f2bf(f.z), f2bf(f.w) };
    ((ushort4*)owb)[idx] = o;
  } else {
    const int idx = (blk - 20992) * 256 + tid;
    float4 z = {0.f, 0.f, 0.f, 0.f};
    ((float4*)zout)[idx] = z;
  }
}

// ============ pipelined NT GEMM: BM=128 x BN tile, BK=32, ring-3 LDS, counted vmcnt ============
// C[M][N] = A[M][K_total] * B[N][K_total]^T over a K-slice. bf16 in. T threads = T/64 waves.
// If ATOMIC: grid = 2*nInner, block bid>>8 handles K-half, epilogue atomicAdd fp32
// (exactly 2 contributions/addr -> deterministic).
// R6-proven schedule: per K-step { STAGE(kt+2); setprio(1); 16 MFMA; setprio(0);
// lgkmcnt(0); vmcnt(LOADS); s_barrier; ds_read next frags }. vmcnt never drains to 0.
// LDS swizzle (0-conflict, R4-verified): logical k-slot s of row r at phys s ^ ((r>>1)&3).
template <int BN, int WN, int T, bool BF16OUT, bool ATOMIC>
__global__ __launch_bounds__(T, 4) void gemm_pipe(
    const bf16* __restrict__ A, const bf16* __restrict__ Bm,
    void* __restrict__ Cv, int N, int K, int ldk) {
  constexpr int AI = (128 * 32) / (T * 8);   // A glds insts/thread per K-tile
  constexpr int BI = (BN * 32) / (T * 8);    // B glds insts/thread per K-tile
  constexpr int LOADS = AI + BI;
  __shared__ bf16 LA[3][128 * 32];
  __shared__ bf16 LB[3][BN * 32];
  const int tid = threadIdx.x;
  const int lane = tid & 63;
  const int wid = tid >> 6;
  const int wm = wid / WN, wn = wid % WN;
  // XCD-chunked bijective block map: xcd owns m-rows {xcd, xcd+8} x all n-tiles
  const int bidAll = blockIdx.x;
  const int bid = ATOMIC ? (bidAll & 255) : bidAll;
  const long kofs = ATOMIC ? (long)(bidAll >> 8) * K : 0;
  const int xcd = bid & 7, jj = bid >> 3;
  const long brow = (long)(xcd + 8 * (jj & 1)) * 128;
  const long bcol = (long)(jj >> 1) * BN;

  f32x4 acc[4][4];
#pragma unroll
  for (int m = 0; m < 4; ++m)
#pragma unroll
    for (int n = 0; n < 4; ++n)
#pragma unroll
      for (int r = 0; r < 4; ++r) acc[m][n][r] = 0.f;

  // staging map: flat slot = e*T + tid -> (row = flat>>2, pslot = flat&3);
  // global source col = (pslot ^ ((row>>1)&3)) * 8  (inverse swizzle, linear LDS dest)
  const bf16* AgS[AI];
  const bf16* BgS[BI];
  int adst[AI], bdst[BI];
#pragma unroll
  for (int e = 0; e < AI; ++e) {
    const int flat = e * T + tid;
    const int row = flat >> 2;
    const int sl = (flat & 3) ^ ((row >> 1) & 3);
    AgS[e] = A + (brow + row) * (long)ldk + kofs + sl * 8;
    adst[e] = flat * 8;
  }
#pragma unroll
  for (int e = 0; e < BI; ++e) {
    const int flat = e * T + tid;
    const int row = flat >> 2;
    const int sl = (flat & 3) ^ ((row >> 1) & 3);
    BgS[e] = Bm + (bcol + row) * (long)ldk + kofs + sl * 8;
    bdst[e] = flat * 8;
  }

#define STAGE(kt, sb)                                              \
  {                                                                \
    const long ko = (long)(kt) * 32;                               \
    _Pragma("unroll")                                              \
    for (int e = 0; e < AI; ++e) GLDS(AgS[e] + ko, &LA[sb][0] + adst[e]); \
    _Pragma("unroll")                                              \
    for (int e = 0; e < BI; ++e) GLDS(BgS[e] + ko, &LB[sb][0] + bdst[e]); \
  }
#define WAIT_VM()                                                  \
  if constexpr (LOADS == 3) asm volatile("s_waitcnt vmcnt(3)" ::: "memory"); \
  else                      asm volatile("s_waitcnt vmcnt(4)" ::: "memory");

  // read offsets (halfwords): row*32 + (ks ^ ((r16>>1)&3))*8
  const int r16 = lane & 15;
  const int ks = lane >> 4;
  const int pso = (ks ^ ((r16 >> 1) & 3)) * 8;
  int rdA[4], rdB[4];
#pragma unroll
  for (int i = 0; i < 4; ++i) rdA[i] = (wm * 64 + i * 16 + r16) * 32 + pso;
#pragma unroll
  for (int j = 0; j < 4; ++j) rdB[j] = (wn * 64 + j * 16 + r16) * 32 + pso;

  const int nkt = K >> 5;
  STAGE(0, 0);
  STAGE(1, 1);
  WAIT_VM();                         // buf0 landed (stage(1) may stay in flight)
  __builtin_amdgcn_s_barrier();

  bf16x8 af[4], bfr[4];
#pragma unroll
  for (int i = 0; i < 4; ++i) af[i] = *(const bf16x8*)(&LA[0][0] + rdA[i]);
#pragma unroll
  for (int j = 0; j < 4; ++j) bfr[j] = *(const bf16x8*)(&LB[0][0] + rdB[j]);

  for (int kt = 0; kt < nkt; ++kt) {
    const int kts = (kt + 2 < nkt) ? kt + 2 : nkt - 1;  // clamp src, keep count uniform
    const int sb = (kt + 2) % 3;                        // == (kt-1)%3: read-complete slot
    const int nb = (kt + 1) % 3;

    STAGE(kts, sb);
    __builtin_amdgcn_s_setprio(1);
#pragma unroll
    for (int i = 0; i < 4; ++i)
#pragma unroll
      for (int j = 0; j < 4; ++j)
        acc[i][j] = __builtin_amdgcn_mfma_f32_16x16x32_bf16(af[i], bfr[j], acc[i][j], 0, 0, 0);
    __builtin_amdgcn_s_setprio(0);

    asm volatile("s_waitcnt lgkmcnt(0)" ::: "memory");
    WAIT_VM();                       // kt+1 landed; kt+2 stays in flight
    __builtin_amdgcn_s_barrier();
#pragma unroll
    for (int i = 0; i < 4; ++i) af[i] = *(const bf16x8*)(&LA[nb][0] + rdA[i]);
#pragma unroll
    for (int j = 0; j < 4; ++j) bfr[j] = *(const bf16x8*)(&LB[nb][0] + rdB[j]);
  }
#undef STAGE
#undef WAIT_VM

  // epilogue: C/D layout col=lane&15, row=(lane>>4)*4+r
  const long row0 = brow + wm * 64 + ((lane >> 4) * 4);
  const long col0 = bcol + wn * 64 + (lane & 15);
#pragma unroll
  for (int m = 0; m < 4; ++m)
#pragma unroll
    for (int n = 0; n < 4; ++n)
#pragma unroll
      for (int r = 0; r < 4; ++r) {
        const long idx = (row0 + m * 16 + r) * (long)N + col0 + n * 16;
        if constexpr (ATOMIC)
          atomicAdd((float*)Cv + idx, acc[m][n][r]);
        else if constexpr (BF16OUT)
          ((unsigned short*)Cv)[idx] = f2bf(acc[m][n][r]);
        else
          ((float*)Cv)[idx] = acc[m][n][r];
      }
}

// ---------------- small NT GEMM on LDS operands: OUT[i][j] = sum_k A[i][k]*B[j][k] ----------------
// A: [M][K] bf16 LDS, B: [N][K] bf16 LDS. NW waves. Output bf16 global (ldg).
template <int M, int N, int K, int NW>
__device__ __forceinline__ void mm_nt_lds(const unsigned short* A, const unsigned short* B,
                                          unsigned short* outG, int ldg, int tid) {
  constexpr int NT16 = N / 16;
  constexpr int PW = (M / 16) * NT16 / NW;
  const int w = tid >> 6, l = tid & 63;
  const int row = l & 15, ko = (l >> 4) * 8;
  f32x4 acc[PW];
#pragma unroll
  for (int i = 0; i < PW; ++i)
#pragma unroll
    for (int r = 0; r < 4; ++r) acc[i][r] = 0.f;
#pragma unroll
  for (int i = 0; i < PW; ++i) {
    const int ti = w + NW * i;
    const int rt = ti / NT16, ct = ti % NT16;
#pragma unroll
    for (int kk = 0; kk < K / 32; ++kk) {
      bf16x8 af = *(const bf16x8*)(A + (rt * 16 + row) * K + kk * 32 + ko);
      bf16x8 bf = *(const bf16x8*)(B + (ct * 16 + row) * K + kk * 32 + ko);
      acc[i] = __builtin_amdgcn_mfma_f32_16x16x32_bf16(af, bf, acc[i], 0, 0, 0);
    }
  }
#pragma unroll
  for (int i = 0; i < PW; ++i) {
    const int ti = w + NW * i;
    const int rt = ti / NT16, ct = ti % NT16;
    const int r0 = rt * 16 + (l >> 4) * 4;
    const int col = ct * 16 + (l & 15);
#pragma unroll
    for (int r = 0; r < 4; ++r)
      outG[(size_t)(r0 + r) * ldg + col] = f2bf(acc[i][r]);
  }
}

// 64x64 NT MFMA accumulate (8 waves, 2 tiles/wave), epilogue left to caller
template <int K>
__device__ __forceinline__ void mm64_acc(const unsigned short* A, const unsigned short* B,
                                         f32x4 acc[2], int w, int row, int ko) {
#pragma unroll
  for (int i = 0; i < 2; ++i) {
    const int ti = w + 8 * i;
    const int rt = ti >> 2, ct = ti & 3;
#pragma unroll
    for (int kk = 0; kk < K / 32; ++kk) {
      bf16x8 af = *(const bf16x8*)(A + (rt * 16 + row) * K + kk * 32 + ko);
      bf16x8 bf = *(const bf16x8*)(B + (ct * 16 + row) * K + kk * 32 + ko);
      acc[i] = __builtin_amdgcn_mfma_f32_16x16x32_bf16(af, bf, acc[i], 0, 0, 0);
    }
  }
}

// ---------------- phase 1: conv+norm fused + per-chunk UT transform (C=64), 512 threads ----------------
// LDS overlaid to 73 KB -> 2 blocks/CU (was 112 KB -> 1/CU): Newton scratch {Mb,Xt,Yt}
// and VbT time-share one 32 KB region (v-conv runs AFTER Newton, scratch then dead).
// X updated in place (mid-phase barrier separates reads from writes; 3 barriers/Newton iter).
__global__ __launch_bounds__(512, 4) void chunk_prep(
    const unsigned short* __restrict__ Y,
    const float* __restrict__ qcw, const float* __restrict__ kcw, const float* __restrict__ vcw,
    const float* __restrict__ A_log, const float* __restrict__ dt_bias,
    unsigned short* __restrict__ Wg, unsigned short* __restrict__ Ubg,
    unsigned short* __restrict__ Attg, unsigned short* __restrict__ Qgg,
    unsigned short* __restrict__ KgTg, float* __restrict__ decg) {
  __shared__ unsigned short SM[36864];          // 72 KB overlay arena
  unsigned short* Kb_s   = SM;                  // [64][128]   8192 us
  unsigned short* Qb_s   = SM + 8192;           // [64][128]   8192 us (later KbgT)
  unsigned short* Xrow_s = SM + 16384;          // [64][64]    4096 us
  unsigned short* Mb_s   = SM + 20480;          // [64][64]    4096 us (scratch)
  unsigned short* Xt_s   = SM + 24576;          // [64][64]    4096 us (scratch)
  unsigned short* Yt_s   = SM + 28672;          // [64][64]    4096 us (scratch)
  unsigned short* VbT_s  = SM + 20480;          // [256][64]  16384 us (overlays scratch)
  __shared__ float carr_s[64];
  __shared__ float beta_s[64];

  const int tid = threadIdx.x;
  const int w = tid >> 6, l = tid & 63;
  const int row16 = l & 15, ko = (l >> 4) * 8;
  const int ch = blockIdx.x;
  const int bh = ch >> 4, p = ch & 15;
  const int b = bh >> 3, h = bh & 7;
  const size_t tbase = (size_t)b * T_LEN + p * 64;
  const bool head = (p == 0);

  // 1. per-step scalars + cumulative log-decay (wave 0, from Y directly)
  if (tid < 64) {
    const unsigned short* Yr = Y + (tbase + tid) * NBIG;
    float a = bf2f(Yr[6144 + h]) + dt_bias[h];
    float sp = (a > 20.f) ? a : log1pf(expf(a));
    float g = -expf(A_log[h]) * sp;
    float bp = bf2f(Yr[6152 + h]);
    beta_s[tid] = 1.f / (1.f + expf(-bp));
    float c = g;
#pragma unroll
    for (int d = 1; d < 64; d <<= 1) {
      float y = __shfl_up(c, d);
      if (tid >= d) c += y;
    }
    carr_s[tid] = c;
    if (tid == 63) decg[ch] = __expf(c);
  }
  __syncthreads();   // beta/carr ready

  // 2. conv+SiLU+l2norm for q (waves 0-3) and k (waves 4-7) -> Qb_s/Kb_s [64][128]
  {
    const bool isQ = (tid < 256);
    const int wk = tid & 255;
    const int quad = wk & 31, tg = wk >> 5;     // 32 quads x 8 t-groups (8 t each)
    const int c = quad * 4;
    const float* cw = isQ ? qcw : kcw;
    const int cb = (isQ ? 0 : 1024) + h * 128 + c;
    float4 wv[4];
#pragma unroll
    for (int e = 0; e < 4; ++e) wv[e] = ((const float4*)cw)[h * 128 + c + e];
    float rows[11][4];
#pragma unroll
    for (int r = 0; r < 11; ++r) {
      if (head && tg == 0 && r < 3) {
        rows[r][0] = rows[r][1] = rows[r][2] = rows[r][3] = 0.f;
      } else {
        const ushort4 x = *(const ushort4*)(Y + (tbase + tg * 8 - 3 + r) * NBIG + cb);
        rows[r][0] = bf2f(x.x); rows[r][1] = bf2f(x.y);
        rows[r][2] = bf2f(x.z); rows[r][3] = bf2f(x.w);
      }
    }
    unsigned short* dst = isQ ? Qb_s : Kb_s;
    const float sc = isQ ? SCALE_Q : 1.f;
#pragma unroll
    for (int i = 0; i < 8; ++i) {
      float acc[4], ss = 0.f;
#pragma unroll
      for (int e = 0; e < 4; ++e) {
        float a = wv[e].x * rows[i][e];
        a = fmaf(wv[e].y, rows[i + 1][e], a);
        a = fmaf(wv[e].z, rows[i + 2][e], a);
        a = fmaf(wv[e].w, rows[i + 3][e], a);
        a = silu_f(a);
        acc[e] = a;
        ss += a * a;
      }
#pragma unroll
      for (int m = 16; m >= 1; m >>= 1) ss += __shfl_xor(ss, m);
      const float rn = rsqrtf(ss + 1e-6f) * sc;
      ushort4 o = {f2bf(acc[0] * rn), f2bf(acc[1] * rn), f2bf(acc[2] * rn), f2bf(acc[3] * rn)};
      *(ushort4*)(dst + (tg * 8 + i) * 128 + c) = o;
    }
  }
  __syncthreads();   // Kb/Qb ready

  float xf[2][4];    // X fp32 master, per-thread (same tile indices across phases)
  // 4+5 fused: A_raw = K K^T; epilogue builds M = I+A, X0 = I-A (xf, Xrow, Xt)
  {
    f32x4 acc[2];
#pragma unroll
    for (int i = 0; i < 2; ++i)
#pragma unroll
      for (int r = 0; r < 4; ++r) acc[i][r] = 0.f;
    mm64_acc<128>(Kb_s, Kb_s, acc, w, row16, ko);
#pragma unroll
    for (int i = 0; i < 2; ++i) {
      const int ti = w + 8 * i;
      const int rt = ti >> 2, ct = ti & 3;
      const int r0 = rt * 16 + (l >> 4) * 4;
      const int col = ct * 16 + (l & 15);
#pragma unroll
      for (int r = 0; r < 4; ++r) {
        const int t = r0 + r, j = col;
        const float av = (j < t) ? beta_s[t] * __expf(carr_s[t] - carr_s[j]) * acc[i][r] : 0.f;
        const float dg = (t == j) ? 1.f : 0.f;
        Mb_s[t * 64 + j] = f2bf(dg + av);
        const float x0 = dg - av;
        xf[i][r] = x0;
        const unsigned short xb = f2bf(x0);
        Xrow_s[t * 64 + j] = xb;
        Xt_s[j * 64 + t] = xb;
      }
    }
  }
  __syncthreads();
  // 6. Newton x5: X <- X(2I - M X), in place (exact: A nilpotent)
  for (int it = 0; it < 5; ++it) {
    {  // Yt = (M X)^T  (transposed-write epilogue; Yt disjoint from Mb/Xt)
      f32x4 acc[2];
#pragma unroll
      for (int i = 0; i < 2; ++i)
#pragma unroll
        for (int r = 0; r < 4; ++r) acc[i][r] = 0.f;
      mm64_acc<64>(Mb_s, Xt_s, acc, w, row16, ko);
#pragma unroll
      for (int i = 0; i < 2; ++i) {
        const int ti = w + 8 * i;
        const int rt = ti >> 2, ct = ti & 3;
        const int r0 = rt * 16 + (l >> 4) * 4;
        const int col = ct * 16 + (l & 15);
#pragma unroll
        for (int r = 0; r < 4; ++r)
          Yt_s[col * 64 + (r0 + r)] = f2bf(acc[i][r]);
      }
    }
    __syncthreads();
    {  // P = X Y ; X' = 2*xf - P   (in-place: barrier between reads and writes)
      f32x4 acc[2];
#pragma unroll
      for (int i = 0; i < 2; ++i)
#pragma unroll
        for (int r = 0; r < 4; ++r) acc[i][r] = 0.f;
      mm64_acc<64>(Xrow_s, Yt_s, acc, w, row16, ko);
      __syncthreads();   // all Xrow reads drained before overwrite
#pragma unroll
      for (int i = 0; i < 2; ++i) {
        const int ti = w + 8 * i;
        const int rt = ti >> 2, ct = ti & 3;
        const int r0 = rt * 16 + (l >> 4) * 4;
        const int col = ct * 16 + (l & 15);
#pragma unroll
        for (int r = 0; r < 4; ++r) {
          const float xn = 2.f * xf[i][r] - acc[i][r];
          xf[i][r] = xn;
          const unsigned short xb = f2bf(xn);
          Xrow_s[(r0 + r) * 64 + col] = xb;
          Xt_s[col * 64 + (r0 + r)] = xb;
        }
      }
    }
    __syncthreads();
  }
  const float ctot = carr_s[63];
  // 3 (moved): conv+SiLU for v, *beta, transposed -> VbT_s (overlays dead Newton scratch)
  {
    const int quad = tid & 63, tg = tid >> 6;   // 64 quads x 8 t-groups
    const int c = quad * 4;
    float4 wv[4];
#pragma unroll
    for (int e = 0; e < 4; ++e) wv[e] = ((const float4*)vcw)[h * 256 + c + e];
    float rows[11][4];
#pragma unroll
    for (int r = 0; r < 11; ++r) {
      if (head && tg == 0 && r < 3) {
        rows[r][0] = rows[r][1] = rows[r][2] = rows[r][3] = 0.f;
      } else {
        const ushort4 x = *(const ushort4*)(Y + (tbase + tg * 8 - 3 + r) * NBIG + 2048 + h * 256 + c);
        rows[r][0] = bf2f(x.x); rows[r][1] = bf2f(x.y);
        rows[r][2] = bf2f(x.z); rows[r][3] = bf2f(x.w);
      }
    }
#pragma unroll
    for (int i = 0; i < 8; ++i) {
      const int t = tg * 8 + i;
      const float bt = beta_s[t];
#pragma unroll
      for (int e = 0; e < 4; ++e) {
        float a = wv[e].x * rows[i][e];
        a = fmaf(wv[e].y, rows[i + 1][e], a);
        a = fmaf(wv[e].z, rows[i + 2][e], a);
        a = fmaf(wv[e].w, rows[i + 3][e], a);
        VbT_s[(c + e) * 64 + t] = f2bf(bt * silu_f(a));
      }
    }
  }
  // 7+8 fused: Att = mask(exp) o (Q K^T) -> global directly
  {
    f32x4 acc[2];
#pragma unroll
    for (int i = 0; i < 2; ++i)
#pragma unroll
      for (int r = 0; r < 4; ++r) acc[i][r] = 0.f;
    mm64_acc<128>(Qb_s, Kb_s, acc, w, row16, ko);
#pragma unroll
    for (int i = 0; i < 2; ++i) {
      const int ti = w + 8 * i;
      const int rt = ti >> 2, ct = ti & 3;
      const int r0 = rt * 16 + (l >> 4) * 4;
      const int col = ct * 16 + (l & 15);
#pragma unroll
      for (int r = 0; r < 4; ++r) {
        const int t = r0 + r, j = col;
        const float av = (j <= t) ? __expf(carr_s[t] - carr_s[j]) * acc[i][r] : 0.f;
        Attg[(size_t)ch * 4096 + t * 64 + j] = f2bf(av);
      }
    }
  }
  // Qg, KgT -> global (elementwise from Qb/Kb)
#pragma unroll
  for (int i = 0; i < 16; ++i) {
    const int idx = i * 512 + tid;
    const int t = idx >> 7;
    Qgg[(size_t)ch * 8192 + idx] = f2bf(__expf(carr_s[t]) * bf2f(Qb_s[idx]));
  }
#pragma unroll
  for (int i = 0; i < 16; ++i) {
    const int idx = i * 512 + tid;
    const int d = idx >> 6, t = idx & 63;
    KgTg[(size_t)ch * 8192 + idx] = f2bf(__expf(ctot - carr_s[t]) * bf2f(Kb_s[t * 128 + d]));
  }
  __syncthreads();   // Qb reads done before reuse; VbT writes visible
  // 9. KbgT[d][t] = bf16(beta_t exp(c_t) k[t][d])  (into Qb space)
  unsigned short* KbgT = Qb_s;
#pragma unroll
  for (int i = 0; i < 16; ++i) {
    const int idx = i * 512 + tid;
    const int d = idx >> 6, t = idx & 63;
    KbgT[idx] = f2bf(beta_s[t] * __expf(carr_s[t]) * bf2f(Kb_s[t * 128 + d]));
  }
  __syncthreads();
  // 10. W = T (betaG.K)  [64x128];  Ub = T (betaV)  [64x256]  -> global bf16
  mm_nt_lds<64, 128, 64, 8>(Xrow_s, KbgT, Wg + (size_t)ch * 8192, 128, tid);
  mm_nt_lds<64, 256, 64, 8>(Xrow_s, VbT_s, Ubg + (size_t)ch * 16384, 256, tid);
}

// ---------------- phase 2: serial chunk recurrence (MFMA), 16 bh x 16 v-blocks, 512 thr ----------------
// 256 blocks (1/CU). Same-bh blocks land on one XCD (blk%8 = bh%8) -> staged data L2-shared.
// stage buffer (ushort offsets): W@0(8192) Att@8192(4096) Qg@12288(8192) KgT@20480(8192) Ub@28672(1024)
__device__ __forceinline__ void p2_stage(
    const unsigned short* Wg, const unsigned short* Attg, const unsigned short* Qgg,
    const unsigned short* KgTg, const unsigned short* Ubg,
    int ch, int vb, unsigned short* buf, int tid) {
#pragma unroll
  for (int i = 0; i < 2; ++i) {
    const int f = i * 512 + tid;
    GLDS(Wg + (size_t)ch * 8192 + f * 8, (char*)buf + f * 16);
  }
  {
    const int f = tid;
    GLDS(Attg + (size_t)ch * 4096 + f * 8, (char*)(buf + 8192) + f * 16);
  }
#pragma unroll
  for (int i = 0; i < 2; ++i) {
    const int f = i * 512 + tid;
    GLDS(Qgg + (size_t)ch * 8192 + f * 8, (char*)(buf + 12288) + f * 16);
  }
#pragma unroll
  for (int i = 0; i < 2; ++i) {
    const int f = i * 512 + tid;
    GLDS(KgTg + (size_t)ch * 8192 + f * 8, (char*)(buf + 20480) + f * 16);
  }
  if (tid < 128) {                   // Ub slice: 64 t x 16 cols
    const int f = tid;
    const int t = f >> 1, c8 = f & 1;
    GLDS(Ubg + (size_t)ch * 16384 + t * 256 + vb * 16 + c8 * 8, (char*)(buf + 28672) + f * 16);
  }
}

__global__ __launch_bounds__(512, 1) void scan_chunks(
    const unsigned short* __restrict__ Wg, const unsigned short* __restrict__ Ubg,
    const unsigned short* __restrict__ Attg, const unsigned short* __restrict__ Qgg,
    const unsigned short* __restrict__ KgTg, const float* __restrict__ decg,
    float* __restrict__ osc) {
  __shared__ float StT_s[16 * 128];            // S^T fp32 [vcol][d]
  __shared__ unsigned short StTb_s[16 * 128];  // S^T bf16
  __shared__ unsigned short uT_s[16 * 64];     // u^T bf16 [vcol][t]
  __shared__ unsigned short stage_s[2][29696];

  const int tid = threadIdx.x;
  const int w = tid >> 6, l = tid & 63;
  const int row = l & 15, ko = (l >> 4) * 8;
  const int blk = blockIdx.x;                  // vb*16 + bh  (same-bh blocks share an XCD)
  const int vb = blk >> 4, bh = blk & 15;
  const int b = bh >> 3, h = bh & 7;
  const bool uw = (w < 4);                     // u/O phases use 4 waves (4 tiles of 64x16)

  for (int i = tid; i < 2048; i += 512) { StT_s[i] = 0.f; StTb_s[i] = 0; }
  p2_stage(Wg, Attg, Qgg, KgTg, Ubg, bh * 16, vb, stage_s[0], tid);

  for (int p = 0; p < 16; ++p) {
    unsigned short* bufc = stage_s[p & 1];
    const unsigned short* Wl   = bufc;
    const unsigned short* Attl = bufc + 8192;
    const unsigned short* Qgl  = bufc + 12288;
    const unsigned short* KgTl = bufc + 20480;
    const unsigned short* Ubl  = bufc + 28672;
    __syncthreads();   // staged buf + previous S writes visible (vmcnt drained)

    // ---- u = Ub - W S : acc [64x16], 4 tiles, waves 0-3 ----
    f32x4 uacc;
#pragma unroll
    for (int r = 0; r < 4; ++r) uacc[r] = 0.f;
    if (uw) {
#pragma unroll
      for (int kk = 0; kk < 4; ++kk) {
        bf16x8 af = *(const bf16x8*)(Wl + (w * 16 + row) * 128 + kk * 32 + ko);
        bf16x8 bf = *(const bf16x8*)(StTb_s + row * 128 + kk * 32 + ko);
        uacc = __builtin_amdgcn_mfma_f32_16x16x32_bf16(af, bf, uacc, 0, 0, 0);
      }
      const int r0 = w * 16 + (l >> 4) * 4;
      const int col = l & 15;
#pragma unroll
      for (int r = 0; r < 4; ++r) {
        const int t = r0 + r;
        const float ubv = bf2f(Ubl[t * 16 + col]);
        uT_s[col * 64 + t] = f2bf(ubv - uacc[r]);
      }
    }
    __syncthreads();   // uT ready
    if (p < 15)
      p2_stage(Wg, Attg, Qgg, KgTg, Ubg, bh * 16 + p + 1, vb, stage_s[(p + 1) & 1], tid);

    // ---- O = Qg S + Att u : acc [64x16], waves 0-3 ----
    f32x4 oacc;
#pragma unroll
    for (int r = 0; r < 4; ++r) oacc[r] = 0.f;
    if (uw) {
#pragma unroll
      for (int kk = 0; kk < 4; ++kk) {
        bf16x8 af = *(const bf16x8*)(Qgl + (w * 16 + row) * 128 + kk * 32 + ko);
        bf16x8 bf = *(const bf16x8*)(StTb_s + row * 128 + kk * 32 + ko);
        oacc = __builtin_amdgcn_mfma_f32_16x16x32_bf16(af, bf, oacc, 0, 0, 0);
      }
#pragma unroll
      for (int kk = 0; kk < 2; ++kk) {
        bf16x8 af = *(const bf16x8*)(Attl + (w * 16 + row) * 64 + kk * 32 + ko);
        bf16x8 bf = *(const bf16x8*)(uT_s + row * 64 + kk * 32 + ko);
        oacc = __builtin_amdgcn_mfma_f32_16x16x32_bf16(af, bf, oacc, 0, 0, 0);
      }
    }
    // ---- Snew^T = dec*S^T + (u^T)(KgT^T) : acc [16x128], 8 tiles, 1/wave ----
    f32x4 sacc;
#pragma unroll
    for (int r = 0; r < 4; ++r) sacc[r] = 0.f;
#pragma unroll
    for (int kk = 0; kk < 2; ++kk) {
      bf16x8 af = *(const bf16x8*)(uT_s + row * 64 + kk * 32 + ko);
      bf16x8 bf = *(const bf16x8*)(KgTl + (w * 16 + row) * 64 + kk * 32 + ko);
      sacc = __builtin_amdgcn_mfma_f32_16x16x32_bf16(af, bf, sacc, 0, 0, 0);
    }
    const float dec = decg[bh * 16 + p];
    __syncthreads();   // all reads of StT/StTb/uT done before overwrite

    // epilogues
    if (uw) {
      const int r0 = w * 16 + (l >> 4) * 4;
      const int col = l & 15;
#pragma unroll
      for (int r = 0; r < 4; ++r) {
        const size_t trow = (size_t)b * T_LEN + p * 64 + r0 + r;
        osc[(trow * 8 + h) * 256 + vb * 16 + col] = oacc[r];
      }
    }
    {
      const int cold = w * 16 + (l & 15);
#pragma unroll
      for (int r = 0; r < 4; ++r) {
        const int idx = ((l >> 4) * 4 + r) * 128 + cold;
        const float sn = fmaf(dec, StT_s[idx], sacc[r]);
        StT_s[idx] = sn;
        StTb_s[idx] = f2bf(sn);
      }
    }
  }
}

// ---------------- gated RMSNorm + silu(gate) -> bf16 ----------------
__global__ __launch_bounds__(256) void rmsgate(
    const float* __restrict__ ob, const unsigned short* __restrict__ Y,
    const float* __restrict__ onw, unsigned short* __restrict__ Obf) {
  const int bt = blockIdx.x;
  const int tid = threadIdx.x;
  const int c = tid * 8;                // head = c/256 = tid/32
  const float* orow = ob + (size_t)bt * 2048 + c;
  const unsigned short* grow = Y + (size_t)bt * NBIG + 4096 + c;
  const float4 o0 = *(const float4*)orow, o1 = *(const float4*)(orow + 4);
  const ushort4 g0 = *(const ushort4*)grow, g1 = *(const ushort4*)(grow + 4);
  const float ov[8] = {o0.x, o0.y, o0.z, o0.w, o1.x, o1.y, o1.z, o1.w};
  const float gv[8] = {bf2f(g0.x), bf2f(g0.y), bf2f(g0.z), bf2f(g0.w),
                       bf2f(g1.x), bf2f(g1.y), bf2f(g1.z), bf2f(g1.w)};
  float ss = 0.f;
#pragma unroll
  for (int e = 0; e < 8; ++e) ss += ov[e] * ov[e];
#pragma unroll
  for (int m = 16; m >= 1; m >>= 1) ss += __shfl_xor(ss, m);
  const float rn = rsqrtf(ss * (1.f / 256.f) + 1e-5f);
  const int dv = c & 255;
  unsigned short rr[8];
#pragma unroll
  for (int e = 0; e < 8; ++e) {
    const float val = ov[e] * rn * onw[dv + e] * silu_f(gv[e]);
    rr[e] = f2bf(val);
  }
  ushort4 r0 = {rr[0], rr[1], rr[2], rr[3]};
  ushort4 r1 = {rr[4], rr[5], rr[6], rr[7]};
  *(ushort4*)(Obf + (size_t)bt * 2048 + c) = r0;
  *(ushort4*)(Obf + (size_t)bt * 2048 + c + 4) = r1;
}

extern "C" void kernel_launch(void* const* d_in, const int* in_sizes, int n_in,
                              void* d_out, int out_size, void* d_ws, size_t ws_size,
                              hipStream_t stream) {
  (void)in_sizes; (void)n_in; (void)out_size; (void)ws_size;
  const float* h    = (const float*)d_in[0];
  const float* qw   = (const float*)d_in[1];
  const float* kw   = (const float*)d_in[2];
  const float* vw   = (const float*)d_in[3];
  const float* aw   = (const float*)d_in[4];
  const float* bw   = (const float*)d_in[5];
  const float* gw   = (const float*)d_in[6];
  const float* ow   = (const float*)d_in[7];
  const float* qcw  = (const float*)d_in[8];
  const float* kcw  = (const float*)d_in[9];
  const float* vcw  = (const float*)d_in[10];
  const float* Alog = (const float*)d_in[11];
  const float* dtb  = (const float*)d_in[12];
  const float* onw  = (const float*)d_in[13];

  char* ws = (char*)d_ws;
  size_t off = 0;
  auto alloc = [&](size_t bytes) {
    char* p = ws + off;
    off = (off + bytes + 255) & ~(size_t)255;
    return p;
  };
  unsigned short* hbf  = (unsigned short*)alloc(2048ull * 2048 * 2);
  unsigned short* Wb   = (unsigned short*)alloc((size_t)NBIG * 2048 * 2);
  unsigned short* owb  = (unsigned short*)alloc(2048ull * 2048 * 2);
  unsigned short* Ybf  = (unsigned short*)alloc(2048ull * NBIG * 2);
  float* osc           = (float*)alloc(2048ull * 2048 * 4);
  unsigned short* Obf  = (unsigned short*)alloc(2048ull * 2048 * 2);
  unsigned short* Wg   = (unsigned short*)alloc(256ull * 8192 * 2);
  unsigned short* Ubg  = (unsigned short*)alloc(256ull * 16384 * 2);
  unsigned short* Attg = (unsigned short*)alloc(256ull * 4096 * 2);
  unsigned short* Qgg  = (unsigned short*)alloc(256ull * 8192 * 2);
  unsigned short* KgTg = (unsigned short*)alloc(256ull * 8192 * 2);
  float* decg          = (float*)alloc(256ull * 4);

  // fused prologue: cvt(h) + build_w + cvt(ow) + zero(d_out) in one dispatch
  prep_all<<<25088, 256, 0, stream>>>(h, ow, qw, kw, vw, gw, aw, bw,
                                      hbf, owb, Wb, (float*)d_out);
  // GEMM1: 16 x 25 tiles of 128x256 -> 400 blocks (R9-measured best config)
  gemm_pipe<256, 4, 512, true, false><<<400, 512, 0, stream>>>(
      (const bf16*)hbf, (const bf16*)Wb, Ybf, NBIG, 2048, 2048);
  chunk_prep<<<256, 512, 0, stream>>>(Ybf, qcw, kcw, vcw, Alog, dtb,
                                      Wg, Ubg, Attg, Qgg, KgTg, decg);
  scan_chunks<<<256, 512, 0, stream>>>(Wg, Ubg, Attg, Qgg, KgTg, decg, osc);
  rmsgate<<<2048, 256, 0, stream>>>(osc, Ybf, onw, Obf);
  // GEMM2: K-split x2 -> 512 blocks (2/CU), fp32 atomicAdd epilogue (2 contribs/addr)
  gemm_pipe<128, 2, 256, false, true><<<512, 256, 0, stream>>>(
      (const bf16*)Obf, (const bf16*)owb, d_out, 2048, 1024, 2048);
}

// Round 15
// 212.774 us; speedup vs baseline: 1.2619x; 1.0111x over previous
//
#include <hip/hip_runtime.h>
#include <cstdint>

#define T_LEN 1024
#define NBIG  6400     // padded N for fused projection GEMM (6160 real cols, 25 x 256 tiles)
#define SCALE_Q 0.08838834764831843f   // DK^-0.5

typedef __bf16 bf16;
typedef __bf16 bf16x8 __attribute__((ext_vector_type(8)));
typedef float  f32x4  __attribute__((ext_vector_type(4)));

__device__ __forceinline__ unsigned short f2bf(float f) {
  unsigned int u = __builtin_bit_cast(unsigned int, f);
  u += 0x7FFFu + ((u >> 16) & 1u);          // RNE
  return (unsigned short)(u >> 16);
}
__device__ __forceinline__ float bf2f(unsigned short u) {
  return __builtin_bit_cast(float, (unsigned int)u << 16);
}
__device__ __forceinline__ float silu_f(float x) { return x / (1.f + __expf(-x)); }

#define GLDS(src, dst) \
  __builtin_amdgcn_global_load_lds( \
      (__attribute__((address_space(1))) void*)(void*)(src), \
      (__attribute__((address_space(3))) void*)(void*)(dst), 16, 0, 0)

// ---------------- fused prologue: cvt(h), build_w, cvt(ow), zero(d_out) ----------------
// one dispatch, 25088 blocks of 256: [0,4096) h->hbf, [4096,16896) W concat,
// [16896,20992) ow->owb, [20992,25088) zero d_out.
__global__ __launch_bounds__(256) void prep_all(
    const float* __restrict__ h, const float* __restrict__ ow,
    const float* __restrict__ qw, const float* __restrict__ kw,
    const float* __restrict__ vw, const float* __restrict__ gw,
    const float* __restrict__ aw, const float* __restrict__ bw,
    unsigned short* __restrict__ hbf, unsigned short* __restrict__ owb,
    unsigned short* __restrict__ Wb, float* __restrict__ zout) {
  const int blk = blockIdx.x;
  const int tid = threadIdx.x;
  if (blk < 4096) {
    const int idx = blk * 256 + tid;
    float4 f = ((const float4*)h)[idx];
    ushort4 o = { f2bf(f.x), f2bf(f.y), f2bf(f.z), f2bf(f.w) };
    ((ushort4*)hbf)[idx] = o;
  } else if (blk < 16896) {
    const int idx = (blk - 4096) * 256 + tid;
    const int r = idx >> 9;
    const int c = (idx & 511) << 2;
    const float* src;
    if      (r < 1024) src = qw + (size_t)r * 2048;
    else if (r < 2048) src = kw + (size_t)(r - 1024) * 2048;
    else if (r < 4096) src = vw + (size_t)(r - 2048) * 2048;
    else if (r < 6144) src = gw + (size_t)(r - 4096) * 2048;
    else if (r < 6152) src = aw + (size_t)(r - 6144) * 2048;
    else if (r < 6160) src = bw + (size_t)(r - 6152) * 2048;
    else               src = nullptr;
    ushort4 o;
    if (src) {
      float4 f = *(const float4*)(src + c);
      o = { f2bf(f.x), f2bf(f.y), f2bf(f.z), f2bf(f.w) };
    } else {
      o = { 0, 0, 0, 0 };
    }
    *(ushort4*)(Wb + (size_t)r * 2048 + c) = o;
  } else if (blk < 20992) {
    const int idx = (blk - 16896) * 256 + tid;
    float4 f = ((const float4*)ow)[idx];
    ushort4 o = { f2bf(f.x), f2bf(f.y), f2bf(f.z), f2bf(f.w) };
    ((ushort4*)owb)[idx] = o;
  } else {
    const int idx = (blk - 20992) * 256 + tid;
    float4 z = {0.f, 0.f, 0.f, 0.f};
    ((float4*)zout)[idx] = z;
  }
}

// ============ pipelined NT GEMM: BM=128 x BN tile, BK=32, ring-3 LDS, counted vmcnt ============
// C[M][N] = A[M][K_total] * B[N][K_total]^T over a K-slice. bf16 in. T threads = T/64 waves.
// If ATOMIC: inner grid = 1<<ILOG blocks, block bidAll>>ILOG handles K-slice
// [ (bidAll>>ILOG)*K , +K ), epilogue atomicAdd fp32 (exactly 2 contributions/addr).
// R6-proven schedule: per K-step { STAGE(kt+2); setprio(1); 16 MFMA; setprio(0);
// lgkmcnt(0); vmcnt(LOADS); s_barrier; ds_read next frags }. vmcnt never drains to 0.
// LDS swizzle (0-conflict, R4-verified): logical k-slot s of row r at phys s ^ ((r>>1)&3).
template <int BN, int WN, int T, bool BF16OUT, bool ATOMIC, int ILOG>
__global__ __launch_bounds__(T, 4) void gemm_pipe(
    const bf16* __restrict__ A, const bf16* __restrict__ Bm,
    void* __restrict__ Cv, int N, int K, int ldk) {
  constexpr int AI = (128 * 32) / (T * 8);   // A glds insts/thread per K-tile
  constexpr int BI = (BN * 32) / (T * 8);    // B glds insts/thread per K-tile
  constexpr int LOADS = AI + BI;
  __shared__ bf16 LA[3][128 * 32];
  __shared__ bf16 LB[3][BN * 32];
  const int tid = threadIdx.x;
  const int lane = tid & 63;
  const int wid = tid >> 6;
  const int wm = wid / WN, wn = wid % WN;
  // XCD-chunked bijective block map: xcd owns m-rows {xcd, xcd+8} x all n-tiles
  const int bidAll = blockIdx.x;
  const int bid = ATOMIC ? (bidAll & ((1 << ILOG) - 1)) : bidAll;
  const long kofs = ATOMIC ? (long)(bidAll >> ILOG) * K : 0;
  const int xcd = bid & 7, jj = bid >> 3;
  const long brow = (long)(xcd + 8 * (jj & 1)) * 128;
  const long bcol = (long)(jj >> 1) * BN;

  f32x4 acc[4][4];
#pragma unroll
  for (int m = 0; m < 4; ++m)
#pragma unroll
    for (int n = 0; n < 4; ++n)
#pragma unroll
      for (int r = 0; r < 4; ++r) acc[m][n][r] = 0.f;

  // staging map: flat slot = e*T + tid -> (row = flat>>2, pslot = flat&3);
  // global source col = (pslot ^ ((row>>1)&3)) * 8  (inverse swizzle, linear LDS dest)
  const bf16* AgS[AI];
  const bf16* BgS[BI];
  int adst[AI], bdst[BI];
#pragma unroll
  for (int e = 0; e < AI; ++e) {
    const int flat = e * T + tid;
    const int row = flat >> 2;
    const int sl = (flat & 3) ^ ((row >> 1) & 3);
    AgS[e] = A + (brow + row) * (long)ldk + kofs + sl * 8;
    adst[e] = flat * 8;
  }
#pragma unroll
  for (int e = 0; e < BI; ++e) {
    const int flat = e * T + tid;
    const int row = flat >> 2;
    const int sl = (flat & 3) ^ ((row >> 1) & 3);
    BgS[e] = Bm + (bcol + row) * (long)ldk + kofs + sl * 8;
    bdst[e] = flat * 8;
  }

#define STAGE(kt, sb)                                              \
  {                                                                \
    const long ko = (long)(kt) * 32;                               \
    _Pragma("unroll")                                              \
    for (int e = 0; e < AI; ++e) GLDS(AgS[e] + ko, &LA[sb][0] + adst[e]); \
    _Pragma("unroll")                                              \
    for (int e = 0; e < BI; ++e) GLDS(BgS[e] + ko, &LB[sb][0] + bdst[e]); \
  }
#define WAIT_VM()                                                  \
  if constexpr (LOADS == 3) asm volatile("s_waitcnt vmcnt(3)" ::: "memory"); \
  else                      asm volatile("s_waitcnt vmcnt(4)" ::: "memory");

  // read offsets (halfwords): row*32 + (ks ^ ((r16>>1)&3))*8
  const int r16 = lane & 15;
  const int ks = lane >> 4;
  const int pso = (ks ^ ((r16 >> 1) & 3)) * 8;
  int rdA[4], rdB[4];
#pragma unroll
  for (int i = 0; i < 4; ++i) rdA[i] = (wm * 64 + i * 16 + r16) * 32 + pso;
#pragma unroll
  for (int j = 0; j < 4; ++j) rdB[j] = (wn * 64 + j * 16 + r16) * 32 + pso;

  const int nkt = K >> 5;
  STAGE(0, 0);
  STAGE(1, 1);
  WAIT_VM();                         // buf0 landed (stage(1) may stay in flight)
  __builtin_amdgcn_s_barrier();

  bf16x8 af[4], bfr[4];
#pragma unroll
  for (int i = 0; i < 4; ++i) af[i] = *(const bf16x8*)(&LA[0][0] + rdA[i]);
#pragma unroll
  for (int j = 0; j < 4; ++j) bfr[j] = *(const bf16x8*)(&LB[0][0] + rdB[j]);

  for (int kt = 0; kt < nkt; ++kt) {
    const int kts = (kt + 2 < nkt) ? kt + 2 : nkt - 1;  // clamp src, keep count uniform
    const int sb = (kt + 2) % 3;                        // == (kt-1)%3: read-complete slot
    const int nb = (kt + 1) % 3;

    STAGE(kts, sb);
    __builtin_amdgcn_s_setprio(1);
#pragma unroll
    for (int i = 0; i < 4; ++i)
#pragma unroll
      for (int j = 0; j < 4; ++j)
        acc[i][j] = __builtin_amdgcn_mfma_f32_16x16x32_bf16(af[i], bfr[j], acc[i][j], 0, 0, 0);
    __builtin_amdgcn_s_setprio(0);

    asm volatile("s_waitcnt lgkmcnt(0)" ::: "memory");
    WAIT_VM();                       // kt+1 landed; kt+2 stays in flight
    __builtin_amdgcn_s_barrier();
#pragma unroll
    for (int i = 0; i < 4; ++i) af[i] = *(const bf16x8*)(&LA[nb][0] + rdA[i]);
#pragma unroll
    for (int j = 0; j < 4; ++j) bfr[j] = *(const bf16x8*)(&LB[nb][0] + rdB[j]);
  }
#undef STAGE
#undef WAIT_VM

  // epilogue: C/D layout col=lane&15, row=(lane>>4)*4+r
  const long row0 = brow + wm * 64 + ((lane >> 4) * 4);
  const long col0 = bcol + wn * 64 + (lane & 15);
#pragma unroll
  for (int m = 0; m < 4; ++m)
#pragma unroll
    for (int n = 0; n < 4; ++n)
#pragma unroll
      for (int r = 0; r < 4; ++r) {
        const long idx = (row0 + m * 16 + r) * (long)N + col0 + n * 16;
        if constexpr (ATOMIC)
          atomicAdd((float*)Cv + idx, acc[m][n][r]);
        else if constexpr (BF16OUT)
          ((unsigned short*)Cv)[idx] = f2bf(acc[m][n][r]);
        else
          ((float*)Cv)[idx] = acc[m][n][r];
      }
}

// ---------------- small NT GEMM on LDS operands: OUT[i][j] = sum_k A[i][k]*B[j][k] ----------------
// A: [M][K] bf16 LDS, B: [N][K] bf16 LDS. NW waves. Output bf16 global (ldg).
template <int M, int N, int K, int NW>
__device__ __forceinline__ void mm_nt_lds(const unsigned short* A, const unsigned short* B,
                                          unsigned short* outG, int ldg, int tid) {
  constexpr int NT16 = N / 16;
  constexpr int PW = (M / 16) * NT16 / NW;
  const int w = tid >> 6, l = tid & 63;
  const int row = l & 15, ko = (l >> 4) * 8;
  f32x4 acc[PW];
#pragma unroll
  for (int i = 0; i < PW; ++i)
#pragma unroll
    for (int r = 0; r < 4; ++r) acc[i][r] = 0.f;
#pragma unroll
  for (int i = 0; i < PW; ++i) {
    const int ti = w + NW * i;
    const int rt = ti / NT16, ct = ti % NT16;
#pragma unroll
    for (int kk = 0; kk < K / 32; ++kk) {
      bf16x8 af = *(const bf16x8*)(A + (rt * 16 + row) * K + kk * 32 + ko);
      bf16x8 bf = *(const bf16x8*)(B + (ct * 16 + row) * K + kk * 32 + ko);
      acc[i] = __builtin_amdgcn_mfma_f32_16x16x32_bf16(af, bf, acc[i], 0, 0, 0);
    }
  }
#pragma unroll
  for (int i = 0; i < PW; ++i) {
    const int ti = w + NW * i;
    const int rt = ti / NT16, ct = ti % NT16;
    const int r0 = rt * 16 + (l >> 4) * 4;
    const int col = ct * 16 + (l & 15);
#pragma unroll
    for (int r = 0; r < 4; ++r)
      outG[(size_t)(r0 + r) * ldg + col] = f2bf(acc[i][r]);
  }
}

// 64x64 NT MFMA accumulate (8 waves, 2 tiles/wave), epilogue left to caller
template <int K>
__device__ __forceinline__ void mm64_acc(const unsigned short* A, const unsigned short* B,
                                         f32x4 acc[2], int w, int row, int ko) {
#pragma unroll
  for (int i = 0; i < 2; ++i) {
    const int ti = w + 8 * i;
    const int rt = ti >> 2, ct = ti & 3;
#pragma unroll
    for (int kk = 0; kk < K / 32; ++kk) {
      bf16x8 af = *(const bf16x8*)(A + (rt * 16 + row) * K + kk * 32 + ko);
      bf16x8 bf = *(const bf16x8*)(B + (ct * 16 + row) * K + kk * 32 + ko);
      acc[i] = __builtin_amdgcn_mfma_f32_16x16x32_bf16(af, bf, acc[i], 0, 0, 0);
    }
  }
}

// ---------------- phase 1: conv+norm fused + per-chunk UT transform (C=64), 512 threads ----------------
// LDS overlaid to 73 KB -> 2 blocks/CU: Newton scratch {Mb,Xt,Yt} and VbT time-share one
// region (v-conv runs AFTER Newton). X updated in place (mid-phase barrier).
__global__ __launch_bounds__(512, 4) void chunk_prep(
    const unsigned short* __restrict__ Y,
    const float* __restrict__ qcw, const float* __restrict__ kcw, const float* __restrict__ vcw,
    const float* __restrict__ A_log, const float* __restrict__ dt_bias,
    unsigned short* __restrict__ Wg, unsigned short* __restrict__ Ubg,
    unsigned short* __restrict__ Attg, unsigned short* __restrict__ Qgg,
    unsigned short* __restrict__ KgTg, float* __restrict__ decg) {
  __shared__ unsigned short SM[36864];          // 72 KB overlay arena
  unsigned short* Kb_s   = SM;                  // [64][128]   8192 us
  unsigned short* Qb_s   = SM + 8192;           // [64][128]   8192 us (later KbgT)
  unsigned short* Xrow_s = SM + 16384;          // [64][64]    4096 us
  unsigned short* Mb_s   = SM + 20480;          // [64][64]    4096 us (scratch)
  unsigned short* Xt_s   = SM + 24576;          // [64][64]    4096 us (scratch)
  unsigned short* Yt_s   = SM + 28672;          // [64][64]    4096 us (scratch)
  unsigned short* VbT_s  = SM + 20480;          // [256][64]  16384 us (overlays scratch)
  __shared__ float carr_s[64];
  __shared__ float beta_s[64];

  const int tid = threadIdx.x;
  const int w = tid >> 6, l = tid & 63;
  const int row16 = l & 15, ko = (l >> 4) * 8;
  const int ch = blockIdx.x;
  const int bh = ch >> 4, p = ch & 15;
  const int b = bh >> 3, h = bh & 7;
  const size_t tbase = (size_t)b * T_LEN + p * 64;
  const bool head = (p == 0);

  // 1. per-step scalars + cumulative log-decay (wave 0, from Y directly)
  if (tid < 64) {
    const unsigned short* Yr = Y + (tbase + tid) * NBIG;
    float a = bf2f(Yr[6144 + h]) + dt_bias[h];
    float sp = (a > 20.f) ? a : log1pf(expf(a));
    float g = -expf(A_log[h]) * sp;
    float bp = bf2f(Yr[6152 + h]);
    beta_s[tid] = 1.f / (1.f + expf(-bp));
    float c = g;
#pragma unroll
    for (int d = 1; d < 64; d <<= 1) {
      float y = __shfl_up(c, d);
      if (tid >= d) c += y;
    }
    carr_s[tid] = c;
    if (tid == 63) decg[ch] = __expf(c);
  }
  __syncthreads();   // beta/carr ready

  // 2. conv+SiLU+l2norm for q (waves 0-3) and k (waves 4-7) -> Qb_s/Kb_s [64][128]
  {
    const bool isQ = (tid < 256);
    const int wk = tid & 255;
    const int quad = wk & 31, tg = wk >> 5;     // 32 quads x 8 t-groups (8 t each)
    const int c = quad * 4;
    const float* cw = isQ ? qcw : kcw;
    const int cb = (isQ ? 0 : 1024) + h * 128 + c;
    float4 wv[4];
#pragma unroll
    for (int e = 0; e < 4; ++e) wv[e] = ((const float4*)cw)[h * 128 + c + e];
    float rows[11][4];
#pragma unroll
    for (int r = 0; r < 11; ++r) {
      if (head && tg == 0 && r < 3) {
        rows[r][0] = rows[r][1] = rows[r][2] = rows[r][3] = 0.f;
      } else {
        const ushort4 x = *(const ushort4*)(Y + (tbase + tg * 8 - 3 + r) * NBIG + cb);
        rows[r][0] = bf2f(x.x); rows[r][1] = bf2f(x.y);
        rows[r][2] = bf2f(x.z); rows[r][3] = bf2f(x.w);
      }
    }
    unsigned short* dst = isQ ? Qb_s : Kb_s;
    const float sc = isQ ? SCALE_Q : 1.f;
#pragma unroll
    for (int i = 0; i < 8; ++i) {
      float acc[4], ss = 0.f;
#pragma unroll
      for (int e = 0; e < 4; ++e) {
        float a = wv[e].x * rows[i][e];
        a = fmaf(wv[e].y, rows[i + 1][e], a);
        a = fmaf(wv[e].z, rows[i + 2][e], a);
        a = fmaf(wv[e].w, rows[i + 3][e], a);
        a = silu_f(a);
        acc[e] = a;
        ss += a * a;
      }
#pragma unroll
      for (int m = 16; m >= 1; m >>= 1) ss += __shfl_xor(ss, m);
      const float rn = rsqrtf(ss + 1e-6f) * sc;
      ushort4 o = {f2bf(acc[0] * rn), f2bf(acc[1] * rn), f2bf(acc[2] * rn), f2bf(acc[3] * rn)};
      *(ushort4*)(dst + (tg * 8 + i) * 128 + c) = o;
    }
  }
  __syncthreads();   // Kb/Qb ready

  float xf[2][4];    // X fp32 master, per-thread (same tile indices across phases)
  // 4+5 fused: A_raw = K K^T; epilogue builds M = I+A, X0 = I-A (xf, Xrow, Xt)
  {
    f32x4 acc[2];
#pragma unroll
    for (int i = 0; i < 2; ++i)
#pragma unroll
      for (int r = 0; r < 4; ++r) acc[i][r] = 0.f;
    mm64_acc<128>(Kb_s, Kb_s, acc, w, row16, ko);
#pragma unroll
    for (int i = 0; i < 2; ++i) {
      const int ti = w + 8 * i;
      const int rt = ti >> 2, ct = ti & 3;
      const int r0 = rt * 16 + (l >> 4) * 4;
      const int col = ct * 16 + (l & 15);
#pragma unroll
      for (int r = 0; r < 4; ++r) {
        const int t = r0 + r, j = col;
        const float av = (j < t) ? beta_s[t] * __expf(carr_s[t] - carr_s[j]) * acc[i][r] : 0.f;
        const float dg = (t == j) ? 1.f : 0.f;
        Mb_s[t * 64 + j] = f2bf(dg + av);
        const float x0 = dg - av;
        xf[i][r] = x0;
        const unsigned short xb = f2bf(x0);
        Xrow_s[t * 64 + j] = xb;
        Xt_s[j * 64 + t] = xb;
      }
    }
  }
  __syncthreads();
  // 6. Newton x5: X <- X(2I - M X), in place (exact: A nilpotent)
  for (int it = 0; it < 5; ++it) {
    {  // Yt = (M X)^T  (transposed-write epilogue; Yt disjoint from Mb/Xt)
      f32x4 acc[2];
#pragma unroll
      for (int i = 0; i < 2; ++i)
#pragma unroll
        for (int r = 0; r < 4; ++r) acc[i][r] = 0.f;
      mm64_acc<64>(Mb_s, Xt_s, acc, w, row16, ko);
#pragma unroll
      for (int i = 0; i < 2; ++i) {
        const int ti = w + 8 * i;
        const int rt = ti >> 2, ct = ti & 3;
        const int r0 = rt * 16 + (l >> 4) * 4;
        const int col = ct * 16 + (l & 15);
#pragma unroll
        for (int r = 0; r < 4; ++r)
          Yt_s[col * 64 + (r0 + r)] = f2bf(acc[i][r]);
      }
    }
    __syncthreads();
    {  // P = X Y ; X' = 2*xf - P   (in-place: barrier between reads and writes)
      f32x4 acc[2];
#pragma unroll
      for (int i = 0; i < 2; ++i)
#pragma unroll
        for (int r = 0; r < 4; ++r) acc[i][r] = 0.f;
      mm64_acc<64>(Xrow_s, Yt_s, acc, w, row16, ko);
      __syncthreads();   // all Xrow reads drained before overwrite
#pragma unroll
      for (int i = 0; i < 2; ++i) {
        const int ti = w + 8 * i;
        const int rt = ti >> 2, ct = ti & 3;
        const int r0 = rt * 16 + (l >> 4) * 4;
        const int col = ct * 16 + (l & 15);
#pragma unroll
        for (int r = 0; r < 4; ++r) {
          const float xn = 2.f * xf[i][r] - acc[i][r];
          xf[i][r] = xn;
          const unsigned short xb = f2bf(xn);
          Xrow_s[(r0 + r) * 64 + col] = xb;
          Xt_s[col * 64 + (r0 + r)] = xb;
        }
      }
    }
    __syncthreads();
  }
  const float ctot = carr_s[63];
  // 3 (moved): conv+SiLU for v, *beta, transposed -> VbT_s (overlays dead Newton scratch)
  {
    const int quad = tid & 63, tg = tid >> 6;   // 64 quads x 8 t-groups
    const int c = quad * 4;
    float4 wv[4];
#pragma unroll
    for (int e = 0; e < 4; ++e) wv[e] = ((const float4*)vcw)[h * 256 + c + e];
    float rows[11][4];
#pragma unroll
    for (int r = 0; r < 11; ++r) {
      if (head && tg == 0 && r < 3) {
        rows[r][0] = rows[r][1] = rows[r][2] = rows[r][3] = 0.f;
      } else {
        const ushort4 x = *(const ushort4*)(Y + (tbase + tg * 8 - 3 + r) * NBIG + 2048 + h * 256 + c);
        rows[r][0] = bf2f(x.x); rows[r][1] = bf2f(x.y);
        rows[r][2] = bf2f(x.z); rows[r][3] = bf2f(x.w);
      }
    }
#pragma unroll
    for (int i = 0; i < 8; ++i) {
      const int t = tg * 8 + i;
      const float bt = beta_s[t];
#pragma unroll
      for (int e = 0; e < 4; ++e) {
        float a = wv[e].x * rows[i][e];
        a = fmaf(wv[e].y, rows[i + 1][e], a);
        a = fmaf(wv[e].z, rows[i + 2][e], a);
        a = fmaf(wv[e].w, rows[i + 3][e], a);
        VbT_s[(c + e) * 64 + t] = f2bf(bt * silu_f(a));
      }
    }
  }
  // 7+8 fused: Att = mask(exp) o (Q K^T) -> global directly
  {
    f32x4 acc[2];
#pragma unroll
    for (int i = 0; i < 2; ++i)
#pragma unroll
      for (int r = 0; r < 4; ++r) acc[i][r] = 0.f;
    mm64_acc<128>(Qb_s, Kb_s, acc, w, row16, ko);
#pragma unroll
    for (int i = 0; i < 2; ++i) {
      const int ti = w + 8 * i;
      const int rt = ti >> 2, ct = ti & 3;
      const int r0 = rt * 16 + (l >> 4) * 4;
      const int col = ct * 16 + (l & 15);
#pragma unroll
      for (int r = 0; r < 4; ++r) {
        const int t = r0 + r, j = col;
        const float av = (j <= t) ? __expf(carr_s[t] - carr_s[j]) * acc[i][r] : 0.f;
        Attg[(size_t)ch * 4096 + t * 64 + j] = f2bf(av);
      }
    }
  }
  // Qg, KgT -> global (elementwise from Qb/Kb)
#pragma unroll
  for (int i = 0; i < 16; ++i) {
    const int idx = i * 512 + tid;
    const int t = idx >> 7;
    Qgg[(size_t)ch * 8192 + idx] = f2bf(__expf(carr_s[t]) * bf2f(Qb_s[idx]));
  }
#pragma unroll
  for (int i = 0; i < 16; ++i) {
    const int idx = i * 512 + tid;
    const int d = idx >> 6, t = idx & 63;
    KgTg[(size_t)ch * 8192 + idx] = f2bf(__expf(ctot - carr_s[t]) * bf2f(Kb_s[t * 128 + d]));
  }
  __syncthreads();   // Qb reads done before reuse; VbT writes visible
  // 9. KbgT[d][t] = bf16(beta_t exp(c_t) k[t][d])  (into Qb space)
  unsigned short* KbgT = Qb_s;
#pragma unroll
  for (int i = 0; i < 16; ++i) {
    const int idx = i * 512 + tid;
    const int d = idx >> 6, t = idx & 63;
    KbgT[idx] = f2bf(beta_s[t] * __expf(carr_s[t]) * bf2f(Kb_s[t * 128 + d]));
  }
  __syncthreads();
  // 10. W = T (betaG.K)  [64x128];  Ub = T (betaV)  [64x256]  -> global bf16
  mm_nt_lds<64, 128, 64, 8>(Xrow_s, KbgT, Wg + (size_t)ch * 8192, 128, tid);
  mm_nt_lds<64, 256, 64, 8>(Xrow_s, VbT_s, Ubg + (size_t)ch * 16384, 256, tid);
}

// ---------------- phase 2: serial chunk recurrence (MFMA), 16 bh x 16 v-blocks, 512 thr ----------------
// 256 blocks (1/CU). Same-bh blocks land on one XCD (blk%8 = bh%8) -> staged data L2-shared.
// stage buffer (ushort offsets): W@0(8192) Att@8192(4096) Qg@12288(8192) KgT@20480(8192) Ub@28672(1024)
__device__ __forceinline__ void p2_stage(
    const unsigned short* Wg, const unsigned short* Attg, const unsigned short* Qgg,
    const unsigned short* KgTg, const unsigned short* Ubg,
    int ch, int vb, unsigned short* buf, int tid) {
#pragma unroll
  for (int i = 0; i < 2; ++i) {
    const int f = i * 512 + tid;
    GLDS(Wg + (size_t)ch * 8192 + f * 8, (char*)buf + f * 16);
  }
  {
    const int f = tid;
    GLDS(Attg + (size_t)ch * 4096 + f * 8, (char*)(buf + 8192) + f * 16);
  }
#pragma unroll
  for (int i = 0; i < 2; ++i) {
    const int f = i * 512 + tid;
    GLDS(Qgg + (size_t)ch * 8192 + f * 8, (char*)(buf + 12288) + f * 16);
  }
#pragma unroll
  for (int i = 0; i < 2; ++i) {
    const int f = i * 512 + tid;
    GLDS(KgTg + (size_t)ch * 8192 + f * 8, (char*)(buf + 20480) + f * 16);
  }
  if (tid < 128) {                   // Ub slice: 64 t x 16 cols
    const int f = tid;
    const int t = f >> 1, c8 = f & 1;
    GLDS(Ubg + (size_t)ch * 16384 + t * 256 + vb * 16 + c8 * 8, (char*)(buf + 28672) + f * 16);
  }
}

__global__ __launch_bounds__(512, 1) void scan_chunks(
    const unsigned short* __restrict__ Wg, const unsigned short* __restrict__ Ubg,
    const unsigned short* __restrict__ Attg, const unsigned short* __restrict__ Qgg,
    const unsigned short* __restrict__ KgTg, const float* __restrict__ decg,
    float* __restrict__ osc) {
  __shared__ float StT_s[16 * 128];            // S^T fp32 [vcol][d]
  __shared__ unsigned short StTb_s[16 * 128];  // S^T bf16
  __shared__ unsigned short uT_s[16 * 64];     // u^T bf16 [vcol][t]
  __shared__ unsigned short stage_s[2][29696];

  const int tid = threadIdx.x;
  const int w = tid >> 6, l = tid & 63;
  const int row = l & 15, ko = (l >> 4) * 8;
  const int blk = blockIdx.x;                  // vb*16 + bh  (same-bh blocks share an XCD)
  const int vb = blk >> 4, bh = blk & 15;
  const int b = bh >> 3, h = bh & 7;
  const bool uw = (w < 4);                     // u/O phases use 4 waves (4 tiles of 64x16)

  for (int i = tid; i < 2048; i += 512) { StT_s[i] = 0.f; StTb_s[i] = 0; }
  p2_stage(Wg, Attg, Qgg, KgTg, Ubg, bh * 16, vb, stage_s[0], tid);

  for (int p = 0; p < 16; ++p) {
    unsigned short* bufc = stage_s[p & 1];
    const unsigned short* Wl   = bufc;
    const unsigned short* Attl = bufc + 8192;
    const unsigned short* Qgl  = bufc + 12288;
    const unsigned short* KgTl = bufc + 20480;
    const unsigned short* Ubl  = bufc + 28672;
    __syncthreads();   // staged buf + previous S writes visible (vmcnt drained)

    // ---- u = Ub - W S : acc [64x16], 4 tiles, waves 0-3 ----
    f32x4 uacc;
#pragma unroll
    for (int r = 0; r < 4; ++r) uacc[r] = 0.f;
    if (uw) {
#pragma unroll
      for (int kk = 0; kk < 4; ++kk) {
        bf16x8 af = *(const bf16x8*)(Wl + (w * 16 + row) * 128 + kk * 32 + ko);
        bf16x8 bf = *(const bf16x8*)(StTb_s + row * 128 + kk * 32 + ko);
        uacc = __builtin_amdgcn_mfma_f32_16x16x32_bf16(af, bf, uacc, 0, 0, 0);
      }
      const int r0 = w * 16 + (l >> 4) * 4;
      const int col = l & 15;
#pragma unroll
      for (int r = 0; r < 4; ++r) {
        const int t = r0 + r;
        const float ubv = bf2f(Ubl[t * 16 + col]);
        uT_s[col * 64 + t] = f2bf(ubv - uacc[r]);
      }
    }
    __syncthreads();   // uT ready
    if (p < 15)
      p2_stage(Wg, Attg, Qgg, KgTg, Ubg, bh * 16 + p + 1, vb, stage_s[(p + 1) & 1], tid);

    // ---- O = Qg S + Att u : acc [64x16], waves 0-3 ----
    f32x4 oacc;
#pragma unroll
    for (int r = 0; r < 4; ++r) oacc[r] = 0.f;
    if (uw) {
#pragma unroll
      for (int kk = 0; kk < 4; ++kk) {
        bf16x8 af = *(const bf16x8*)(Qgl + (w * 16 + row) * 128 + kk * 32 + ko);
        bf16x8 bf = *(const bf16x8*)(StTb_s + row * 128 + kk * 32 + ko);
        oacc = __builtin_amdgcn_mfma_f32_16x16x32_bf16(af, bf, oacc, 0, 0, 0);
      }
#pragma unroll
      for (int kk = 0; kk < 2; ++kk) {
        bf16x8 af = *(const bf16x8*)(Attl + (w * 16 + row) * 64 + kk * 32 + ko);
        bf16x8 bf = *(const bf16x8*)(uT_s + row * 64 + kk * 32 + ko);
        oacc = __builtin_amdgcn_mfma_f32_16x16x32_bf16(af, bf, oacc, 0, 0, 0);
      }
    }
    // ---- Snew^T = dec*S^T + (u^T)(KgT^T) : acc [16x128], 8 tiles, 1/wave ----
    f32x4 sacc;
#pragma unroll
    for (int r = 0; r < 4; ++r) sacc[r] = 0.f;
#pragma unroll
    for (int kk = 0; kk < 2; ++kk) {
      bf16x8 af = *(const bf16x8*)(uT_s + row * 64 + kk * 32 + ko);
      bf16x8 bf = *(const bf16x8*)(KgTl + (w * 16 + row) * 64 + kk * 32 + ko);
      sacc = __builtin_amdgcn_mfma_f32_16x16x32_bf16(af, bf, sacc, 0, 0, 0);
    }
    const float dec = decg[bh * 16 + p];
    __syncthreads();   // all reads of StT/StTb/uT done before overwrite

    // epilogues
    if (uw) {
      const int r0 = w * 16 + (l >> 4) * 4;
      const int col = l & 15;
#pragma unroll
      for (int r = 0; r < 4; ++r) {
        const size_t trow = (size_t)b * T_LEN + p * 64 + r0 + r;
        osc[(trow * 8 + h) * 256 + vb * 16 + col] = oacc[r];
      }
    }
    {
      const int cold = w * 16 + (l & 15);
#pragma unroll
      for (int r = 0; r < 4; ++r) {
        const int idx = ((l >> 4) * 4 + r) * 128 + cold;
        const float sn = fmaf(dec, StT_s[idx], sacc[r]);
        StT_s[idx] = sn;
        StTb_s[idx] = f2bf(sn);
      }
    }
  }
}

// ---------------- gated RMSNorm + silu(gate) -> bf16 ----------------
__global__ __launch_bounds__(256) void rmsgate(
    const float* __restrict__ ob, const unsigned short* __restrict__ Y,
    const float* __restrict__ onw, unsigned short* __restrict__ Obf) {
  const int bt = blockIdx.x;
  const int tid = threadIdx.x;
  const int c = tid * 8;                // head = c/256 = tid/32
  const float* orow = ob + (size_t)bt * 2048 + c;
  const unsigned short* grow = Y + (size_t)bt * NBIG + 4096 + c;
  const float4 o0 = *(const float4*)orow, o1 = *(const float4*)(orow + 4);
  const ushort4 g0 = *(const ushort4*)grow, g1 = *(const ushort4*)(grow + 4);
  const float ov[8] = {o0.x, o0.y, o0.z, o0.w, o1.x, o1.y, o1.z, o1.w};
  const float gv[8] = {bf2f(g0.x), bf2f(g0.y), bf2f(g0.z), bf2f(g0.w),
                       bf2f(g1.x), bf2f(g1.y), bf2f(g1.z), bf2f(g1.w)};
  float ss = 0.f;
#pragma unroll
  for (int e = 0; e < 8; ++e) ss += ov[e] * ov[e];
#pragma unroll
  for (int m = 16; m >= 1; m >>= 1) ss += __shfl_xor(ss, m);
  const float rn = rsqrtf(ss * (1.f / 256.f) + 1e-5f);
  const int dv = c & 255;
  unsigned short rr[8];
#pragma unroll
  for (int e = 0; e < 8; ++e) {
    const float val = ov[e] * rn * onw[dv + e] * silu_f(gv[e]);
    rr[e] = f2bf(val);
  }
  ushort4 r0 = {rr[0], rr[1], rr[2], rr[3]};
  ushort4 r1 = {rr[4], rr[5], rr[6], rr[7]};
  *(ushort4*)(Obf + (size_t)bt * 2048 + c) = r0;
  *(ushort4*)(Obf + (size_t)bt * 2048 + c + 4) = r1;
}

extern "C" void kernel_launch(void* const* d_in, const int* in_sizes, int n_in,
                              void* d_out, int out_size, void* d_ws, size_t ws_size,
                              hipStream_t stream) {
  (void)in_sizes; (void)n_in; (void)out_size; (void)ws_size;
  const float* h    = (const float*)d_in[0];
  const float* qw   = (const float*)d_in[1];
  const float* kw   = (const float*)d_in[2];
  const float* vw   = (const float*)d_in[3];
  const float* aw   = (const float*)d_in[4];
  const float* bw   = (const float*)d_in[5];
  const float* gw   = (const float*)d_in[6];
  const float* ow   = (const float*)d_in[7];
  const float* qcw  = (const float*)d_in[8];
  const float* kcw  = (const float*)d_in[9];
  const float* vcw  = (const float*)d_in[10];
  const float* Alog = (const float*)d_in[11];
  const float* dtb  = (const float*)d_in[12];
  const float* onw  = (const float*)d_in[13];

  char* ws = (char*)d_ws;
  size_t off = 0;
  auto alloc = [&](size_t bytes) {
    char* p = ws + off;
    off = (off + bytes + 255) & ~(size_t)255;
    return p;
  };
  unsigned short* hbf  = (unsigned short*)alloc(2048ull * 2048 * 2);
  unsigned short* Wb   = (unsigned short*)alloc((size_t)NBIG * 2048 * 2);
  unsigned short* owb  = (unsigned short*)alloc(2048ull * 2048 * 2);
  unsigned short* Ybf  = (unsigned short*)alloc(2048ull * NBIG * 2);
  float* osc           = (float*)alloc(2048ull * 2048 * 4);
  unsigned short* Obf  = (unsigned short*)alloc(2048ull * 2048 * 2);
  unsigned short* Wg   = (unsigned short*)alloc(256ull * 8192 * 2);
  unsigned short* Ubg  = (unsigned short*)alloc(256ull * 16384 * 2);
  unsigned short* Attg = (unsigned short*)alloc(256ull * 4096 * 2);
  unsigned short* Qgg  = (unsigned short*)alloc(256ull * 8192 * 2);
  unsigned short* KgTg = (unsigned short*)alloc(256ull * 8192 * 2);
  float* decg          = (float*)alloc(256ull * 4);

  // fused prologue: cvt(h) + build_w + cvt(ow) + zero(d_out) in one dispatch
  prep_all<<<25088, 256, 0, stream>>>(h, ow, qw, kw, vw, gw, aw, bw,
                                      hbf, owb, Wb, (float*)d_out);
  // GEMM1: 16 x 25 tiles of 128x256 -> 400 blocks (R9-measured best config)
  gemm_pipe<256, 4, 512, true, false, 0><<<400, 512, 0, stream>>>(
      (const bf16*)hbf, (const bf16*)Wb, Ybf, NBIG, 2048, 2048);
  chunk_prep<<<256, 512, 0, stream>>>(Ybf, qcw, kcw, vcw, Alog, dtb,
                                      Wg, Ubg, Attg, Qgg, KgTg, decg);
  scan_chunks<<<256, 512, 0, stream>>>(Wg, Ubg, Attg, Qgg, KgTg, decg, osc);
  rmsgate<<<2048, 256, 0, stream>>>(osc, Ybf, onw, Obf);
  // GEMM2: K-split x2 at BN=256/T=512 -> inner 16x8=128, total 256 blocks (1/CU, balanced),
  // fp32 atomicAdd epilogue (exactly 2 contributions/addr, deterministic)
  gemm_pipe<256, 4, 512, false, true, 7><<<256, 512, 0, stream>>>(
      (const bf16*)Obf, (const bf16*)owb, d_out, 2048, 1024, 2048);
}

// Round 17
// 208.855 us; speedup vs baseline: 1.2856x; 1.0188x over previous
//
#include <hip/hip_runtime.h>
#include <cstdint>

#define T_LEN 1024
#define NBIG  6400     // padded N for fused projection GEMM (6160 real cols, 25 x 256 tiles)
#define SCALE_Q 0.08838834764831843f   // DK^-0.5

typedef __bf16 bf16;
typedef __bf16 bf16x8 __attribute__((ext_vector_type(8)));
typedef float  f32x4  __attribute__((ext_vector_type(4)));

__device__ __forceinline__ unsigned short f2bf(float f) {
  unsigned int u = __builtin_bit_cast(unsigned int, f);
  u += 0x7FFFu + ((u >> 16) & 1u);          // RNE
  return (unsigned short)(u >> 16);
}
__device__ __forceinline__ float bf2f(unsigned short u) {
  return __builtin_bit_cast(float, (unsigned int)u << 16);
}
__device__ __forceinline__ float silu_f(float x) { return x / (1.f + __expf(-x)); }

#define GLDS(src, dst) \
  __builtin_amdgcn_global_load_lds( \
      (__attribute__((address_space(1))) void*)(void*)(src), \
      (__attribute__((address_space(3))) void*)(void*)(dst), 16, 0, 0)

// ---------------- prologue: cvt(h), build_w (owb/zero moved into chunk_prep's shadow) ----------------
// 16896 blocks of 256: [0,4096) h->hbf, [4096,16896) W concat.
__global__ __launch_bounds__(256) void prep_all(
    const float* __restrict__ h,
    const float* __restrict__ qw, const float* __restrict__ kw,
    const float* __restrict__ vw, const float* __restrict__ gw,
    const float* __restrict__ aw, const float* __restrict__ bw,
    unsigned short* __restrict__ hbf, unsigned short* __restrict__ Wb) {
  const int blk = blockIdx.x;
  const int tid = threadIdx.x;
  if (blk < 4096) {
    const int idx = blk * 256 + tid;
    float4 f = ((const float4*)h)[idx];
    ushort4 o = { f2bf(f.x), f2bf(f.y), f2bf(f.z), f2bf(f.w) };
    ((ushort4*)hbf)[idx] = o;
  } else {
    const int idx = (blk - 4096) * 256 + tid;
    const int r = idx >> 9;
    const int c = (idx & 511) << 2;
    const float* src;
    if      (r < 1024) src = qw + (size_t)r * 2048;
    else if (r < 2048) src = kw + (size_t)(r - 1024) * 2048;
    else if (r < 4096) src = vw + (size_t)(r - 2048) * 2048;
    else if (r < 6144) src = gw + (size_t)(r - 4096) * 2048;
    else if (r < 6152) src = aw + (size_t)(r - 6144) * 2048;
    else if (r < 6160) src = bw + (size_t)(r - 6152) * 2048;
    else               src = nullptr;
    ushort4 o;
    if (src) {
      float4 f = *(const float4*)(src + c);
      o = { f2bf(f.x), f2bf(f.y), f2bf(f.z), f2bf(f.w) };
    } else {
      o = { 0, 0, 0, 0 };
    }
    *(ushort4*)(Wb + (size_t)r * 2048 + c) = o;
  }
}

// ============ pipelined NT GEMM: BM=128 x BN tile, BK=32, ring-3 LDS, counted vmcnt ============
// C[M][N] = A[M][K_total] * B[N][K_total]^T over a K-slice. bf16 in. T threads = T/64 waves.
// If ATOMIC: inner grid = 1<<ILOG blocks, block bidAll>>ILOG handles K-slice
// [ (bidAll>>ILOG)*K , +K ), epilogue atomicAdd fp32 (exactly 2 contributions/addr,
// fp32 a+b == b+a -> bit-deterministic).
// R6-proven schedule: per K-step { STAGE(kt+2); setprio(1); 16 MFMA; setprio(0);
// lgkmcnt(0); vmcnt(LOADS); s_barrier; ds_read next frags }. vmcnt never drains to 0.
// LDS swizzle (0-conflict, R4-verified): logical k-slot s of row r at phys s ^ ((r>>1)&3).
template <int BN, int WN, int T, bool BF16OUT, bool ATOMIC, int ILOG>
__global__ __launch_bounds__(T, 4) void gemm_pipe(
    const bf16* __restrict__ A, const bf16* __restrict__ Bm,
    void* __restrict__ Cv, int N, int K, int ldk) {
  constexpr int AI = (128 * 32) / (T * 8);   // A glds insts/thread per K-tile
  constexpr int BI = (BN * 32) / (T * 8);    // B glds insts/thread per K-tile
  constexpr int LOADS = AI + BI;
  __shared__ bf16 LA[3][128 * 32];
  __shared__ bf16 LB[3][BN * 32];
  const int tid = threadIdx.x;
  const int lane = tid & 63;
  const int wid = tid >> 6;
  const int wm = wid / WN, wn = wid % WN;
  // XCD-chunked bijective block map: xcd owns m-rows {xcd, xcd+8} x all n-tiles
  const int bidAll = blockIdx.x;
  const int bid = ATOMIC ? (bidAll & ((1 << ILOG) - 1)) : bidAll;
  const long kofs = ATOMIC ? (long)(bidAll >> ILOG) * K : 0;
  const int xcd = bid & 7, jj = bid >> 3;
  const long brow = (long)(xcd + 8 * (jj & 1)) * 128;
  const long bcol = (long)(jj >> 1) * BN;

  f32x4 acc[4][4];
#pragma unroll
  for (int m = 0; m < 4; ++m)
#pragma unroll
    for (int n = 0; n < 4; ++n)
#pragma unroll
      for (int r = 0; r < 4; ++r) acc[m][n][r] = 0.f;

  // staging map: flat slot = e*T + tid -> (row = flat>>2, pslot = flat&3);
  // global source col = (pslot ^ ((row>>1)&3)) * 8  (inverse swizzle, linear LDS dest)
  const bf16* AgS[AI];
  const bf16* BgS[BI];
  int adst[AI], bdst[BI];
#pragma unroll
  for (int e = 0; e < AI; ++e) {
    const int flat = e * T + tid;
    const int row = flat >> 2;
    const int sl = (flat & 3) ^ ((row >> 1) & 3);
    AgS[e] = A + (brow + row) * (long)ldk + kofs + sl * 8;
    adst[e] = flat * 8;
  }
#pragma unroll
  for (int e = 0; e < BI; ++e) {
    const int flat = e * T + tid;
    const int row = flat >> 2;
    const int sl = (flat & 3) ^ ((row >> 1) & 3);
    BgS[e] = Bm + (bcol + row) * (long)ldk + kofs + sl * 8;
    bdst[e] = flat * 8;
  }

#define STAGE(kt, sb)                                              \
  {                                                                \
    const long ko = (long)(kt) * 32;                               \
    _Pragma("unroll")                                              \
    for (int e = 0; e < AI; ++e) GLDS(AgS[e] + ko, &LA[sb][0] + adst[e]); \
    _Pragma("unroll")                                              \
    for (int e = 0; e < BI; ++e) GLDS(BgS[e] + ko, &LB[sb][0] + bdst[e]); \
  }
#define WAIT_VM()                                                  \
  if constexpr (LOADS == 3) asm volatile("s_waitcnt vmcnt(3)" ::: "memory"); \
  else                      asm volatile("s_waitcnt vmcnt(4)" ::: "memory");

  // read offsets (halfwords): row*32 + (ks ^ ((r16>>1)&3))*8
  const int r16 = lane & 15;
  const int ks = lane >> 4;
  const int pso = (ks ^ ((r16 >> 1) & 3)) * 8;
  int rdA[4], rdB[4];
#pragma unroll
  for (int i = 0; i < 4; ++i) rdA[i] = (wm * 64 + i * 16 + r16) * 32 + pso;
#pragma unroll
  for (int j = 0; j < 4; ++j) rdB[j] = (wn * 64 + j * 16 + r16) * 32 + pso;

  const int nkt = K >> 5;
  STAGE(0, 0);
  STAGE(1, 1);
  WAIT_VM();                         // buf0 landed (stage(1) may stay in flight)
  __builtin_amdgcn_s_barrier();

  bf16x8 af[4], bfr[4];
#pragma unroll
  for (int i = 0; i < 4; ++i) af[i] = *(const bf16x8*)(&LA[0][0] + rdA[i]);
#pragma unroll
  for (int j = 0; j < 4; ++j) bfr[j] = *(const bf16x8*)(&LB[0][0] + rdB[j]);

  for (int kt = 0; kt < nkt; ++kt) {
    const int kts = (kt + 2 < nkt) ? kt + 2 : nkt - 1;  // clamp src, keep count uniform
    const int sb = (kt + 2) % 3;                        // == (kt-1)%3: read-complete slot
    const int nb = (kt + 1) % 3;

    STAGE(kts, sb);
    __builtin_amdgcn_s_setprio(1);
#pragma unroll
    for (int i = 0; i < 4; ++i)
#pragma unroll
      for (int j = 0; j < 4; ++j)
        acc[i][j] = __builtin_amdgcn_mfma_f32_16x16x32_bf16(af[i], bfr[j], acc[i][j], 0, 0, 0);
    __builtin_amdgcn_s_setprio(0);

    asm volatile("s_waitcnt lgkmcnt(0)" ::: "memory");
    WAIT_VM();                       // kt+1 landed; kt+2 stays in flight
    __builtin_amdgcn_s_barrier();
#pragma unroll
    for (int i = 0; i < 4; ++i) af[i] = *(const bf16x8*)(&LA[nb][0] + rdA[i]);
#pragma unroll
    for (int j = 0; j < 4; ++j) bfr[j] = *(const bf16x8*)(&LB[nb][0] + rdB[j]);
  }
#undef STAGE
#undef WAIT_VM

  // epilogue: C/D layout col=lane&15, row=(lane>>4)*4+r
  const long row0 = brow + wm * 64 + ((lane >> 4) * 4);
  const long col0 = bcol + wn * 64 + (lane & 15);
#pragma unroll
  for (int m = 0; m < 4; ++m)
#pragma unroll
    for (int n = 0; n < 4; ++n)
#pragma unroll
      for (int r = 0; r < 4; ++r) {
        const long idx = (row0 + m * 16 + r) * (long)N + col0 + n * 16;
        if constexpr (ATOMIC)
          atomicAdd((float*)Cv + idx, acc[m][n][r]);
        else if constexpr (BF16OUT)
          ((unsigned short*)Cv)[idx] = f2bf(acc[m][n][r]);
        else
          ((float*)Cv)[idx] = acc[m][n][r];
      }
}

// ---------------- small NT GEMM on LDS operands: OUT[i][j] = sum_k A[i][k]*B[j][k] ----------------
// A: [M][K] bf16 LDS, B: [N][K] bf16 LDS. NW waves. Output bf16 global (ldg).
template <int M, int N, int K, int NW>
__device__ __forceinline__ void mm_nt_lds(const unsigned short* A, const unsigned short* B,
                                          unsigned short* outG, int ldg, int tid) {
  constexpr int NT16 = N / 16;
  constexpr int PW = (M / 16) * NT16 / NW;
  const int w = tid >> 6, l = tid & 63;
  const int row = l & 15, ko = (l >> 4) * 8;
  f32x4 acc[PW];
#pragma unroll
  for (int i = 0; i < PW; ++i)
#pragma unroll
    for (int r = 0; r < 4; ++r) acc[i][r] = 0.f;
#pragma unroll
  for (int i = 0; i < PW; ++i) {
    const int ti = w + NW * i;
    const int rt = ti / NT16, ct = ti % NT16;
#pragma unroll
    for (int kk = 0; kk < K / 32; ++kk) {
      bf16x8 af = *(const bf16x8*)(A + (rt * 16 + row) * K + kk * 32 + ko);
      bf16x8 bf = *(const bf16x8*)(B + (ct * 16 + row) * K + kk * 32 + ko);
      acc[i] = __builtin_amdgcn_mfma_f32_16x16x32_bf16(af, bf, acc[i], 0, 0, 0);
    }
  }
#pragma unroll
  for (int i = 0; i < PW; ++i) {
    const int ti = w + NW * i;
    const int rt = ti / NT16, ct = ti % NT16;
    const int r0 = rt * 16 + (l >> 4) * 4;
    const int col = ct * 16 + (l & 15);
#pragma unroll
    for (int r = 0; r < 4; ++r)
      outG[(size_t)(r0 + r) * ldg + col] = f2bf(acc[i][r]);
  }
}

// 64x64 NT MFMA accumulate (8 waves, 2 tiles/wave), epilogue left to caller
template <int K>
__device__ __forceinline__ void mm64_acc(const unsigned short* A, const unsigned short* B,
                                         f32x4 acc[2], int w, int row, int ko) {
#pragma unroll
  for (int i = 0; i < 2; ++i) {
    const int ti = w + 8 * i;
    const int rt = ti >> 2, ct = ti & 3;
#pragma unroll
    for (int kk = 0; kk < K / 32; ++kk) {
      bf16x8 af = *(const bf16x8*)(A + (rt * 16 + row) * K + kk * 32 + ko);
      bf16x8 bf = *(const bf16x8*)(B + (ct * 16 + row) * K + kk * 32 + ko);
      acc[i] = __builtin_amdgcn_mfma_f32_16x16x32_bf16(af, bf, acc[i], 0, 0, 0);
    }
  }
}

// ---------------- phase 1: conv+norm fused + per-chunk UT transform (C=64), 512 threads ----------------
// Blocks 0-255: chunk work. Blocks 256-1279: owb conversion + d_out zeroing (runs in this
// latency-bound kernel's idle-bandwidth shadow; outputs needed only by GEMM2, 3 dispatches later).
__global__ __launch_bounds__(512, 4) void chunk_prep(
    const unsigned short* __restrict__ Y,
    const float* __restrict__ qcw, const float* __restrict__ kcw, const float* __restrict__ vcw,
    const float* __restrict__ A_log, const float* __restrict__ dt_bias,
    unsigned short* __restrict__ Wg, unsigned short* __restrict__ Ubg,
    unsigned short* __restrict__ Attg, unsigned short* __restrict__ Qgg,
    unsigned short* __restrict__ KgTg, float* __restrict__ decg,
    const float* __restrict__ ow, unsigned short* __restrict__ owb,
    float* __restrict__ zout) {
  __shared__ unsigned short SM[36864];          // 72 KB overlay arena
  unsigned short* Kb_s   = SM;                  // [64][128]   8192 us
  unsigned short* Qb_s   = SM + 8192;           // [64][128]   8192 us (later KbgT)
  unsigned short* Xrow_s = SM + 16384;          // [64][64]    4096 us
  unsigned short* Mb_s   = SM + 20480;          // [64][64]    4096 us (scratch)
  unsigned short* Xt_s   = SM + 24576;          // [64][64]    4096 us (scratch)
  unsigned short* Yt_s   = SM + 28672;          // [64][64]    4096 us (scratch)
  unsigned short* VbT_s  = SM + 20480;          // [256][64]  16384 us (overlays scratch)
  __shared__ float carr_s[64];
  __shared__ float beta_s[64];

  const int tid = threadIdx.x;
  const int ch = blockIdx.x;
  // ---- aux elementwise blocks: owb cvt (4 slots/thread) + d_out zero (4 slots/thread) ----
  if (ch >= 256) {
    const int i = ch - 256;
    if (i < 512) {
#pragma unroll
      for (int e = 0; e < 4; ++e) {
        const int idx = e * 262144 + i * 512 + tid;
        float4 f = ((const float4*)ow)[idx];
        ushort4 o = { f2bf(f.x), f2bf(f.y), f2bf(f.z), f2bf(f.w) };
        ((ushort4*)owb)[idx] = o;
      }
    } else {
      const int i2 = i - 512;
      float4 z = {0.f, 0.f, 0.f, 0.f};
#pragma unroll
      for (int e = 0; e < 4; ++e) {
        const int idx = e * 262144 + i2 * 512 + tid;
        ((float4*)zout)[idx] = z;
      }
    }
    return;
  }

  const int w = tid >> 6, l = tid & 63;
  const int row16 = l & 15, ko = (l >> 4) * 8;
  const int bh = ch >> 4, p = ch & 15;
  const int b = bh >> 3, h = bh & 7;
  const size_t tbase = (size_t)b * T_LEN + p * 64;
  const bool head = (p == 0);

  // 1. per-step scalars + cumulative log-decay (wave 0, from Y directly)
  if (tid < 64) {
    const unsigned short* Yr = Y + (tbase + tid) * NBIG;
    float a = bf2f(Yr[6144 + h]) + dt_bias[h];
    float sp = (a > 20.f) ? a : log1pf(expf(a));
    float g = -expf(A_log[h]) * sp;
    float bp = bf2f(Yr[6152 + h]);
    beta_s[tid] = 1.f / (1.f + expf(-bp));
    float c = g;
#pragma unroll
    for (int d = 1; d < 64; d <<= 1) {
      float y = __shfl_up(c, d);
      if (tid >= d) c += y;
    }
    carr_s[tid] = c;
    if (tid == 63) decg[ch] = __expf(c);
  }
  __syncthreads();   // beta/carr ready

  // 2. conv+SiLU+l2norm for q (waves 0-3) and k (waves 4-7) -> Qb_s/Kb_s [64][128]
  {
    const bool isQ = (tid < 256);
    const int wk = tid & 255;
    const int quad = wk & 31, tg = wk >> 5;     // 32 quads x 8 t-groups (8 t each)
    const int c = quad * 4;
    const float* cw = isQ ? qcw : kcw;
    const int cb = (isQ ? 0 : 1024) + h * 128 + c;
    float4 wv[4];
#pragma unroll
    for (int e = 0; e < 4; ++e) wv[e] = ((const float4*)cw)[h * 128 + c + e];
    float rows[11][4];
#pragma unroll
    for (int r = 0; r < 11; ++r) {
      if (head && tg == 0 && r < 3) {
        rows[r][0] = rows[r][1] = rows[r][2] = rows[r][3] = 0.f;
      } else {
        const ushort4 x = *(const ushort4*)(Y + (tbase + tg * 8 - 3 + r) * NBIG + cb);
        rows[r][0] = bf2f(x.x); rows[r][1] = bf2f(x.y);
        rows[r][2] = bf2f(x.z); rows[r][3] = bf2f(x.w);
      }
    }
    unsigned short* dst = isQ ? Qb_s : Kb_s;
    const float sc = isQ ? SCALE_Q : 1.f;
#pragma unroll
    for (int i = 0; i < 8; ++i) {
      float acc[4], ss = 0.f;
#pragma unroll
      for (int e = 0; e < 4; ++e) {
        float a = wv[e].x * rows[i][e];
        a = fmaf(wv[e].y, rows[i + 1][e], a);
        a = fmaf(wv[e].z, rows[i + 2][e], a);
        a = fmaf(wv[e].w, rows[i + 3][e], a);
        a = silu_f(a);
        acc[e] = a;
        ss += a * a;
      }
#pragma unroll
      for (int m = 16; m >= 1; m >>= 1) ss += __shfl_xor(ss, m);
      const float rn = rsqrtf(ss + 1e-6f) * sc;
      ushort4 o = {f2bf(acc[0] * rn), f2bf(acc[1] * rn), f2bf(acc[2] * rn), f2bf(acc[3] * rn)};
      *(ushort4*)(dst + (tg * 8 + i) * 128 + c) = o;
    }
  }
  __syncthreads();   // Kb/Qb ready

  float xf[2][4];    // X fp32 master, per-thread (same tile indices across phases)
  // 4+5 fused: A_raw = K K^T; epilogue builds M = I+A, X0 = I-A (xf, Xrow, Xt)
  {
    f32x4 acc[2];
#pragma unroll
    for (int i = 0; i < 2; ++i)
#pragma unroll
      for (int r = 0; r < 4; ++r) acc[i][r] = 0.f;
    mm64_acc<128>(Kb_s, Kb_s, acc, w, row16, ko);
#pragma unroll
    for (int i = 0; i < 2; ++i) {
      const int ti = w + 8 * i;
      const int rt = ti >> 2, ct = ti & 3;
      const int r0 = rt * 16 + (l >> 4) * 4;
      const int col = ct * 16 + (l & 15);
#pragma unroll
      for (int r = 0; r < 4; ++r) {
        const int t = r0 + r, j = col;
        const float av = (j < t) ? beta_s[t] * __expf(carr_s[t] - carr_s[j]) * acc[i][r] : 0.f;
        const float dg = (t == j) ? 1.f : 0.f;
        Mb_s[t * 64 + j] = f2bf(dg + av);
        const float x0 = dg - av;
        xf[i][r] = x0;
        const unsigned short xb = f2bf(x0);
        Xrow_s[t * 64 + j] = xb;
        Xt_s[j * 64 + t] = xb;
      }
    }
  }
  __syncthreads();
  // 6. Newton x5: X <- X(2I - M X), in place (exact: A nilpotent)
  for (int it = 0; it < 5; ++it) {
    {  // Yt = (M X)^T  (transposed-write epilogue; Yt disjoint from Mb/Xt)
      f32x4 acc[2];
#pragma unroll
      for (int i = 0; i < 2; ++i)
#pragma unroll
        for (int r = 0; r < 4; ++r) acc[i][r] = 0.f;
      mm64_acc<64>(Mb_s, Xt_s, acc, w, row16, ko);
#pragma unroll
      for (int i = 0; i < 2; ++i) {
        const int ti = w + 8 * i;
        const int rt = ti >> 2, ct = ti & 3;
        const int r0 = rt * 16 + (l >> 4) * 4;
        const int col = ct * 16 + (l & 15);
#pragma unroll
        for (int r = 0; r < 4; ++r)
          Yt_s[col * 64 + (r0 + r)] = f2bf(acc[i][r]);
      }
    }
    __syncthreads();
    {  // P = X Y ; X' = 2*xf - P   (in-place: barrier between reads and writes)
      f32x4 acc[2];
#pragma unroll
      for (int i = 0; i < 2; ++i)
#pragma unroll
        for (int r = 0; r < 4; ++r) acc[i][r] = 0.f;
      mm64_acc<64>(Xrow_s, Yt_s, acc, w, row16, ko);
      __syncthreads();   // all Xrow reads drained before overwrite
#pragma unroll
      for (int i = 0; i < 2; ++i) {
        const int ti = w + 8 * i;
        const int rt = ti >> 2, ct = ti & 3;
        const int r0 = rt * 16 + (l >> 4) * 4;
        const int col = ct * 16 + (l & 15);
#pragma unroll
        for (int r = 0; r < 4; ++r) {
          const float xn = 2.f * xf[i][r] - acc[i][r];
          xf[i][r] = xn;
          const unsigned short xb = f2bf(xn);
          Xrow_s[(r0 + r) * 64 + col] = xb;
          Xt_s[col * 64 + (r0 + r)] = xb;
        }
      }
    }
    __syncthreads();
  }
  const float ctot = carr_s[63];
  // 3 (moved): conv+SiLU for v, *beta, transposed -> VbT_s (overlays dead Newton scratch)
  {
    const int quad = tid & 63, tg = tid >> 6;   // 64 quads x 8 t-groups
    const int c = quad * 4;
    float4 wv[4];
#pragma unroll
    for (int e = 0; e < 4; ++e) wv[e] = ((const float4*)vcw)[h * 256 + c + e];
    float rows[11][4];
#pragma unroll
    for (int r = 0; r < 11; ++r) {
      if (head && tg == 0 && r < 3) {
        rows[r][0] = rows[r][1] = rows[r][2] = rows[r][3] = 0.f;
      } else {
        const ushort4 x = *(const ushort4*)(Y + (tbase + tg * 8 - 3 + r) * NBIG + 2048 + h * 256 + c);
        rows[r][0] = bf2f(x.x); rows[r][1] = bf2f(x.y);
        rows[r][2] = bf2f(x.z); rows[r][3] = bf2f(x.w);
      }
    }
#pragma unroll
    for (int i = 0; i < 8; ++i) {
      const int t = tg * 8 + i;
      const float bt = beta_s[t];
#pragma unroll
      for (int e = 0; e < 4; ++e) {
        float a = wv[e].x * rows[i][e];
        a = fmaf(wv[e].y, rows[i + 1][e], a);
        a = fmaf(wv[e].z, rows[i + 2][e], a);
        a = fmaf(wv[e].w, rows[i + 3][e], a);
        VbT_s[(c + e) * 64 + t] = f2bf(bt * silu_f(a));
      }
    }
  }
  // 7+8 fused: Att = mask(exp) o (Q K^T) -> global directly
  {
    f32x4 acc[2];
#pragma unroll
    for (int i = 0; i < 2; ++i)
#pragma unroll
      for (int r = 0; r < 4; ++r) acc[i][r] = 0.f;
    mm64_acc<128>(Qb_s, Kb_s, acc, w, row16, ko);
#pragma unroll
    for (int i = 0; i < 2; ++i) {
      const int ti = w + 8 * i;
      const int rt = ti >> 2, ct = ti & 3;
      const int r0 = rt * 16 + (l >> 4) * 4;
      const int col = ct * 16 + (l & 15);
#pragma unroll
      for (int r = 0; r < 4; ++r) {
        const int t = r0 + r, j = col;
        const float av = (j <= t) ? __expf(carr_s[t] - carr_s[j]) * acc[i][r] : 0.f;
        Attg[(size_t)ch * 4096 + t * 64 + j] = f2bf(av);
      }
    }
  }
  // Qg, KgT -> global (elementwise from Qb/Kb)
#pragma unroll
  for (int i = 0; i < 16; ++i) {
    const int idx = i * 512 + tid;
    const int t = idx >> 7;
    Qgg[(size_t)ch * 8192 + idx] = f2bf(__expf(carr_s[t]) * bf2f(Qb_s[idx]));
  }
#pragma unroll
  for (int i = 0; i < 16; ++i) {
    const int idx = i * 512 + tid;
    const int d = idx >> 6, t = idx & 63;
    KgTg[(size_t)ch * 8192 + idx] = f2bf(__expf(ctot - carr_s[t]) * bf2f(Kb_s[t * 128 + d]));
  }
  __syncthreads();   // Qb reads done before reuse; VbT writes visible
  // 9. KbgT[d][t] = bf16(beta_t exp(c_t) k[t][d])  (into Qb space)
  unsigned short* KbgT = Qb_s;
#pragma unroll
  for (int i = 0; i < 16; ++i) {
    const int idx = i * 512 + tid;
    const int d = idx >> 6, t = idx & 63;
    KbgT[idx] = f2bf(beta_s[t] * __expf(carr_s[t]) * bf2f(Kb_s[t * 128 + d]));
  }
  __syncthreads();
  // 10. W = T (betaG.K)  [64x128];  Ub = T (betaV)  [64x256]  -> global bf16
  mm_nt_lds<64, 128, 64, 8>(Xrow_s, KbgT, Wg + (size_t)ch * 8192, 128, tid);
  mm_nt_lds<64, 256, 64, 8>(Xrow_s, VbT_s, Ubg + (size_t)ch * 16384, 256, tid);
}

// ---------------- phase 2: serial chunk recurrence (MFMA), 16 bh x 16 v-blocks, 512 thr ----------------
// 256 blocks (1/CU). Same-bh blocks land on one XCD (blk%8 = bh%8) -> staged data L2-shared.
// stage buffer (ushort offsets): W@0(8192) Att@8192(4096) Qg@12288(8192) KgT@20480(8192) Ub@28672(1024)
__device__ __forceinline__ void p2_stage(
    const unsigned short* Wg, const unsigned short* Attg, const unsigned short* Qgg,
    const unsigned short* KgTg, const unsigned short* Ubg,
    int ch, int vb, unsigned short* buf, int tid) {
#pragma unroll
  for (int i = 0; i < 2; ++i) {
    const int f = i * 512 + tid;
    GLDS(Wg + (size_t)ch * 8192 + f * 8, (char*)buf + f * 16);
  }
  {
    const int f = tid;
    GLDS(Attg + (size_t)ch * 4096 + f * 8, (char*)(buf + 8192) + f * 16);
  }
#pragma unroll
  for (int i = 0; i < 2; ++i) {
    const int f = i * 512 + tid;
    GLDS(Qgg + (size_t)ch * 8192 + f * 8, (char*)(buf + 12288) + f * 16);
  }
#pragma unroll
  for (int i = 0; i < 2; ++i) {
    const int f = i * 512 + tid;
    GLDS(KgTg + (size_t)ch * 8192 + f * 8, (char*)(buf + 20480) + f * 16);
  }
  if (tid < 128) {                   // Ub slice: 64 t x 16 cols
    const int f = tid;
    const int t = f >> 1, c8 = f & 1;
    GLDS(Ubg + (size_t)ch * 16384 + t * 256 + vb * 16 + c8 * 8, (char*)(buf + 28672) + f * 16);
  }
}

__global__ __launch_bounds__(512, 1) void scan_chunks(
    const unsigned short* __restrict__ Wg, const unsigned short* __restrict__ Ubg,
    const unsigned short* __restrict__ Attg, const unsigned short* __restrict__ Qgg,
    const unsigned short* __restrict__ KgTg, const float* __restrict__ decg,
    float* __restrict__ osc) {
  __shared__ float StT_s[16 * 128];            // S^T fp32 [vcol][d]
  __shared__ unsigned short StTb_s[16 * 128];  // S^T bf16
  __shared__ unsigned short uT_s[16 * 64];     // u^T bf16 [vcol][t]
  __shared__ unsigned short stage_s[2][29696];

  const int tid = threadIdx.x;
  const int w = tid >> 6, l = tid & 63;
  const int row = l & 15, ko = (l >> 4) * 8;
  const int blk = blockIdx.x;                  // vb*16 + bh  (same-bh blocks share an XCD)
  const int vb = blk >> 4, bh = blk & 15;
  const int b = bh >> 3, h = bh & 7;
  const bool uw = (w < 4);                     // u/O phases use 4 waves (4 tiles of 64x16)

  for (int i = tid; i < 2048; i += 512) { StT_s[i] = 0.f; StTb_s[i] = 0; }
  p2_stage(Wg, Attg, Qgg, KgTg, Ubg, bh * 16, vb, stage_s[0], tid);

  for (int p = 0; p < 16; ++p) {
    unsigned short* bufc = stage_s[p & 1];
    const unsigned short* Wl   = bufc;
    const unsigned short* Attl = bufc + 8192;
    const unsigned short* Qgl  = bufc + 12288;
    const unsigned short* KgTl = bufc + 20480;
    const unsigned short* Ubl  = bufc + 28672;
    __syncthreads();   // staged buf + previous S writes visible (vmcnt drained)

    // ---- u = Ub - W S : acc [64x16], 4 tiles, waves 0-3 ----
    f32x4 uacc;
#pragma unroll
    for (int r = 0; r < 4; ++r) uacc[r] = 0.f;
    if (uw) {
#pragma unroll
      for (int kk = 0; kk < 4; ++kk) {
        bf16x8 af = *(const bf16x8*)(Wl + (w * 16 + row) * 128 + kk * 32 + ko);
        bf16x8 bf = *(const bf16x8*)(StTb_s + row * 128 + kk * 32 + ko);
        uacc = __builtin_amdgcn_mfma_f32_16x16x32_bf16(af, bf, uacc, 0, 0, 0);
      }
      const int r0 = w * 16 + (l >> 4) * 4;
      const int col = l & 15;
#pragma unroll
      for (int r = 0; r < 4; ++r) {
        const int t = r0 + r;
        const float ubv = bf2f(Ubl[t * 16 + col]);
        uT_s[col * 64 + t] = f2bf(ubv - uacc[r]);
      }
    }
    __syncthreads();   // uT ready
    if (p < 15)
      p2_stage(Wg, Attg, Qgg, KgTg, Ubg, bh * 16 + p + 1, vb, stage_s[(p + 1) & 1], tid);

    // ---- O = Qg S + Att u : acc [64x16], waves 0-3 ----
    f32x4 oacc;
#pragma unroll
    for (int r = 0; r < 4; ++r) oacc[r] = 0.f;
    if (uw) {
#pragma unroll
      for (int kk = 0; kk < 4; ++kk) {
        bf16x8 af = *(const bf16x8*)(Qgl + (w * 16 + row) * 128 + kk * 32 + ko);
        bf16x8 bf = *(const bf16x8*)(StTb_s + row * 128 + kk * 32 + ko);
        oacc = __builtin_amdgcn_mfma_f32_16x16x32_bf16(af, bf, oacc, 0, 0, 0);
      }
#pragma unroll
      for (int kk = 0; kk < 2; ++kk) {
        bf16x8 af = *(const bf16x8*)(Attl + (w * 16 + row) * 64 + kk * 32 + ko);
        bf16x8 bf = *(const bf16x8*)(uT_s + row * 64 + kk * 32 + ko);
        oacc = __builtin_amdgcn_mfma_f32_16x16x32_bf16(af, bf, oacc, 0, 0, 0);
      }
    }
    // ---- Snew^T = dec*S^T + (u^T)(KgT^T) : acc [16x128], 8 tiles, 1/wave ----
    f32x4 sacc;
#pragma unroll
    for (int r = 0; r < 4; ++r) sacc[r] = 0.f;
#pragma unroll
    for (int kk = 0; kk < 2; ++kk) {
      bf16x8 af = *(const bf16x8*)(uT_s + row * 64 + kk * 32 + ko);
      bf16x8 bf = *(const bf16x8*)(KgTl + (w * 16 + row) * 64 + kk * 32 + ko);
      sacc = __builtin_amdgcn_mfma_f32_16x16x32_bf16(af, bf, sacc, 0, 0, 0);
    }
    const float dec = decg[bh * 16 + p];
    __syncthreads();   // all reads of StT/StTb/uT done before overwrite

    // epilogues
    if (uw) {
      const int r0 = w * 16 + (l >> 4) * 4;
      const int col = l & 15;
#pragma unroll
      for (int r = 0; r < 4; ++r) {
        const size_t trow = (size_t)b * T_LEN + p * 64 + r0 + r;
        osc[(trow * 8 + h) * 256 + vb * 16 + col] = oacc[r];
      }
    }
    {
      const int cold = w * 16 + (l & 15);
#pragma unroll
      for (int r = 0; r < 4; ++r) {
        const int idx = ((l >> 4) * 4 + r) * 128 + cold;
        const float sn = fmaf(dec, StT_s[idx], sacc[r]);
        StT_s[idx] = sn;
        StTb_s[idx] = f2bf(sn);
      }
    }
  }
}

// ---------------- gated RMSNorm + silu(gate) -> bf16 ----------------
__global__ __launch_bounds__(256) void rmsgate(
    const float* __restrict__ ob, const unsigned short* __restrict__ Y,
    const float* __restrict__ onw, unsigned short* __restrict__ Obf) {
  const int bt = blockIdx.x;
  const int tid = threadIdx.x;
  const int c = tid * 8;                // head = c/256 = tid/32
  const float* orow = ob + (size_t)bt * 2048 + c;
  const unsigned short* grow = Y + (size_t)bt * NBIG + 4096 + c;
  const float4 o0 = *(const float4*)orow, o1 = *(const float4*)(orow + 4);
  const ushort4 g0 = *(const ushort4*)grow, g1 = *(const ushort4*)(grow + 4);
  const float ov[8] = {o0.x, o0.y, o0.z, o0.w, o1.x, o1.y, o1.z, o1.w};
  const float gv[8] = {bf2f(g0.x), bf2f(g0.y), bf2f(g0.z), bf2f(g0.w),
                       bf2f(g1.x), bf2f(g1.y), bf2f(g1.z), bf2f(g1.w)};
  float ss = 0.f;
#pragma unroll
  for (int e = 0; e < 8; ++e) ss += ov[e] * ov[e];
#pragma unroll
  for (int m = 16; m >= 1; m >>= 1) ss += __shfl_xor(ss, m);
  const float rn = rsqrtf(ss * (1.f / 256.f) + 1e-5f);
  const int dv = c & 255;
  unsigned short rr[8];
#pragma unroll
  for (int e = 0; e < 8; ++e) {
    const float val = ov[e] * rn * onw[dv + e] * silu_f(gv[e]);
    rr[e] = f2bf(val);
  }
  ushort4 r0 = {rr[0], rr[1], rr[2], rr[3]};
  ushort4 r1 = {rr[4], rr[5], rr[6], rr[7]};
  *(ushort4*)(Obf + (size_t)bt * 2048 + c) = r0;
  *(ushort4*)(Obf + (size_t)bt * 2048 + c + 4) = r1;
}

extern "C" void kernel_launch(void* const* d_in, const int* in_sizes, int n_in,
                              void* d_out, int out_size, void* d_ws, size_t ws_size,
                              hipStream_t stream) {
  (void)in_sizes; (void)n_in; (void)out_size; (void)ws_size;
  const float* h    = (const float*)d_in[0];
  const float* qw   = (const float*)d_in[1];
  const float* kw   = (const float*)d_in[2];
  const float* vw   = (const float*)d_in[3];
  const float* aw   = (const float*)d_in[4];
  const float* bw   = (const float*)d_in[5];
  const float* gw   = (const float*)d_in[6];
  const float* ow   = (const float*)d_in[7];
  const float* qcw  = (const float*)d_in[8];
  const float* kcw  = (const float*)d_in[9];
  const float* vcw  = (const float*)d_in[10];
  const float* Alog = (const float*)d_in[11];
  const float* dtb  = (const float*)d_in[12];
  const float* onw  = (const float*)d_in[13];

  char* ws = (char*)d_ws;
  size_t off = 0;
  auto alloc = [&](size_t bytes) {
    char* p = ws + off;
    off = (off + bytes + 255) & ~(size_t)255;
    return p;
  };
  unsigned short* hbf  = (unsigned short*)alloc(2048ull * 2048 * 2);
  unsigned short* Wb   = (unsigned short*)alloc((size_t)NBIG * 2048 * 2);
  unsigned short* owb  = (unsigned short*)alloc(2048ull * 2048 * 2);
  unsigned short* Ybf  = (unsigned short*)alloc(2048ull * NBIG * 2);
  float* osc           = (float*)alloc(2048ull * 2048 * 4);
  unsigned short* Obf  = (unsigned short*)alloc(2048ull * 2048 * 2);
  unsigned short* Wg   = (unsigned short*)alloc(256ull * 8192 * 2);
  unsigned short* Ubg  = (unsigned short*)alloc(256ull * 16384 * 2);
  unsigned short* Attg = (unsigned short*)alloc(256ull * 4096 * 2);
  unsigned short* Qgg  = (unsigned short*)alloc(256ull * 8192 * 2);
  unsigned short* KgTg = (unsigned short*)alloc(256ull * 8192 * 2);
  float* decg          = (float*)alloc(256ull * 4);

  // prologue: cvt(h) + build_w (owb cvt + d_out zero moved into chunk_prep's shadow)
  prep_all<<<16896, 256, 0, stream>>>(h, qw, kw, vw, gw, aw, bw, hbf, Wb);
  // GEMM1: 16 x 25 tiles of 128x256 -> 400 blocks (R9-measured best config)
  gemm_pipe<256, 4, 512, true, false, 0><<<400, 512, 0, stream>>>(
      (const bf16*)hbf, (const bf16*)Wb, Ybf, NBIG, 2048, 2048);
  // chunk_prep (blocks 0-255) + aux owb/zero (blocks 256-1279, 4 slots/thread)
  chunk_prep<<<1280, 512, 0, stream>>>(Ybf, qcw, kcw, vcw, Alog, dtb,
                                       Wg, Ubg, Attg, Qgg, KgTg, decg,
                                       ow, owb, (float*)d_out);
  scan_chunks<<<256, 512, 0, stream>>>(Wg, Ubg, Attg, Qgg, KgTg, decg, osc);
  rmsgate<<<2048, 256, 0, stream>>>(osc, Ybf, onw, Obf);
  // GEMM2: K-split x2 at BN=256/T=512 -> inner 16x8=128, total 256 blocks (1/CU, balanced),
  // fp32 atomicAdd epilogue (exactly 2 contributions/addr -> bit-deterministic)
  gemm_pipe<256, 4, 512, false, true, 7><<<256, 512, 0, stream>>>(
      (const bf16*)Obf, (const bf16*)owb, d_out, 2048, 1024, 2048);
}

// Round 18
// 207.316 us; speedup vs baseline: 1.2951x; 1.0074x over previous
//
#include <hip/hip_runtime.h>
#include <cstdint>

#define T_LEN 1024
#define NBIG  6400     // padded N for fused projection GEMM (6160 real cols, 25 x 256 tiles)
#define SCALE_Q 0.08838834764831843f   // DK^-0.5

typedef __bf16 bf16;
typedef __bf16 bf16x8 __attribute__((ext_vector_type(8)));
typedef float  f32x4  __attribute__((ext_vector_type(4)));

__device__ __forceinline__ unsigned short f2bf(float f) {
  unsigned int u = __builtin_bit_cast(unsigned int, f);
  u += 0x7FFFu + ((u >> 16) & 1u);          // RNE
  return (unsigned short)(u >> 16);
}
__device__ __forceinline__ float bf2f(unsigned short u) {
  return __builtin_bit_cast(float, (unsigned int)u << 16);
}
__device__ __forceinline__ float silu_f(float x) { return x / (1.f + __expf(-x)); }

#define GLDS(src, dst) \
  __builtin_amdgcn_global_load_lds( \
      (__attribute__((address_space(1))) void*)(void*)(src), \
      (__attribute__((address_space(3))) void*)(void*)(dst), 16, 0, 0)

// ---------------- prologue: cvt(h), build_w (owb/zero moved into chunk_prep's shadow) ----------------
// 16896 blocks of 256: [0,4096) h->hbf, [4096,16896) W concat.
__global__ __launch_bounds__(256) void prep_all(
    const float* __restrict__ h,
    const float* __restrict__ qw, const float* __restrict__ kw,
    const float* __restrict__ vw, const float* __restrict__ gw,
    const float* __restrict__ aw, const float* __restrict__ bw,
    unsigned short* __restrict__ hbf, unsigned short* __restrict__ Wb) {
  const int blk = blockIdx.x;
  const int tid = threadIdx.x;
  if (blk < 4096) {
    const int idx = blk * 256 + tid;
    float4 f = ((const float4*)h)[idx];
    ushort4 o = { f2bf(f.x), f2bf(f.y), f2bf(f.z), f2bf(f.w) };
    ((ushort4*)hbf)[idx] = o;
  } else {
    const int idx = (blk - 4096) * 256 + tid;
    const int r = idx >> 9;
    const int c = (idx & 511) << 2;
    const float* src;
    if      (r < 1024) src = qw + (size_t)r * 2048;
    else if (r < 2048) src = kw + (size_t)(r - 1024) * 2048;
    else if (r < 4096) src = vw + (size_t)(r - 2048) * 2048;
    else if (r < 6144) src = gw + (size_t)(r - 4096) * 2048;
    else if (r < 6152) src = aw + (size_t)(r - 6144) * 2048;
    else if (r < 6160) src = bw + (size_t)(r - 6152) * 2048;
    else               src = nullptr;
    ushort4 o;
    if (src) {
      float4 f = *(const float4*)(src + c);
      o = { f2bf(f.x), f2bf(f.y), f2bf(f.z), f2bf(f.w) };
    } else {
      o = { 0, 0, 0, 0 };
    }
    *(ushort4*)(Wb + (size_t)r * 2048 + c) = o;
  }
}

// ============ pipelined NT GEMM: BM=128 x BN tile, BK=32, ring-3 LDS, counted vmcnt ============
// C[M][N] = A[M][K_total] * B[N][K_total]^T over a K-slice. bf16 in. T threads = T/64 waves.
// If ATOMIC: inner grid = 1<<ILOG blocks, block bidAll>>ILOG handles K-slice
// [ (bidAll>>ILOG)*K , +K ), epilogue atomicAdd fp32 (exactly 2 contributions/addr,
// fp32 a+b == b+a -> bit-deterministic).
// R6-proven schedule: per K-step { STAGE(kt+2); setprio(1); 16 MFMA; setprio(0);
// lgkmcnt(0); vmcnt(LOADS); s_barrier; ds_read next frags }. vmcnt never drains to 0.
// LDS swizzle (0-conflict, R4-verified): logical k-slot s of row r at phys s ^ ((r>>1)&3).
template <int BN, int WN, int T, bool BF16OUT, bool ATOMIC, int ILOG>
__global__ __launch_bounds__(T, 4) void gemm_pipe(
    const bf16* __restrict__ A, const bf16* __restrict__ Bm,
    void* __restrict__ Cv, int N, int K, int ldk) {
  constexpr int AI = (128 * 32) / (T * 8);   // A glds insts/thread per K-tile
  constexpr int BI = (BN * 32) / (T * 8);    // B glds insts/thread per K-tile
  constexpr int LOADS = AI + BI;
  __shared__ bf16 LA[3][128 * 32];
  __shared__ bf16 LB[3][BN * 32];
  const int tid = threadIdx.x;
  const int lane = tid & 63;
  const int wid = tid >> 6;
  const int wm = wid / WN, wn = wid % WN;
  // XCD-chunked bijective block map: xcd owns m-rows {xcd, xcd+8} x all n-tiles
  const int bidAll = blockIdx.x;
  const int bid = ATOMIC ? (bidAll & ((1 << ILOG) - 1)) : bidAll;
  const long kofs = ATOMIC ? (long)(bidAll >> ILOG) * K : 0;
  const int xcd = bid & 7, jj = bid >> 3;
  const long brow = (long)(xcd + 8 * (jj & 1)) * 128;
  const long bcol = (long)(jj >> 1) * BN;

  f32x4 acc[4][4];
#pragma unroll
  for (int m = 0; m < 4; ++m)
#pragma unroll
    for (int n = 0; n < 4; ++n)
#pragma unroll
      for (int r = 0; r < 4; ++r) acc[m][n][r] = 0.f;

  // staging map: flat slot = e*T + tid -> (row = flat>>2, pslot = flat&3);
  // global source col = (pslot ^ ((row>>1)&3)) * 8  (inverse swizzle, linear LDS dest)
  const bf16* AgS[AI];
  const bf16* BgS[BI];
  int adst[AI], bdst[BI];
#pragma unroll
  for (int e = 0; e < AI; ++e) {
    const int flat = e * T + tid;
    const int row = flat >> 2;
    const int sl = (flat & 3) ^ ((row >> 1) & 3);
    AgS[e] = A + (brow + row) * (long)ldk + kofs + sl * 8;
    adst[e] = flat * 8;
  }
#pragma unroll
  for (int e = 0; e < BI; ++e) {
    const int flat = e * T + tid;
    const int row = flat >> 2;
    const int sl = (flat & 3) ^ ((row >> 1) & 3);
    BgS[e] = Bm + (bcol + row) * (long)ldk + kofs + sl * 8;
    bdst[e] = flat * 8;
  }

#define STAGE(kt, sb)                                              \
  {                                                                \
    const long ko = (long)(kt) * 32;                               \
    _Pragma("unroll")                                              \
    for (int e = 0; e < AI; ++e) GLDS(AgS[e] + ko, &LA[sb][0] + adst[e]); \
    _Pragma("unroll")                                              \
    for (int e = 0; e < BI; ++e) GLDS(BgS[e] + ko, &LB[sb][0] + bdst[e]); \
  }
#define WAIT_VM()                                                  \
  if constexpr (LOADS == 3) asm volatile("s_waitcnt vmcnt(3)" ::: "memory"); \
  else                      asm volatile("s_waitcnt vmcnt(4)" ::: "memory");

  // read offsets (halfwords): row*32 + (ks ^ ((r16>>1)&3))*8
  const int r16 = lane & 15;
  const int ks = lane >> 4;
  const int pso = (ks ^ ((r16 >> 1) & 3)) * 8;
  int rdA[4], rdB[4];
#pragma unroll
  for (int i = 0; i < 4; ++i) rdA[i] = (wm * 64 + i * 16 + r16) * 32 + pso;
#pragma unroll
  for (int j = 0; j < 4; ++j) rdB[j] = (wn * 64 + j * 16 + r16) * 32 + pso;

  const int nkt = K >> 5;
  STAGE(0, 0);
  STAGE(1, 1);
  WAIT_VM();                         // buf0 landed (stage(1) may stay in flight)
  __builtin_amdgcn_s_barrier();

  bf16x8 af[4], bfr[4];
#pragma unroll
  for (int i = 0; i < 4; ++i) af[i] = *(const bf16x8*)(&LA[0][0] + rdA[i]);
#pragma unroll
  for (int j = 0; j < 4; ++j) bfr[j] = *(const bf16x8*)(&LB[0][0] + rdB[j]);

  for (int kt = 0; kt < nkt; ++kt) {
    const int kts = (kt + 2 < nkt) ? kt + 2 : nkt - 1;  // clamp src, keep count uniform
    const int sb = (kt + 2) % 3;                        // == (kt-1)%3: read-complete slot
    const int nb = (kt + 1) % 3;

    STAGE(kts, sb);
    __builtin_amdgcn_s_setprio(1);
#pragma unroll
    for (int i = 0; i < 4; ++i)
#pragma unroll
      for (int j = 0; j < 4; ++j)
        acc[i][j] = __builtin_amdgcn_mfma_f32_16x16x32_bf16(af[i], bfr[j], acc[i][j], 0, 0, 0);
    __builtin_amdgcn_s_setprio(0);

    asm volatile("s_waitcnt lgkmcnt(0)" ::: "memory");
    WAIT_VM();                       // kt+1 landed; kt+2 stays in flight
    __builtin_amdgcn_s_barrier();
#pragma unroll
    for (int i = 0; i < 4; ++i) af[i] = *(const bf16x8*)(&LA[nb][0] + rdA[i]);
#pragma unroll
    for (int j = 0; j < 4; ++j) bfr[j] = *(const bf16x8*)(&LB[nb][0] + rdB[j]);
  }
#undef STAGE
#undef WAIT_VM

  // epilogue: C/D layout col=lane&15, row=(lane>>4)*4+r
  const long row0 = brow + wm * 64 + ((lane >> 4) * 4);
  const long col0 = bcol + wn * 64 + (lane & 15);
#pragma unroll
  for (int m = 0; m < 4; ++m)
#pragma unroll
    for (int n = 0; n < 4; ++n)
#pragma unroll
      for (int r = 0; r < 4; ++r) {
        const long idx = (row0 + m * 16 + r) * (long)N + col0 + n * 16;
        if constexpr (ATOMIC)
          atomicAdd((float*)Cv + idx, acc[m][n][r]);
        else if constexpr (BF16OUT)
          ((unsigned short*)Cv)[idx] = f2bf(acc[m][n][r]);
        else
          ((float*)Cv)[idx] = acc[m][n][r];
      }
}

// ---------------- small NT GEMM on LDS operands: OUT[i][j] = sum_k A[i][k]*B[j][k] ----------------
// A: [M][K] bf16 LDS, B: [N][K] bf16 LDS. NW waves. Output bf16 global (ldg).
template <int M, int N, int K, int NW>
__device__ __forceinline__ void mm_nt_lds(const unsigned short* A, const unsigned short* B,
                                          unsigned short* outG, int ldg, int tid) {
  constexpr int NT16 = N / 16;
  constexpr int PW = (M / 16) * NT16 / NW;
  const int w = tid >> 6, l = tid & 63;
  const int row = l & 15, ko = (l >> 4) * 8;
  f32x4 acc[PW];
#pragma unroll
  for (int i = 0; i < PW; ++i)
#pragma unroll
    for (int r = 0; r < 4; ++r) acc[i][r] = 0.f;
#pragma unroll
  for (int i = 0; i < PW; ++i) {
    const int ti = w + NW * i;
    const int rt = ti / NT16, ct = ti % NT16;
#pragma unroll
    for (int kk = 0; kk < K / 32; ++kk) {
      bf16x8 af = *(const bf16x8*)(A + (rt * 16 + row) * K + kk * 32 + ko);
      bf16x8 bf = *(const bf16x8*)(B + (ct * 16 + row) * K + kk * 32 + ko);
      acc[i] = __builtin_amdgcn_mfma_f32_16x16x32_bf16(af, bf, acc[i], 0, 0, 0);
    }
  }
#pragma unroll
  for (int i = 0; i < PW; ++i) {
    const int ti = w + NW * i;
    const int rt = ti / NT16, ct = ti % NT16;
    const int r0 = rt * 16 + (l >> 4) * 4;
    const int col = ct * 16 + (l & 15);
#pragma unroll
    for (int r = 0; r < 4; ++r)
      outG[(size_t)(r0 + r) * ldg + col] = f2bf(acc[i][r]);
  }
}

// 64x64 NT MFMA accumulate (8 waves, 2 tiles/wave), epilogue left to caller
template <int K>
__device__ __forceinline__ void mm64_acc(const unsigned short* A, const unsigned short* B,
                                         f32x4 acc[2], int w, int row, int ko) {
#pragma unroll
  for (int i = 0; i < 2; ++i) {
    const int ti = w + 8 * i;
    const int rt = ti >> 2, ct = ti & 3;
#pragma unroll
    for (int kk = 0; kk < K / 32; ++kk) {
      bf16x8 af = *(const bf16x8*)(A + (rt * 16 + row) * K + kk * 32 + ko);
      bf16x8 bf = *(const bf16x8*)(B + (ct * 16 + row) * K + kk * 32 + ko);
      acc[i] = __builtin_amdgcn_mfma_f32_16x16x32_bf16(af, bf, acc[i], 0, 0, 0);
    }
  }
}

// ---------------- phase 1: conv+norm fused + per-chunk UT transform (C=64), 512 threads ----------------
// Blocks 0-255: chunk work. Blocks 256-1279: owb conversion + d_out zeroing (runs in this
// latency-bound kernel's idle-bandwidth shadow; outputs needed only by GEMM2, 3 dispatches later).
__global__ __launch_bounds__(512, 4) void chunk_prep(
    const unsigned short* __restrict__ Y,
    const float* __restrict__ qcw, const float* __restrict__ kcw, const float* __restrict__ vcw,
    const float* __restrict__ A_log, const float* __restrict__ dt_bias,
    unsigned short* __restrict__ Wg, unsigned short* __restrict__ Ubg,
    unsigned short* __restrict__ Attg, unsigned short* __restrict__ Qgg,
    unsigned short* __restrict__ KgTg, float* __restrict__ decg,
    const float* __restrict__ ow, unsigned short* __restrict__ owb,
    float* __restrict__ zout) {
  __shared__ unsigned short SM[36864];          // 72 KB overlay arena
  unsigned short* Kb_s   = SM;                  // [64][128]   8192 us
  unsigned short* Qb_s   = SM + 8192;           // [64][128]   8192 us (later KbgT)
  unsigned short* Xrow_s = SM + 16384;          // [64][64]    4096 us
  unsigned short* Mb_s   = SM + 20480;          // [64][64]    4096 us (scratch)
  unsigned short* Xt_s   = SM + 24576;          // [64][64]    4096 us (scratch)
  unsigned short* Yt_s   = SM + 28672;          // [64][64]    4096 us (scratch)
  unsigned short* VbT_s  = SM + 20480;          // [256][64]  16384 us (overlays scratch)
  __shared__ float carr_s[64];
  __shared__ float beta_s[64];

  const int tid = threadIdx.x;
  const int ch = blockIdx.x;
  // ---- aux elementwise blocks: owb cvt (4 slots/thread) + d_out zero (4 slots/thread) ----
  if (ch >= 256) {
    const int i = ch - 256;
    if (i < 512) {
#pragma unroll
      for (int e = 0; e < 4; ++e) {
        const int idx = e * 262144 + i * 512 + tid;
        float4 f = ((const float4*)ow)[idx];
        ushort4 o = { f2bf(f.x), f2bf(f.y), f2bf(f.z), f2bf(f.w) };
        ((ushort4*)owb)[idx] = o;
      }
    } else {
      const int i2 = i - 512;
      float4 z = {0.f, 0.f, 0.f, 0.f};
#pragma unroll
      for (int e = 0; e < 4; ++e) {
        const int idx = e * 262144 + i2 * 512 + tid;
        ((float4*)zout)[idx] = z;
      }
    }
    return;
  }

  const int w = tid >> 6, l = tid & 63;
  const int row16 = l & 15, ko = (l >> 4) * 8;
  const int bh = ch >> 4, p = ch & 15;
  const int b = bh >> 3, h = bh & 7;
  const size_t tbase = (size_t)b * T_LEN + p * 64;
  const bool head = (p == 0);

  // 1. per-step scalars + cumulative log-decay (wave 0, from Y directly)
  if (tid < 64) {
    const unsigned short* Yr = Y + (tbase + tid) * NBIG;
    float a = bf2f(Yr[6144 + h]) + dt_bias[h];
    float sp = (a > 20.f) ? a : log1pf(expf(a));
    float g = -expf(A_log[h]) * sp;
    float bp = bf2f(Yr[6152 + h]);
    beta_s[tid] = 1.f / (1.f + expf(-bp));
    float c = g;
#pragma unroll
    for (int d = 1; d < 64; d <<= 1) {
      float y = __shfl_up(c, d);
      if (tid >= d) c += y;
    }
    carr_s[tid] = c;
    if (tid == 63) decg[ch] = __expf(c);
  }
  __syncthreads();   // beta/carr ready

  // 2. conv+SiLU+l2norm for q (waves 0-3) and k (waves 4-7) -> Qb_s/Kb_s [64][128]
  {
    const bool isQ = (tid < 256);
    const int wk = tid & 255;
    const int quad = wk & 31, tg = wk >> 5;     // 32 quads x 8 t-groups (8 t each)
    const int c = quad * 4;
    const float* cw = isQ ? qcw : kcw;
    const int cb = (isQ ? 0 : 1024) + h * 128 + c;
    float4 wv[4];
#pragma unroll
    for (int e = 0; e < 4; ++e) wv[e] = ((const float4*)cw)[h * 128 + c + e];
    float rows[11][4];
#pragma unroll
    for (int r = 0; r < 11; ++r) {
      if (head && tg == 0 && r < 3) {
        rows[r][0] = rows[r][1] = rows[r][2] = rows[r][3] = 0.f;
      } else {
        const ushort4 x = *(const ushort4*)(Y + (tbase + tg * 8 - 3 + r) * NBIG + cb);
        rows[r][0] = bf2f(x.x); rows[r][1] = bf2f(x.y);
        rows[r][2] = bf2f(x.z); rows[r][3] = bf2f(x.w);
      }
    }
    unsigned short* dst = isQ ? Qb_s : Kb_s;
    const float sc = isQ ? SCALE_Q : 1.f;
#pragma unroll
    for (int i = 0; i < 8; ++i) {
      float acc[4], ss = 0.f;
#pragma unroll
      for (int e = 0; e < 4; ++e) {
        float a = wv[e].x * rows[i][e];
        a = fmaf(wv[e].y, rows[i + 1][e], a);
        a = fmaf(wv[e].z, rows[i + 2][e], a);
        a = fmaf(wv[e].w, rows[i + 3][e], a);
        a = silu_f(a);
        acc[e] = a;
        ss += a * a;
      }
#pragma unroll
      for (int m = 16; m >= 1; m >>= 1) ss += __shfl_xor(ss, m);
      const float rn = rsqrtf(ss + 1e-6f) * sc;
      ushort4 o = {f2bf(acc[0] * rn), f2bf(acc[1] * rn), f2bf(acc[2] * rn), f2bf(acc[3] * rn)};
      *(ushort4*)(dst + (tg * 8 + i) * 128 + c) = o;
    }
  }
  __syncthreads();   // Kb/Qb ready

  float xf[2][4];    // X fp32 master, per-thread (same tile indices across phases)
  // 4+5 fused: A_raw = K K^T; epilogue builds M = I+A, X0 = I-A (xf, Xrow, Xt)
  {
    f32x4 acc[2];
#pragma unroll
    for (int i = 0; i < 2; ++i)
#pragma unroll
      for (int r = 0; r < 4; ++r) acc[i][r] = 0.f;
    mm64_acc<128>(Kb_s, Kb_s, acc, w, row16, ko);
#pragma unroll
    for (int i = 0; i < 2; ++i) {
      const int ti = w + 8 * i;
      const int rt = ti >> 2, ct = ti & 3;
      const int r0 = rt * 16 + (l >> 4) * 4;
      const int col = ct * 16 + (l & 15);
#pragma unroll
      for (int r = 0; r < 4; ++r) {
        const int t = r0 + r, j = col;
        const float av = (j < t) ? beta_s[t] * __expf(carr_s[t] - carr_s[j]) * acc[i][r] : 0.f;
        const float dg = (t == j) ? 1.f : 0.f;
        Mb_s[t * 64 + j] = f2bf(dg + av);
        const float x0 = dg - av;
        xf[i][r] = x0;
        const unsigned short xb = f2bf(x0);
        Xrow_s[t * 64 + j] = xb;
        Xt_s[j * 64 + t] = xb;
      }
    }
  }
  __syncthreads();
  // 6. Newton x5: X <- X(2I - M X), in place (exact: A nilpotent)
  for (int it = 0; it < 5; ++it) {
    {  // Yt = (M X)^T  (transposed-write epilogue; Yt disjoint from Mb/Xt)
      f32x4 acc[2];
#pragma unroll
      for (int i = 0; i < 2; ++i)
#pragma unroll
        for (int r = 0; r < 4; ++r) acc[i][r] = 0.f;
      mm64_acc<64>(Mb_s, Xt_s, acc, w, row16, ko);
#pragma unroll
      for (int i = 0; i < 2; ++i) {
        const int ti = w + 8 * i;
        const int rt = ti >> 2, ct = ti & 3;
        const int r0 = rt * 16 + (l >> 4) * 4;
        const int col = ct * 16 + (l & 15);
#pragma unroll
        for (int r = 0; r < 4; ++r)
          Yt_s[col * 64 + (r0 + r)] = f2bf(acc[i][r]);
      }
    }
    __syncthreads();
    {  // P = X Y ; X' = 2*xf - P   (in-place: barrier between reads and writes)
      f32x4 acc[2];
#pragma unroll
      for (int i = 0; i < 2; ++i)
#pragma unroll
        for (int r = 0; r < 4; ++r) acc[i][r] = 0.f;
      mm64_acc<64>(Xrow_s, Yt_s, acc, w, row16, ko);
      __syncthreads();   // all Xrow reads drained before overwrite
#pragma unroll
      for (int i = 0; i < 2; ++i) {
        const int ti = w + 8 * i;
        const int rt = ti >> 2, ct = ti & 3;
        const int r0 = rt * 16 + (l >> 4) * 4;
        const int col = ct * 16 + (l & 15);
#pragma unroll
        for (int r = 0; r < 4; ++r) {
          const float xn = 2.f * xf[i][r] - acc[i][r];
          xf[i][r] = xn;
          const unsigned short xb = f2bf(xn);
          Xrow_s[(r0 + r) * 64 + col] = xb;
          Xt_s[col * 64 + (r0 + r)] = xb;
        }
      }
    }
    __syncthreads();
  }
  const float ctot = carr_s[63];
  // 3 (moved): conv+SiLU for v, *beta, transposed -> VbT_s (overlays dead Newton scratch)
  {
    const int quad = tid & 63, tg = tid >> 6;   // 64 quads x 8 t-groups
    const int c = quad * 4;
    float4 wv[4];
#pragma unroll
    for (int e = 0; e < 4; ++e) wv[e] = ((const float4*)vcw)[h * 256 + c + e];
    float rows[11][4];
#pragma unroll
    for (int r = 0; r < 11; ++r) {
      if (head && tg == 0 && r < 3) {
        rows[r][0] = rows[r][1] = rows[r][2] = rows[r][3] = 0.f;
      } else {
        const ushort4 x = *(const ushort4*)(Y + (tbase + tg * 8 - 3 + r) * NBIG + 2048 + h * 256 + c);
        rows[r][0] = bf2f(x.x); rows[r][1] = bf2f(x.y);
        rows[r][2] = bf2f(x.z); rows[r][3] = bf2f(x.w);
      }
    }
#pragma unroll
    for (int i = 0; i < 8; ++i) {
      const int t = tg * 8 + i;
      const float bt = beta_s[t];
#pragma unroll
      for (int e = 0; e < 4; ++e) {
        float a = wv[e].x * rows[i][e];
        a = fmaf(wv[e].y, rows[i + 1][e], a);
        a = fmaf(wv[e].z, rows[i + 2][e], a);
        a = fmaf(wv[e].w, rows[i + 3][e], a);
        VbT_s[(c + e) * 64 + t] = f2bf(bt * silu_f(a));
      }
    }
  }
  // 7+8 fused: Att = mask(exp) o (Q K^T) -> global directly
  {
    f32x4 acc[2];
#pragma unroll
    for (int i = 0; i < 2; ++i)
#pragma unroll
      for (int r = 0; r < 4; ++r) acc[i][r] = 0.f;
    mm64_acc<128>(Qb_s, Kb_s, acc, w, row16, ko);
#pragma unroll
    for (int i = 0; i < 2; ++i) {
      const int ti = w + 8 * i;
      const int rt = ti >> 2, ct = ti & 3;
      const int r0 = rt * 16 + (l >> 4) * 4;
      const int col = ct * 16 + (l & 15);
#pragma unroll
      for (int r = 0; r < 4; ++r) {
        const int t = r0 + r, j = col;
        const float av = (j <= t) ? __expf(carr_s[t] - carr_s[j]) * acc[i][r] : 0.f;
        Attg[(size_t)ch * 4096 + t * 64 + j] = f2bf(av);
      }
    }
  }
  // Qg, KgT -> global (elementwise from Qb/Kb)
#pragma unroll
  for (int i = 0; i < 16; ++i) {
    const int idx = i * 512 + tid;
    const int t = idx >> 7;
    Qgg[(size_t)ch * 8192 + idx] = f2bf(__expf(carr_s[t]) * bf2f(Qb_s[idx]));
  }
#pragma unroll
  for (int i = 0; i < 16; ++i) {
    const int idx = i * 512 + tid;
    const int d = idx >> 6, t = idx & 63;
    KgTg[(size_t)ch * 8192 + idx] = f2bf(__expf(ctot - carr_s[t]) * bf2f(Kb_s[t * 128 + d]));
  }
  __syncthreads();   // Qb reads done before reuse; VbT writes visible
  // 9. KbgT[d][t] = bf16(beta_t exp(c_t) k[t][d])  (into Qb space)
  unsigned short* KbgT = Qb_s;
#pragma unroll
  for (int i = 0; i < 16; ++i) {
    const int idx = i * 512 + tid;
    const int d = idx >> 6, t = idx & 63;
    KbgT[idx] = f2bf(beta_s[t] * __expf(carr_s[t]) * bf2f(Kb_s[t * 128 + d]));
  }
  __syncthreads();
  // 10. W = T (betaG.K)  [64x128];  Ub = T (betaV)  [64x256]  -> global bf16
  mm_nt_lds<64, 128, 64, 8>(Xrow_s, KbgT, Wg + (size_t)ch * 8192, 128, tid);
  mm_nt_lds<64, 256, 64, 8>(Xrow_s, VbT_s, Ubg + (size_t)ch * 16384, 256, tid);
}

// ---------------- phase 2: serial chunk recurrence (MFMA), 16 bh x 16 v-blocks, 512 thr ----------------
// 256 blocks (1/CU). Same-bh blocks land on one XCD (blk%8 = bh%8) -> W/Att/Qg/KgT L2-resident.
// De-staged: all MFMA fragments read DIRECTLY global->register (16B contiguous; L2-hot, 16x reuse
// per XCD). LDS keeps only S-state and uT. 2 barriers/phase:
//   A: StTb(p-1) ready + uT readers of p-1 done;  B: uT ready.
__global__ __launch_bounds__(512, 1) void scan_chunks(
    const unsigned short* __restrict__ Wg, const unsigned short* __restrict__ Ubg,
    const unsigned short* __restrict__ Attg, const unsigned short* __restrict__ Qgg,
    const unsigned short* __restrict__ KgTg, const float* __restrict__ decg,
    float* __restrict__ osc) {
  __shared__ float StT_s[16 * 128];            // S^T fp32 [vcol][d]
  __shared__ unsigned short StTb_s[16 * 128];  // S^T bf16
  __shared__ unsigned short uT_s[16 * 64];     // u^T bf16 [vcol][t]

  const int tid = threadIdx.x;
  const int w = tid >> 6, l = tid & 63;
  const int row = l & 15, ko = (l >> 4) * 8;
  const int blk = blockIdx.x;                  // vb*16 + bh  (same-bh blocks share an XCD)
  const int vb = blk >> 4, bh = blk & 15;
  const int b = bh >> 3, h = bh & 7;
  const bool uw = (w < 4);                     // u/O phases use 4 waves (4 tiles of 64x16)
  const int r0 = w * 16 + (l >> 4) * 4;        // uw epilogue row base
  const int col = l & 15;

  for (int i = tid; i < 2048; i += 512) { StT_s[i] = 0.f; StTb_s[i] = 0; }

  for (int p = 0; p < 16; ++p) {
    const size_t ch = (size_t)(bh * 16 + p);
    const unsigned short* Wp   = Wg   + ch * 8192;
    const unsigned short* Attp = Attg + ch * 4096;
    const unsigned short* Qgp  = Qgg  + ch * 8192;
    const unsigned short* KgTp = KgTg + ch * 8192;
    const unsigned short* Ubp  = Ubg  + ch * 16384;
    const float dec = decg[ch];

    // ---- issue this phase's global fragment loads (read-only; no sync hazard) ----
    bf16x8 wf[4], qf[4], atf[2], kf[2];
    float ubv[4];
    if (uw) {
#pragma unroll
      for (int kk = 0; kk < 4; ++kk) wf[kk]  = *(const bf16x8*)(Wp  + (w * 16 + row) * 128 + kk * 32 + ko);
#pragma unroll
      for (int kk = 0; kk < 4; ++kk) qf[kk]  = *(const bf16x8*)(Qgp + (w * 16 + row) * 128 + kk * 32 + ko);
#pragma unroll
      for (int kk = 0; kk < 2; ++kk) atf[kk] = *(const bf16x8*)(Attp + (w * 16 + row) * 64 + kk * 32 + ko);
#pragma unroll
      for (int r = 0; r < 4; ++r)    ubv[r]  = bf2f(Ubp[(r0 + r) * 256 + vb * 16 + col]);
    }
#pragma unroll
    for (int kk = 0; kk < 2; ++kk)   kf[kk]  = *(const bf16x8*)(KgTp + (w * 16 + row) * 64 + kk * 32 + ko);

    __syncthreads();   // A: StTb from p-1 epilogue ready; p-1's uT readers done

    // ---- u = Ub - W S : acc [64x16], waves 0-3; StTb frags kept for O ----
    bf16x8 stf[4];
    f32x4 uacc;
#pragma unroll
    for (int r = 0; r < 4; ++r) uacc[r] = 0.f;
    if (uw) {
#pragma unroll
      for (int kk = 0; kk < 4; ++kk) {
        stf[kk] = *(const bf16x8*)(StTb_s + row * 128 + kk * 32 + ko);
        uacc = __builtin_amdgcn_mfma_f32_16x16x32_bf16(wf[kk], stf[kk], uacc, 0, 0, 0);
      }
#pragma unroll
      for (int r = 0; r < 4; ++r)
        uT_s[col * 64 + (r0 + r)] = f2bf(ubv[r] - uacc[r]);
    }
    __syncthreads();   // B: uT ready

    // ---- O = Qg S + Att u : waves 0-3 ----
    f32x4 oacc;
#pragma unroll
    for (int r = 0; r < 4; ++r) oacc[r] = 0.f;
    bf16x8 utf[2];
#pragma unroll
    for (int kk = 0; kk < 2; ++kk) utf[kk] = *(const bf16x8*)(uT_s + row * 64 + kk * 32 + ko);
    if (uw) {
#pragma unroll
      for (int kk = 0; kk < 4; ++kk)
        oacc = __builtin_amdgcn_mfma_f32_16x16x32_bf16(qf[kk], stf[kk], oacc, 0, 0, 0);
#pragma unroll
      for (int kk = 0; kk < 2; ++kk)
        oacc = __builtin_amdgcn_mfma_f32_16x16x32_bf16(atf[kk], utf[kk], oacc, 0, 0, 0);
    }
    // ---- Snew^T = dec*S^T + (u^T)(KgT^T) : all 8 waves, 1 tile each ----
    f32x4 sacc;
#pragma unroll
    for (int r = 0; r < 4; ++r) sacc[r] = 0.f;
#pragma unroll
    for (int kk = 0; kk < 2; ++kk)
      sacc = __builtin_amdgcn_mfma_f32_16x16x32_bf16(utf[kk], kf[kk], sacc, 0, 0, 0);

    // epilogues (per-thread-owned S locations; StTb written before next barrier A)
    if (uw) {
#pragma unroll
      for (int r = 0; r < 4; ++r) {
        const size_t trow = (size_t)b * T_LEN + p * 64 + r0 + r;
        osc[(trow * 8 + h) * 256 + vb * 16 + col] = oacc[r];
      }
    }
    {
      const int cold = w * 16 + (l & 15);
#pragma unroll
      for (int r = 0; r < 4; ++r) {
        const int idx = ((l >> 4) * 4 + r) * 128 + cold;
        const float sn = fmaf(dec, StT_s[idx], sacc[r]);
        StT_s[idx] = sn;
        StTb_s[idx] = f2bf(sn);
      }
    }
  }
}

// ---------------- gated RMSNorm + silu(gate) -> bf16 ----------------
__global__ __launch_bounds__(256) void rmsgate(
    const float* __restrict__ ob, const unsigned short* __restrict__ Y,
    const float* __restrict__ onw, unsigned short* __restrict__ Obf) {
  const int bt = blockIdx.x;
  const int tid = threadIdx.x;
  const int c = tid * 8;                // head = c/256 = tid/32
  const float* orow = ob + (size_t)bt * 2048 + c;
  const unsigned short* grow = Y + (size_t)bt * NBIG + 4096 + c;
  const float4 o0 = *(const float4*)orow, o1 = *(const float4*)(orow + 4);
  const ushort4 g0 = *(const ushort4*)grow, g1 = *(const ushort4*)(grow + 4);
  const float ov[8] = {o0.x, o0.y, o0.z, o0.w, o1.x, o1.y, o1.z, o1.w};
  const float gv[8] = {bf2f(g0.x), bf2f(g0.y), bf2f(g0.z), bf2f(g0.w),
                       bf2f(g1.x), bf2f(g1.y), bf2f(g1.z), bf2f(g1.w)};
  float ss = 0.f;
#pragma unroll
  for (int e = 0; e < 8; ++e) ss += ov[e] * ov[e];
#pragma unroll
  for (int m = 16; m >= 1; m >>= 1) ss += __shfl_xor(ss, m);
  const float rn = rsqrtf(ss * (1.f / 256.f) + 1e-5f);
  const int dv = c & 255;
  unsigned short rr[8];
#pragma unroll
  for (int e = 0; e < 8; ++e) {
    const float val = ov[e] * rn * onw[dv + e] * silu_f(gv[e]);
    rr[e] = f2bf(val);
  }
  ushort4 r0 = {rr[0], rr[1], rr[2], rr[3]};
  ushort4 r1 = {rr[4], rr[5], rr[6], rr[7]};
  *(ushort4*)(Obf + (size_t)bt * 2048 + c) = r0;
  *(ushort4*)(Obf + (size_t)bt * 2048 + c + 4) = r1;
}

extern "C" void kernel_launch(void* const* d_in, const int* in_sizes, int n_in,
                              void* d_out, int out_size, void* d_ws, size_t ws_size,
                              hipStream_t stream) {
  (void)in_sizes; (void)n_in; (void)out_size; (void)ws_size;
  const float* h    = (const float*)d_in[0];
  const float* qw   = (const float*)d_in[1];
  const float* kw   = (const float*)d_in[2];
  const float* vw   = (const float*)d_in[3];
  const float* aw   = (const float*)d_in[4];
  const float* bw   = (const float*)d_in[5];
  const float* gw   = (const float*)d_in[6];
  const float* ow   = (const float*)d_in[7];
  const float* qcw  = (const float*)d_in[8];
  const float* kcw  = (const float*)d_in[9];
  const float* vcw  = (const float*)d_in[10];
  const float* Alog = (const float*)d_in[11];
  const float* dtb  = (const float*)d_in[12];
  const float* onw  = (const float*)d_in[13];

  char* ws = (char*)d_ws;
  size_t off = 0;
  auto alloc = [&](size_t bytes) {
    char* p = ws + off;
    off = (off + bytes + 255) & ~(size_t)255;
    return p;
  };
  unsigned short* hbf  = (unsigned short*)alloc(2048ull * 2048 * 2);
  unsigned short* Wb   = (unsigned short*)alloc((size_t)NBIG * 2048 * 2);
  unsigned short* owb  = (unsigned short*)alloc(2048ull * 2048 * 2);
  unsigned short* Ybf  = (unsigned short*)alloc(2048ull * NBIG * 2);
  float* osc           = (float*)alloc(2048ull * 2048 * 4);
  unsigned short* Obf  = (unsigned short*)alloc(2048ull * 2048 * 2);
  unsigned short* Wg   = (unsigned short*)alloc(256ull * 8192 * 2);
  unsigned short* Ubg  = (unsigned short*)alloc(256ull * 16384 * 2);
  unsigned short* Attg = (unsigned short*)alloc(256ull * 4096 * 2);
  unsigned short* Qgg  = (unsigned short*)alloc(256ull * 8192 * 2);
  unsigned short* KgTg = (unsigned short*)alloc(256ull * 8192 * 2);
  float* decg          = (float*)alloc(256ull * 4);

  // prologue: cvt(h) + build_w (owb cvt + d_out zero moved into chunk_prep's shadow)
  prep_all<<<16896, 256, 0, stream>>>(h, qw, kw, vw, gw, aw, bw, hbf, Wb);
  // GEMM1: 16 x 25 tiles of 128x256 -> 400 blocks (R9-measured best config)
  gemm_pipe<256, 4, 512, true, false, 0><<<400, 512, 0, stream>>>(
      (const bf16*)hbf, (const bf16*)Wb, Ybf, NBIG, 2048, 2048);
  // chunk_prep (blocks 0-255) + aux owb/zero (blocks 256-1279, 4 slots/thread)
  chunk_prep<<<1280, 512, 0, stream>>>(Ybf, qcw, kcw, vcw, Alog, dtb,
                                       Wg, Ubg, Attg, Qgg, KgTg, decg,
                                       ow, owb, (float*)d_out);
  scan_chunks<<<256, 512, 0, stream>>>(Wg, Ubg, Attg, Qgg, KgTg, decg, osc);
  rmsgate<<<2048, 256, 0, stream>>>(osc, Ybf, onw, Obf);
  // GEMM2: K-split x2 at BN=256/T=512 -> inner 16x8=128, total 256 blocks (1/CU, balanced),
  // fp32 atomicAdd epilogue (exactly 2 contributions/addr -> bit-deterministic)
  gemm_pipe<256, 4, 512, false, true, 7><<<256, 512, 0, stream>>>(
      (const bf16*)Obf, (const bf16*)owb, d_out, 2048, 1024, 2048);
}